// Round 2
// baseline (6000.365 us; speedup 1.0000x reference)
//
#include <hip/hip_runtime.h>

#define Nn 4096
#define KK 20
#define BN 16384   // B*N, B=4

// ---------------- extract pts = x[:,:,:3] ---------------------------------
__global__ void k_pts(const float* __restrict__ x, float* __restrict__ pts) {
  int i = blockIdx.x * 256 + threadIdx.x;
  if (i < BN * 3) {
    int pt = i / 3, c = i - 3 * pt;
    pts[i] = x[pt * 6 + c];
  }
}

// ---------------- kNN, C=3 -------------------------------------------------
// block: 256 thr = 64 queries x 4 splits; exact top-20 under (val desc, idx asc)
__global__ __launch_bounds__(256) void k_knn3(const float* __restrict__ src, int* __restrict__ idx) {
  __shared__ float tile[3072];
  __shared__ float mv[64][4][20];
  __shared__ int   mi[64][4][20];
  int t = threadIdx.x;
  int ql = t >> 2, s = t & 3;
  int g = blockIdx.x * 64 + ql;
  int b = g >> 12, n = g & (Nn - 1);
  const float* base = src + (size_t)b * Nn * 3;
  float qx = base[n * 3 + 0], qy = base[n * 3 + 1], qz = base[n * 3 + 2];
  float qsq = qx * qx + qy * qy + qz * qz;
  float vals[20]; int ids[20];
#pragma unroll
  for (int k = 0; k < 20; ++k) { vals[k] = -INFINITY; ids[k] = 0; }
  for (int tb = 0; tb < 4; ++tb) {
    __syncthreads();
    for (int e = t; e < 3072; e += 256) tile[e] = base[tb * 3072 + e];
    __syncthreads();
    for (int c = s; c < 1024; c += 4) {
      float mx = tile[c * 3], my = tile[c * 3 + 1], mz = tile[c * 3 + 2];
      float msq = mx * mx + my * my + mz * mz;
      float d = 2.0f * (qx * mx + qy * my + qz * mz) - qsq - msq;
      int m = tb * 1024 + c;
      if (d > vals[19]) {   // ties lose (m ascending within split) = lowest-idx-first
        vals[19] = d; ids[19] = m;
#pragma unroll
        for (int k = 19; k > 0; --k) {
          if (vals[k] > vals[k - 1]) {
            float tv = vals[k]; vals[k] = vals[k - 1]; vals[k - 1] = tv;
            int ti = ids[k]; ids[k] = ids[k - 1]; ids[k - 1] = ti;
          } else break;
        }
      }
    }
  }
#pragma unroll
  for (int k = 0; k < 20; ++k) { mv[ql][s][k] = vals[k]; mi[ql][s][k] = ids[k]; }
  __syncthreads();
  if (s == 0) {
    int ptr[4] = {0, 0, 0, 0};
    int* op = idx + (size_t)g * KK;
    for (int k = 0; k < 20; ++k) {
      float bv = 0.f; int bi = 0; int bs = -1;
#pragma unroll
      for (int j = 0; j < 4; ++j) {
        int pj = ptr[j];
        if (pj < 20) {
          float v = mv[ql][j][pj]; int id = mi[ql][j][pj];
          if (bs < 0 || v > bv || (v == bv && id < bi)) { bv = v; bi = id; bs = j; }
        }
      }
      op[k] = bi; ptr[bs]++;
    }
  }
}

// ---------------- sq norms for 64-dim features ----------------------------
__global__ void k_sqnorm(const float* __restrict__ src, float* __restrict__ out) {
  int g = blockIdx.x * 256 + threadIdx.x;
  if (g >= BN) return;
  const float4* r = (const float4*)(src + (size_t)g * 64);
  float s = 0.f;
#pragma unroll
  for (int j = 0; j < 16; ++j) { float4 v = r[j]; s += v.x * v.x + v.y * v.y + v.z * v.z + v.w * v.w; }
  out[g] = s;
}

// ---------------- kNN, C=64 ------------------------------------------------
// block: 256 thr = 32 queries x 8 splits; LDS tile 64 rows padded to 68 floats
__global__ __launch_bounds__(256) void k_knn64(const float* __restrict__ src, const float* __restrict__ sqb,
                                               int* __restrict__ idx) {
  __shared__ float tile[64 * 68];
  __shared__ float tsq[64];
  __shared__ float mv[32][8][20];
  __shared__ int   mi[32][8][20];
  int t = threadIdx.x;
  int ql = t >> 3, s = t & 7;
  int g = blockIdx.x * 32 + ql;
  int b = g >> 12, n = g & (Nn - 1);
  const float* base = src + (size_t)b * Nn * 64;
  float q[64];
  const float4* qrow = (const float4*)(base + (size_t)n * 64);
#pragma unroll
  for (int j = 0; j < 16; ++j) {
    float4 v = qrow[j];
    q[4 * j] = v.x; q[4 * j + 1] = v.y; q[4 * j + 2] = v.z; q[4 * j + 3] = v.w;
  }
  float qsq = sqb[g];
  float vals[20]; int ids[20];
#pragma unroll
  for (int k = 0; k < 20; ++k) { vals[k] = -INFINITY; ids[k] = 0; }
  for (int tb = 0; tb < 64; ++tb) {
    __syncthreads();
    const float4* tsrc = (const float4*)(base + (size_t)tb * 64 * 64);
#pragma unroll
    for (int e = 0; e < 4; ++e) {
      int f = t + 256 * e;
      int row = f >> 4, col = f & 15;
      *((float4*)(tile + row * 68) + col) = tsrc[f];
    }
    if (t < 64) tsq[t] = sqb[b * Nn + tb * 64 + t];
    __syncthreads();
    for (int ci = 0; ci < 8; ++ci) {
      int c = (ci << 3) + s;
      const float* mrow = tile + c * 68;
      float dot = 0.f;
#pragma unroll
      for (int j = 0; j < 64; ++j) dot = fmaf(q[j], mrow[j], dot);
      float d = 2.0f * dot - qsq - tsq[c];
      int m = tb * 64 + c;
      if (d > vals[19]) {
        vals[19] = d; ids[19] = m;
#pragma unroll
        for (int k = 19; k > 0; --k) {
          if (vals[k] > vals[k - 1]) {
            float tv = vals[k]; vals[k] = vals[k - 1]; vals[k - 1] = tv;
            int ti = ids[k]; ids[k] = ids[k - 1]; ids[k - 1] = ti;
          } else break;
        }
      }
    }
  }
#pragma unroll
  for (int k = 0; k < 20; ++k) { mv[ql][s][k] = vals[k]; mi[ql][s][k] = ids[k]; }
  __syncthreads();
  if (s == 0) {
    int ptr[8] = {0, 0, 0, 0, 0, 0, 0, 0};
    int* op = idx + (size_t)g * KK;
    for (int k = 0; k < 20; ++k) {
      float bv = 0.f; int bi = 0; int bs = -1;
#pragma unroll
      for (int j = 0; j < 8; ++j) {
        int pj = ptr[j];
        if (pj < 20) {
          float v = mv[ql][j][pj]; int id = mi[ql][j][pj];
          if (bs < 0 || v > bv || (v == bv && id < bi)) { bv = v; bi = id; bs = j; }
        }
      }
      op[k] = bi; ptr[bs]++;
    }
  }
}

// ---------------- edge conv, CF=3, 6->64->OUT, max over K -----------------
template <int OUT>
__global__ __launch_bounds__(256) void k_edge3(const float* __restrict__ fin, const int* __restrict__ idx,
                                               const float* __restrict__ w1, const float* __restrict__ b1,
                                               const float* __restrict__ w2, const float* __restrict__ b2,
                                               float* __restrict__ fout) {
  __shared__ float sw1[384];
  __shared__ float sw2[64 * OUT];
  __shared__ float sb1[64], sb2[OUT];
  __shared__ float scen[3];
  __shared__ float ccon[64];
  __shared__ int   sidx[20];
  __shared__ float dn[60];
  __shared__ float y1[1280];
  __shared__ float pm[256];
  int t = threadIdx.x;
  for (int e = t; e < 384; e += 256) sw1[e] = w1[e];
  for (int e = t; e < 64 * OUT; e += 256) sw2[e] = w2[e];
  if (t < 64) sb1[t] = b1[t];
  if (t < OUT) sb2[t] = b2[t];
  int p0 = blockIdx.x * 16;
  int b = p0 >> 12;
  const float* fb = fin + (size_t)b * Nn * 3;
  for (int it = 0; it < 16; ++it) {
    int pt = p0 + it;
    __syncthreads();
    if (t < 20) sidx[t] = idx[(size_t)pt * KK + t];
    if (t >= 32 && t < 35) scen[t - 32] = fin[(size_t)pt * 3 + t - 32];
    __syncthreads();
    if (t < 60) { int k = t / 3, j = t - 3 * k; dn[t] = fb[(size_t)sidx[k] * 3 + j] - scen[j]; }
    if (t >= 64 && t < 128) { int c = t - 64; ccon[c] = scen[0] * sw1[c] + scen[1] * sw1[64 + c] + scen[2] * sw1[128 + c]; }
    __syncthreads();
    for (int o = t; o < 1280; o += 256) {
      int k = o >> 6, c = o & 63;
      float acc = sb1[c] + ccon[c];
      acc = fmaf(dn[k * 3 + 0], sw1[192 + c], acc);
      acc = fmaf(dn[k * 3 + 1], sw1[256 + c], acc);
      acc = fmaf(dn[k * 3 + 2], sw1[320 + c], acc);
      y1[o] = fmaxf(acc, 0.f);
    }
    __syncthreads();
    {
      constexpr int GR = 256 / OUT;
      int c = t & (OUT - 1), kg = t / OUT;
      float mx = -INFINITY;
      for (int k = kg; k < 20; k += GR) {
        const float* yk = y1 + (k << 6);
        float acc = 0.f;
#pragma unroll
        for (int j = 0; j < 64; ++j) acc = fmaf(yk[j], sw2[j * OUT + c], acc);
        mx = fmaxf(mx, acc);
      }
      pm[t] = mx;
    }
    __syncthreads();
    if (t < OUT) {
      float m = pm[t];
#pragma unroll
      for (int gr = 1; gr < 256 / OUT; ++gr) m = fmaxf(m, pm[gr * OUT + t]);
      fout[(size_t)pt * OUT + t] = fmaxf(m + sb2[t], 0.f);
    }
  }
}

// ---------------- edge conv, CF=64, 128->64->64, max over K ---------------
__global__ __launch_bounds__(256) void k_edgeC(const float* __restrict__ xin, const int* __restrict__ idx,
                                               const float* __restrict__ w1, const float* __restrict__ b1,
                                               const float* __restrict__ w2, const float* __restrict__ b2,
                                               float* __restrict__ xout) {
  __shared__ float sw1[8192];
  __shared__ float sw2[4096];
  __shared__ float sb1[64], sb2[64];
  __shared__ float scen[64], ccon[64];
  __shared__ int   sidx[20];
  __shared__ float dn[1280];
  __shared__ float y1[1280];
  __shared__ float pm[256];
  int t = threadIdx.x;
  for (int e = t; e < 8192; e += 256) sw1[e] = w1[e];
  for (int e = t; e < 4096; e += 256) sw2[e] = w2[e];
  if (t < 64) { sb1[t] = b1[t]; sb2[t] = b2[t]; }
  int p0 = blockIdx.x * 16;
  int b = p0 >> 12;
  const float* xbp = xin + (size_t)b * Nn * 64;
  for (int it = 0; it < 16; ++it) {
    int pt = p0 + it;
    __syncthreads();
    if (t < 20) sidx[t] = idx[(size_t)pt * KK + t];
    if (t >= 32 && t < 96) scen[t - 32] = xin[(size_t)pt * 64 + t - 32];
    __syncthreads();
    for (int e = t; e < 1280; e += 256) { int k = e >> 6, j = e & 63; dn[e] = xbp[(size_t)sidx[k] * 64 + j] - scen[j]; }
    if (t < 64) {
      float a = 0.f;
#pragma unroll
      for (int j = 0; j < 64; ++j) a = fmaf(scen[j], sw1[j * 64 + t], a);
      ccon[t] = a;
    }
    __syncthreads();
    for (int o = t; o < 1280; o += 256) {
      int k = o >> 6, c = o & 63;
      float acc = sb1[c] + ccon[c];
      const float* dk = dn + (k << 6);
#pragma unroll
      for (int j = 0; j < 64; ++j) acc = fmaf(dk[j], sw1[(64 + j) * 64 + c], acc);
      y1[o] = fmaxf(acc, 0.f);
    }
    __syncthreads();
    {
      int c = t & 63, kg = t >> 6;
      float mx = -INFINITY;
      for (int k = kg; k < 20; k += 4) {
        const float* yk = y1 + (k << 6);
        float acc = 0.f;
#pragma unroll
        for (int j = 0; j < 64; ++j) acc = fmaf(yk[j], sw2[j * 64 + c], acc);
        mx = fmaxf(mx, acc);
      }
      pm[t] = mx;
    }
    __syncthreads();
    if (t < 64) {
      float m = fmaxf(fmaxf(pm[t], pm[64 + t]), fmaxf(pm[128 + t], pm[192 + t]));
      xout[(size_t)pt * 64 + t] = fmaxf(m + sb2[t], 0.f);
    }
  }
}

// ---------------- edge conv, CF=64, 128->64 single, max over K ------------
__global__ __launch_bounds__(256) void k_edgeD(const float* __restrict__ xin, const int* __restrict__ idx,
                                               const float* __restrict__ w1, const float* __restrict__ b1,
                                               float* __restrict__ xout) {
  __shared__ float sw1[8192];
  __shared__ float sb1[64];
  __shared__ float scen[64], ccon[64];
  __shared__ int   sidx[20];
  __shared__ float dn[1280];
  __shared__ float zb[1280];
  int t = threadIdx.x;
  for (int e = t; e < 8192; e += 256) sw1[e] = w1[e];
  if (t < 64) sb1[t] = b1[t];
  int p0 = blockIdx.x * 16;
  int b = p0 >> 12;
  const float* xbp = xin + (size_t)b * Nn * 64;
  for (int it = 0; it < 16; ++it) {
    int pt = p0 + it;
    __syncthreads();
    if (t < 20) sidx[t] = idx[(size_t)pt * KK + t];
    if (t >= 32 && t < 96) scen[t - 32] = xin[(size_t)pt * 64 + t - 32];
    __syncthreads();
    for (int e = t; e < 1280; e += 256) { int k = e >> 6, j = e & 63; dn[e] = xbp[(size_t)sidx[k] * 64 + j] - scen[j]; }
    if (t < 64) {
      float a = 0.f;
#pragma unroll
      for (int j = 0; j < 64; ++j) a = fmaf(scen[j], sw1[j * 64 + t], a);
      ccon[t] = a;
    }
    __syncthreads();
    for (int o = t; o < 1280; o += 256) {
      int k = o >> 6, c = o & 63;
      float acc = ccon[c];
      const float* dk = dn + (k << 6);
#pragma unroll
      for (int j = 0; j < 64; ++j) acc = fmaf(dk[j], sw1[(64 + j) * 64 + c], acc);
      zb[o] = acc;
    }
    __syncthreads();
    if (t < 64) {
      float m = -INFINITY;
#pragma unroll
      for (int k = 0; k < 20; ++k) m = fmaxf(m, zb[(k << 6) + t]);
      xout[(size_t)pt * 64 + t] = fmaxf(m + sb1[t], 0.f);
    }
  }
}

// ---------------- t @ tw3, partial max over n-splits ----------------------
__global__ __launch_bounds__(256) void k_dpass1(const float* __restrict__ t128, const float* __restrict__ w3,
                                                float* __restrict__ dpart) {
  __shared__ float wc[8192];    // [j][c] 128x64
  __shared__ float rows[4096];  // 32 rows x 128
  __shared__ float pm[256];
  int t = threadIdx.x;
  int blk = blockIdx.x;
  int b = blk >> 7, cb = (blk >> 3) & 15, ns = blk & 7;
  for (int e = t; e < 8192; e += 256) { int j = e >> 6, c = e & 63; wc[e] = w3[(size_t)j * 1024 + cb * 64 + c]; }
  int c = t & 63, rg = t >> 6;
  float mx = -INFINITY;
  const float* tbase = t128 + ((size_t)b * Nn + ns * 512) * 128;
  for (int tile = 0; tile < 16; ++tile) {
    __syncthreads();
    const float4* src = (const float4*)(tbase + (size_t)tile * 32 * 128);
    float4* dst = (float4*)rows;
#pragma unroll
    for (int e = 0; e < 4; ++e) dst[t + 256 * e] = src[t + 256 * e];
    __syncthreads();
    for (int r = rg; r < 32; r += 4) {
      const float* row = rows + r * 128;
      float acc = 0.f;
#pragma unroll
      for (int j = 0; j < 128; ++j) acc = fmaf(row[j], wc[j * 64 + c], acc);
      mx = fmaxf(mx, acc);
    }
  }
  pm[t] = mx;
  __syncthreads();
  if (t < 64) {
    float m = fmaxf(fmaxf(pm[t], pm[64 + t]), fmaxf(pm[128 + t], pm[192 + t]));
    dpart[((size_t)b * 8 + ns) * 1024 + cb * 64 + t] = m;
  }
}

// ---------------- reduce partials + fc1 (1024->512) -----------------------
__global__ __launch_bounds__(256) void k_fc1(const float* __restrict__ dpart, const float* __restrict__ tb3,
                                             const float* __restrict__ tfw1, const float* __restrict__ tfb1,
                                             float* __restrict__ h1) {
  __shared__ float tv[1024];
  __shared__ float ps[256];
  int t = threadIdx.x;
  int b = blockIdx.x >> 3, cb = blockIdx.x & 7;
  for (int e = t; e < 1024; e += 256) {
    float m = -INFINITY;
#pragma unroll
    for (int s = 0; s < 8; ++s) m = fmaxf(m, dpart[((size_t)b * 8 + s) * 1024 + e]);
    tv[e] = fmaxf(m + tb3[e], 0.f);
  }
  __syncthreads();
  int c = cb * 64 + (t & 63), jg = t >> 6;
  float acc = 0.f;
  for (int j = jg * 256; j < jg * 256 + 256; ++j) acc = fmaf(tv[j], tfw1[(size_t)j * 512 + c], acc);
  ps[t] = acc;
  __syncthreads();
  if (t < 64) {
    float a = ps[t] + ps[64 + t] + ps[128 + t] + ps[192 + t] + tfb1[cb * 64 + t];
    h1[(size_t)b * 512 + cb * 64 + t] = fmaxf(a, 0.f);
  }
}

// ---------------- fc2, fc3 (transform), apply p = pts @ xf ----------------
__global__ __launch_bounds__(256) void k_fc23p(const float* __restrict__ h1, const float* __restrict__ tfw2,
                                               const float* __restrict__ tfb2, const float* __restrict__ txw,
                                               const float* __restrict__ txb, const float* __restrict__ pts,
                                               float* __restrict__ p) {
  __shared__ float sh1[512];
  __shared__ float h2[256];
  __shared__ float sxf[9];
  int t = threadIdx.x;
  int b = blockIdx.x;
  for (int e = t; e < 512; e += 256) sh1[e] = h1[(size_t)b * 512 + e];
  __syncthreads();
  {
    float acc = tfb2[t];
    for (int j = 0; j < 512; ++j) acc = fmaf(sh1[j], tfw2[(size_t)j * 256 + t], acc);
    h2[t] = fmaxf(acc, 0.f);
  }
  __syncthreads();
  if (t < 9) {
    float acc = txb[t];
    for (int j = 0; j < 256; ++j) acc = fmaf(h2[j], txw[j * 9 + t], acc);
    sxf[t] = acc;
  }
  __syncthreads();
  for (int n = t; n < Nn; n += 256) {
    const float* pr = pts + ((size_t)b * Nn + n) * 3;
    float a0 = pr[0], a1 = pr[1], a2 = pr[2];
    float* po = p + ((size_t)b * Nn + n) * 3;
#pragma unroll
    for (int d = 0; d < 3; ++d) po[d] = a0 * sxf[d] + a1 * sxf[3 + d] + a2 * sxf[6 + d];
  }
}

// ---------------- [x1,x2,x3] @ c1w, partial max over n-splits -------------
__global__ __launch_bounds__(256) void k_j1(const float* __restrict__ x1, const float* __restrict__ x2,
                                            const float* __restrict__ x3, const float* __restrict__ c1w,
                                            float* __restrict__ gpart) {
  __shared__ float wc[12288];   // 192x64
  __shared__ float rows[3072];  // 16 rows x 192
  __shared__ float pm[256];
  int t = threadIdx.x;
  int blk = blockIdx.x;
  int b = blk >> 7, cb = (blk >> 3) & 15, ns = blk & 7;
  for (int e = t; e < 12288; e += 256) { int j = e >> 6, c = e & 63; wc[e] = c1w[(size_t)j * 1024 + cb * 64 + c]; }
  int c = t & 63, rg = t >> 6;
  float mx = -INFINITY;
  size_t nbase = (size_t)b * Nn + ns * 512;
  for (int tile = 0; tile < 32; ++tile) {
    __syncthreads();
    int n0 = tile * 16;
    for (int e = t; e < 3072; e += 256) {
      int r = e / 192, j = e - 192 * r;
      size_t nn = nbase + n0 + r;
      float v = (j < 64) ? x1[nn * 64 + j] : (j < 128 ? x2[nn * 64 + j - 64] : x3[nn * 64 + j - 128]);
      rows[e] = v;
    }
    __syncthreads();
    for (int r = rg; r < 16; r += 4) {
      const float* row = rows + r * 192;
      float acc = 0.f;
#pragma unroll
      for (int j = 0; j < 192; ++j) acc = fmaf(row[j], wc[j * 64 + c], acc);
      mx = fmaxf(mx, acc);
    }
  }
  pm[t] = mx;
  __syncthreads();
  if (t < 64) {
    float m = fmaxf(fmaxf(pm[t], pm[64 + t]), fmaxf(pm[128 + t], pm[192 + t]));
    gpart[((size_t)b * 8 + ns) * 1024 + cb * 64 + t] = m;
  }
}

// ---------------- gc = relu(max+b) @ c2w[:1024] ---------------------------
__global__ __launch_bounds__(256) void k_j2(const float* __restrict__ gpart, const float* __restrict__ c1b,
                                            const float* __restrict__ c2w, float* __restrict__ gc) {
  __shared__ float g[1024];
  int t = threadIdx.x;
  int b = blockIdx.x >> 1, half = blockIdx.x & 1;
  for (int e = t; e < 1024; e += 256) {
    float m = -INFINITY;
#pragma unroll
    for (int s = 0; s < 8; ++s) m = fmaxf(m, gpart[((size_t)b * 8 + s) * 1024 + e]);
    g[e] = fmaxf(m + c1b[e], 0.f);
  }
  __syncthreads();
  int d = half * 256 + t;
  float acc = 0.f;
  for (int j = 0; j < 1024; ++j) acc = fmaf(g[j], c2w[(size_t)j * 512 + d], acc);
  gc[(size_t)b * 512 + d] = acc;
}

// ---------------- fused head: 192->512->256->2 per point ------------------
#define MT 16
__global__ __launch_bounds__(512) void k_final(const float* __restrict__ x1, const float* __restrict__ x2,
                                               const float* __restrict__ x3, const float* __restrict__ gc,
                                               const float* __restrict__ c2b, const float* __restrict__ c2wf,
                                               const float* __restrict__ c3w, const float* __restrict__ c3b,
                                               const float* __restrict__ c4w, const float* __restrict__ c4b,
                                               float* __restrict__ out) {
  __shared__ float ubuf[4096];       // sf[192][stride 20, MT cols] then z2[16][256]
  __shared__ float z5[512 * 20];     // z512 transposed [j][m], stride 20
  int t = threadIdx.x;
  int p0 = blockIdx.x * MT;
  int b = p0 >> 12;
  float* sf = ubuf;
  float* z2 = ubuf;
  // gather transposed features: sf[j*20+m], j<192 (x1|x2|x3), m<16
  for (int e = t; e < 768; e += 512) {
    int a = e >> 8, rem = e & 255, m = rem >> 4, ch = rem & 15;
    const float* src = (a == 0 ? x1 : a == 1 ? x2 : x3) + ((size_t)(p0 + m)) * 64 + ch * 4;
    float4 v = *(const float4*)src;
    int jb = a * 64 + ch * 4;
    sf[(jb + 0) * 20 + m] = v.x; sf[(jb + 1) * 20 + m] = v.y;
    sf[(jb + 2) * 20 + m] = v.z; sf[(jb + 3) * 20 + m] = v.w;
  }
  __syncthreads();
  {
    float acc[MT];
    float base0 = gc[(size_t)b * 512 + t] + c2b[t];
#pragma unroll
    for (int m = 0; m < MT; ++m) acc[m] = base0;
    for (int j = 0; j < 192; ++j) {
      float wj = c2wf[(size_t)j * 512 + t];
      const float* sr = sf + j * 20;
#pragma unroll
      for (int m = 0; m < MT; ++m) acc[m] = fmaf(sr[m], wj, acc[m]);
    }
    float* zr = z5 + t * 20;
#pragma unroll
    for (int m = 0; m < MT; ++m) zr[m] = fmaxf(acc[m], 0.f);
  }
  __syncthreads();
  {
    int d2 = t & 255, mh = t >> 8;
    float acc[8];
    float bb = c3b[d2];
#pragma unroll
    for (int i = 0; i < 8; ++i) acc[i] = bb;
    for (int j = 0; j < 512; ++j) {
      float wj = c3w[(size_t)j * 256 + d2];
      const float* zr = z5 + j * 20 + mh * 8;
#pragma unroll
      for (int i = 0; i < 8; ++i) acc[i] = fmaf(zr[i], wj, acc[i]);
    }
#pragma unroll
    for (int i = 0; i < 8; ++i) z2[(mh * 8 + i) * 256 + d2] = fmaxf(acc[i], 0.f);
  }
  __syncthreads();
  if (t < MT * 2) {
    int m = t >> 1, e = t & 1;
    float acc = c4b[e];
    const float* zr = z2 + m * 256;
    for (int j = 0; j < 256; ++j) acc = fmaf(zr[j], c4w[j * 2 + e], acc);
    out[(size_t)(p0 + m) * 2 + e] = acc;
  }
}

// ===========================================================================
extern "C" void kernel_launch(void* const* d_in, const int* in_sizes, int n_in,
                              void* d_out, int out_size, void* d_ws, size_t ws_size,
                              hipStream_t stream) {
  const float* xin = (const float*)d_in[0];
  const float* W[30];
  for (int i = 0; i < 30; ++i) W[i] = (const float*)d_in[i + 1];

  float* ws = (float*)d_ws;
  size_t off = 0;
  float* pts   = ws + off; off += (size_t)BN * 3;
  float* p     = ws + off; off += (size_t)BN * 3;
  int*   idx   = (int*)(ws + off); off += (size_t)BN * KK;
  float* sq    = ws + off; off += BN;
  float* t128  = ws + off; off += (size_t)BN * 128;
  float* dpart = ws + off; off += 4 * 8 * 1024;
  float* h1    = ws + off; off += 4 * 512;
  float* x1    = ws + off; off += (size_t)BN * 64;
  float* x2    = ws + off; off += (size_t)BN * 64;
  float* x3    = ws + off; off += (size_t)BN * 64;
  float* gpart = ws + off; off += 4 * 8 * 1024;
  float* gc    = ws + off; off += 4 * 512;

  k_pts<<<dim3(192), dim3(256), 0, stream>>>(xin, pts);

  // stage 1: transform branch
  k_knn3<<<dim3(256), dim3(256), 0, stream>>>(pts, idx);
  k_edge3<128><<<dim3(1024), dim3(256), 0, stream>>>(pts, idx, W[0], W[1], W[2], W[3], t128);
  k_dpass1<<<dim3(512), dim3(256), 0, stream>>>(t128, W[4], dpart);
  k_fc1<<<dim3(32), dim3(256), 0, stream>>>(dpart, W[5], W[6], W[7], h1);
  k_fc23p<<<dim3(4), dim3(256), 0, stream>>>(h1, W[8], W[9], W[10], W[11], pts, p);

  // stage 2: edge convs on transformed points / features
  k_knn3<<<dim3(256), dim3(256), 0, stream>>>(p, idx);
  k_edge3<64><<<dim3(1024), dim3(256), 0, stream>>>(p, idx, W[12], W[13], W[14], W[15], x1);
  k_sqnorm<<<dim3(64), dim3(256), 0, stream>>>(x1, sq);
  k_knn64<<<dim3(512), dim3(256), 0, stream>>>(x1, sq, idx);
  k_edgeC<<<dim3(1024), dim3(256), 0, stream>>>(x1, idx, W[16], W[17], W[18], W[19], x2);
  k_sqnorm<<<dim3(64), dim3(256), 0, stream>>>(x2, sq);
  k_knn64<<<dim3(512), dim3(256), 0, stream>>>(x2, sq, idx);
  k_edgeD<<<dim3(1024), dim3(256), 0, stream>>>(x2, idx, W[20], W[21], x3);

  // stage 3: global feature + head
  k_j1<<<dim3(512), dim3(256), 0, stream>>>(x1, x2, x3, W[22], gpart);
  k_j2<<<dim3(8), dim3(256), 0, stream>>>(gpart, W[23], W[24], gc);
  k_final<<<dim3(1024), dim3(512), 0, stream>>>(x1, x2, x3, gc, W[25], W[24] + 1024 * 512,
                                                W[26], W[27], W[28], W[29],
                                                (float*)d_out);
}

// Round 3
// 2662.954 us; speedup vs baseline: 2.2533x; 2.2533x over previous
//
#include <hip/hip_runtime.h>

#define Nn 4096
#define KK 20
#define BN 16384   // B*N, B=4

// ---------------- extract pts = x[:,:,:3] ---------------------------------
__global__ void k_pts(const float* __restrict__ x, float* __restrict__ pts) {
  int i = blockIdx.x * 256 + threadIdx.x;
  if (i < BN * 3) {
    int pt = i / 3, c = i - 3 * pt;
    pts[i] = x[pt * 6 + c];
  }
}

// ---------------- exact top-20 selection, one wave per query ---------------
// d[64]: lane's distances for candidates t*64+lane. (m1,t1)=(best,(tile)),
// (m2,t2)=second best. Total order: (val desc, global idx asc) — matches
// lax.top_k tie semantics. 20 rounds of shfl-xor butterfly argmax; winner
// lane shifts its top-2; rescan (rare, ~3/query) uses a removed-bitmask so
// d[] stays in registers (no dynamic register writes).
__device__ __forceinline__ void topk_select(const float (&d)[64], float m1, int t1, float m2, int t2,
                                            int lane, int* __restrict__ op) {
  unsigned long long removed = 0ull;
  bool have2 = true;
  int sel = 0;
#pragma unroll 1
  for (int k = 0; k < 20; ++k) {
    float v = m1; int ci = (t1 << 6) | lane;
#pragma unroll
    for (int off = 32; off; off >>= 1) {
      float ov = __shfl_xor(v, off, 64);
      int   oi = __shfl_xor(ci, off, 64);
      if (ov > v || (ov == v && oi < ci)) { v = ov; ci = oi; }
    }
    if (k == lane) sel = ci;
    if ((ci & 63) == lane) {          // this lane's m1 was selected
      removed |= 1ull << t1;
      if (have2) { m1 = m2; t1 = t2; have2 = false; }
      else {
        m1 = -INFINITY; t1 = 0; m2 = -INFINITY; t2 = 0;
#pragma unroll
        for (int tt = 0; tt < 64; ++tt) {
          if (!((removed >> tt) & 1ull)) {
            float dv = d[tt];
            if (dv > m1) { m2 = m1; t2 = t1; m1 = dv; t1 = tt; }
            else if (dv > m2) { m2 = dv; t2 = tt; }
          }
        }
        have2 = true;
      }
    }
  }
  if (lane < 20) op[lane] = sel;
}

// ---------------- kNN, C=3: 1024 thr = 16 waves = 16 queries --------------
__global__ __launch_bounds__(1024) void k_knn3(const float* __restrict__ src, int* __restrict__ idx) {
  __shared__ float tile[Nn * 3];   // 48 KB: whole batch's points
  int t = threadIdx.x;
  int wave = t >> 6, lane = t & 63;
  int g = blockIdx.x * 16 + wave;
  int b = g >> 12, n = g & (Nn - 1);
  const float* base = src + (size_t)b * Nn * 3;
  for (int e = t; e < Nn * 3; e += 1024) tile[e] = base[e];
  __syncthreads();
  float qx = tile[n * 3 + 0], qy = tile[n * 3 + 1], qz = tile[n * 3 + 2];
  float qsq = qx * qx + qy * qy + qz * qz;
  float d[64];
  float m1 = -INFINITY, m2 = -INFINITY; int t1 = 0, t2 = 0;
#pragma unroll
  for (int tt = 0; tt < 64; ++tt) {
    int c = (tt << 6) + lane;
    float mx = tile[c * 3], my = tile[c * 3 + 1], mz = tile[c * 3 + 2];
    float msq = mx * mx + my * my + mz * mz;
    float dd = 2.0f * (qx * mx + qy * my + qz * mz) - qsq - msq;
    d[tt] = dd;
    if (dd > m1) { m2 = m1; t2 = t1; m1 = dd; t1 = tt; }
    else if (dd > m2) { m2 = dd; t2 = tt; }
  }
  topk_select(d, m1, t1, m2, t2, lane, idx + (size_t)g * KK);
}

// ---------------- sq norms for 64-dim features ----------------------------
__global__ void k_sqnorm(const float* __restrict__ src, float* __restrict__ out) {
  int g = blockIdx.x * 256 + threadIdx.x;
  if (g >= BN) return;
  const float4* r = (const float4*)(src + (size_t)g * 64);
  float s = 0.f;
#pragma unroll
  for (int j = 0; j < 16; ++j) { float4 v = r[j]; s += v.x * v.x + v.y * v.y + v.z * v.z + v.w * v.w; }
  out[g] = s;
}

// ---------------- kNN, C=64: 256 thr = 4 waves = 4 queries ----------------
__global__ __launch_bounds__(256) void k_knn64(const float* __restrict__ src, const float* __restrict__ sqb,
                                               int* __restrict__ idx) {
  __shared__ float tile[64 * 68];   // 64 cand x 64 ch, stride 68 (16B aligned)
  __shared__ float tsq[64];
  int t = threadIdx.x;
  int wave = t >> 6, lane = t & 63;
  int g = blockIdx.x * 4 + wave;
  int b = g >> 12, n = g & (Nn - 1);
  const float* base = src + (size_t)b * Nn * 64;
  float q[64];
  const float4* qrow = (const float4*)(base + (size_t)n * 64);
#pragma unroll
  for (int j = 0; j < 16; ++j) {
    float4 v = qrow[j];
    q[4 * j] = v.x; q[4 * j + 1] = v.y; q[4 * j + 2] = v.z; q[4 * j + 3] = v.w;
  }
  float qsq = sqb[g];
  float d[64];
  float m1 = -INFINITY, m2 = -INFINITY; int t1 = 0, t2 = 0;
#pragma unroll
  for (int tb = 0; tb < 64; ++tb) {
    __syncthreads();
    const float4* tsrc = (const float4*)(base + (size_t)tb * 4096);
#pragma unroll
    for (int e = 0; e < 4; ++e) {
      int f = t + 256 * e;
      int row = f >> 4, col = f & 15;
      *((float4*)(tile + row * 68) + col) = tsrc[f];
    }
    if (t < 64) tsq[t] = sqb[b * Nn + (tb << 6) + t];
    __syncthreads();
    const float* mrow = tile + lane * 68;
    float dot = 0.f;
#pragma unroll
    for (int j = 0; j < 64; ++j) dot = fmaf(q[j], mrow[j], dot);
    float dd = 2.0f * dot - qsq - tsq[lane];
    d[tb] = dd;
    if (dd > m1) { m2 = m1; t2 = t1; m1 = dd; t1 = tb; }
    else if (dd > m2) { m2 = dd; t2 = tb; }
  }
  topk_select(d, m1, t1, m2, t2, lane, idx + (size_t)g * KK);
}

// ---------------- edge conv, CF=3, 6->64->OUT, max over K -----------------
template <int OUT>
__global__ __launch_bounds__(256) void k_edge3(const float* __restrict__ fin, const int* __restrict__ idx,
                                               const float* __restrict__ w1, const float* __restrict__ b1,
                                               const float* __restrict__ w2, const float* __restrict__ b2,
                                               float* __restrict__ fout) {
  __shared__ float sw1[384];
  __shared__ float sw2[64 * OUT];
  __shared__ float sb1[64], sb2[OUT];
  __shared__ float scen[3];
  __shared__ float ccon[64];
  __shared__ int   sidx[20];
  __shared__ float dn[60];
  __shared__ float y1[1280];
  __shared__ float pm[256];
  int t = threadIdx.x;
  for (int e = t; e < 384; e += 256) sw1[e] = w1[e];
  for (int e = t; e < 64 * OUT; e += 256) sw2[e] = w2[e];
  if (t < 64) sb1[t] = b1[t];
  if (t < OUT) sb2[t] = b2[t];
  int p0 = blockIdx.x * 16;
  int b = p0 >> 12;
  const float* fb = fin + (size_t)b * Nn * 3;
  for (int it = 0; it < 16; ++it) {
    int pt = p0 + it;
    __syncthreads();
    if (t < 20) sidx[t] = idx[(size_t)pt * KK + t];
    if (t >= 32 && t < 35) scen[t - 32] = fin[(size_t)pt * 3 + t - 32];
    __syncthreads();
    if (t < 60) { int k = t / 3, j = t - 3 * k; dn[t] = fb[(size_t)sidx[k] * 3 + j] - scen[j]; }
    if (t >= 64 && t < 128) { int c = t - 64; ccon[c] = scen[0] * sw1[c] + scen[1] * sw1[64 + c] + scen[2] * sw1[128 + c]; }
    __syncthreads();
    for (int o = t; o < 1280; o += 256) {
      int k = o >> 6, c = o & 63;
      float acc = sb1[c] + ccon[c];
      acc = fmaf(dn[k * 3 + 0], sw1[192 + c], acc);
      acc = fmaf(dn[k * 3 + 1], sw1[256 + c], acc);
      acc = fmaf(dn[k * 3 + 2], sw1[320 + c], acc);
      y1[o] = fmaxf(acc, 0.f);
    }
    __syncthreads();
    {
      constexpr int GR = 256 / OUT;
      int c = t & (OUT - 1), kg = t / OUT;
      float mx = -INFINITY;
      for (int k = kg; k < 20; k += GR) {
        const float* yk = y1 + (k << 6);
        float acc = 0.f;
#pragma unroll
        for (int j = 0; j < 64; ++j) acc = fmaf(yk[j], sw2[j * OUT + c], acc);
        mx = fmaxf(mx, acc);
      }
      pm[t] = mx;
    }
    __syncthreads();
    if (t < OUT) {
      float m = pm[t];
#pragma unroll
      for (int gr = 1; gr < 256 / OUT; ++gr) m = fmaxf(m, pm[gr * OUT + t]);
      fout[(size_t)pt * OUT + t] = fmaxf(m + sb2[t], 0.f);
    }
  }
}

// ---------------- edge conv, CF=64, 128->64->64, max over K ---------------
__global__ __launch_bounds__(256) void k_edgeC(const float* __restrict__ xin, const int* __restrict__ idx,
                                               const float* __restrict__ w1, const float* __restrict__ b1,
                                               const float* __restrict__ w2, const float* __restrict__ b2,
                                               float* __restrict__ xout) {
  __shared__ float sw1[8192];
  __shared__ float sw2[4096];
  __shared__ float sb1[64], sb2[64];
  __shared__ float scen[64], ccon[64];
  __shared__ int   sidx[20];
  __shared__ float dn[1280];
  __shared__ float y1[1280];
  __shared__ float pm[256];
  int t = threadIdx.x;
  for (int e = t; e < 8192; e += 256) sw1[e] = w1[e];
  for (int e = t; e < 4096; e += 256) sw2[e] = w2[e];
  if (t < 64) { sb1[t] = b1[t]; sb2[t] = b2[t]; }
  int p0 = blockIdx.x * 16;
  int b = p0 >> 12;
  const float* xbp = xin + (size_t)b * Nn * 64;
  for (int it = 0; it < 16; ++it) {
    int pt = p0 + it;
    __syncthreads();
    if (t < 20) sidx[t] = idx[(size_t)pt * KK + t];
    if (t >= 32 && t < 96) scen[t - 32] = xin[(size_t)pt * 64 + t - 32];
    __syncthreads();
    for (int e = t; e < 1280; e += 256) { int k = e >> 6, j = e & 63; dn[e] = xbp[(size_t)sidx[k] * 64 + j] - scen[j]; }
    if (t < 64) {
      float a = 0.f;
#pragma unroll
      for (int j = 0; j < 64; ++j) a = fmaf(scen[j], sw1[j * 64 + t], a);
      ccon[t] = a;
    }
    __syncthreads();
    for (int o = t; o < 1280; o += 256) {
      int k = o >> 6, c = o & 63;
      float acc = sb1[c] + ccon[c];
      const float* dk = dn + (k << 6);
#pragma unroll
      for (int j = 0; j < 64; ++j) acc = fmaf(dk[j], sw1[(64 + j) * 64 + c], acc);
      y1[o] = fmaxf(acc, 0.f);
    }
    __syncthreads();
    {
      int c = t & 63, kg = t >> 6;
      float mx = -INFINITY;
      for (int k = kg; k < 20; k += 4) {
        const float* yk = y1 + (k << 6);
        float acc = 0.f;
#pragma unroll
        for (int j = 0; j < 64; ++j) acc = fmaf(yk[j], sw2[j * 64 + c], acc);
        mx = fmaxf(mx, acc);
      }
      pm[t] = mx;
    }
    __syncthreads();
    if (t < 64) {
      float m = fmaxf(fmaxf(pm[t], pm[64 + t]), fmaxf(pm[128 + t], pm[192 + t]));
      xout[(size_t)pt * 64 + t] = fmaxf(m + sb2[t], 0.f);
    }
  }
}

// ---------------- edge conv, CF=64, 128->64 single, max over K ------------
__global__ __launch_bounds__(256) void k_edgeD(const float* __restrict__ xin, const int* __restrict__ idx,
                                               const float* __restrict__ w1, const float* __restrict__ b1,
                                               float* __restrict__ xout) {
  __shared__ float sw1[8192];
  __shared__ float sb1[64];
  __shared__ float scen[64], ccon[64];
  __shared__ int   sidx[20];
  __shared__ float dn[1280];
  __shared__ float zb[1280];
  int t = threadIdx.x;
  for (int e = t; e < 8192; e += 256) sw1[e] = w1[e];
  if (t < 64) sb1[t] = b1[t];
  int p0 = blockIdx.x * 16;
  int b = p0 >> 12;
  const float* xbp = xin + (size_t)b * Nn * 64;
  for (int it = 0; it < 16; ++it) {
    int pt = p0 + it;
    __syncthreads();
    if (t < 20) sidx[t] = idx[(size_t)pt * KK + t];
    if (t >= 32 && t < 96) scen[t - 32] = xin[(size_t)pt * 64 + t - 32];
    __syncthreads();
    for (int e = t; e < 1280; e += 256) { int k = e >> 6, j = e & 63; dn[e] = xbp[(size_t)sidx[k] * 64 + j] - scen[j]; }
    if (t < 64) {
      float a = 0.f;
#pragma unroll
      for (int j = 0; j < 64; ++j) a = fmaf(scen[j], sw1[j * 64 + t], a);
      ccon[t] = a;
    }
    __syncthreads();
    for (int o = t; o < 1280; o += 256) {
      int k = o >> 6, c = o & 63;
      float acc = ccon[c];
      const float* dk = dn + (k << 6);
#pragma unroll
      for (int j = 0; j < 64; ++j) acc = fmaf(dk[j], sw1[(64 + j) * 64 + c], acc);
      zb[o] = acc;
    }
    __syncthreads();
    if (t < 64) {
      float m = -INFINITY;
#pragma unroll
      for (int k = 0; k < 20; ++k) m = fmaxf(m, zb[(k << 6) + t]);
      xout[(size_t)pt * 64 + t] = fmaxf(m + sb1[t], 0.f);
    }
  }
}

// ---------------- t @ tw3, partial max over n-splits ----------------------
__global__ __launch_bounds__(256) void k_dpass1(const float* __restrict__ t128, const float* __restrict__ w3,
                                                float* __restrict__ dpart) {
  __shared__ float wc[8192];    // [j][c] 128x64
  __shared__ float rows[4096];  // 32 rows x 128
  __shared__ float pm[256];
  int t = threadIdx.x;
  int blk = blockIdx.x;
  int b = blk >> 7, cb = (blk >> 3) & 15, ns = blk & 7;
  for (int e = t; e < 8192; e += 256) { int j = e >> 6, c = e & 63; wc[e] = w3[(size_t)j * 1024 + cb * 64 + c]; }
  int c = t & 63, rg = t >> 6;
  float mx = -INFINITY;
  const float* tbase = t128 + ((size_t)b * Nn + ns * 512) * 128;
  for (int tile = 0; tile < 16; ++tile) {
    __syncthreads();
    const float4* src = (const float4*)(tbase + (size_t)tile * 32 * 128);
    float4* dst = (float4*)rows;
#pragma unroll
    for (int e = 0; e < 4; ++e) dst[t + 256 * e] = src[t + 256 * e];
    __syncthreads();
    for (int r = rg; r < 32; r += 4) {
      const float* row = rows + r * 128;
      float acc = 0.f;
#pragma unroll
      for (int j = 0; j < 128; ++j) acc = fmaf(row[j], wc[j * 64 + c], acc);
      mx = fmaxf(mx, acc);
    }
  }
  pm[t] = mx;
  __syncthreads();
  if (t < 64) {
    float m = fmaxf(fmaxf(pm[t], pm[64 + t]), fmaxf(pm[128 + t], pm[192 + t]));
    dpart[((size_t)b * 8 + ns) * 1024 + cb * 64 + t] = m;
  }
}

// ---------------- reduce partials + fc1 (1024->512) -----------------------
__global__ __launch_bounds__(256) void k_fc1(const float* __restrict__ dpart, const float* __restrict__ tb3,
                                             const float* __restrict__ tfw1, const float* __restrict__ tfb1,
                                             float* __restrict__ h1) {
  __shared__ float tv[1024];
  __shared__ float ps[256];
  int t = threadIdx.x;
  int b = blockIdx.x >> 3, cb = blockIdx.x & 7;
  for (int e = t; e < 1024; e += 256) {
    float m = -INFINITY;
#pragma unroll
    for (int s = 0; s < 8; ++s) m = fmaxf(m, dpart[((size_t)b * 8 + s) * 1024 + e]);
    tv[e] = fmaxf(m + tb3[e], 0.f);
  }
  __syncthreads();
  int c = cb * 64 + (t & 63), jg = t >> 6;
  float acc = 0.f;
  for (int j = jg * 256; j < jg * 256 + 256; ++j) acc = fmaf(tv[j], tfw1[(size_t)j * 512 + c], acc);
  ps[t] = acc;
  __syncthreads();
  if (t < 64) {
    float a = ps[t] + ps[64 + t] + ps[128 + t] + ps[192 + t] + tfb1[cb * 64 + t];
    h1[(size_t)b * 512 + cb * 64 + t] = fmaxf(a, 0.f);
  }
}

// ---------------- fc2, fc3 (transform), apply p = pts @ xf ----------------
__global__ __launch_bounds__(256) void k_fc23p(const float* __restrict__ h1, const float* __restrict__ tfw2,
                                               const float* __restrict__ tfb2, const float* __restrict__ txw,
                                               const float* __restrict__ txb, const float* __restrict__ pts,
                                               float* __restrict__ p) {
  __shared__ float sh1[512];
  __shared__ float h2[256];
  __shared__ float sxf[9];
  int t = threadIdx.x;
  int b = blockIdx.x;
  for (int e = t; e < 512; e += 256) sh1[e] = h1[(size_t)b * 512 + e];
  __syncthreads();
  {
    float acc = tfb2[t];
    for (int j = 0; j < 512; ++j) acc = fmaf(sh1[j], tfw2[(size_t)j * 256 + t], acc);
    h2[t] = fmaxf(acc, 0.f);
  }
  __syncthreads();
  if (t < 9) {
    float acc = txb[t];
    for (int j = 0; j < 256; ++j) acc = fmaf(h2[j], txw[j * 9 + t], acc);
    sxf[t] = acc;
  }
  __syncthreads();
  for (int n = t; n < Nn; n += 256) {
    const float* pr = pts + ((size_t)b * Nn + n) * 3;
    float a0 = pr[0], a1 = pr[1], a2 = pr[2];
    float* po = p + ((size_t)b * Nn + n) * 3;
#pragma unroll
    for (int d = 0; d < 3; ++d) po[d] = a0 * sxf[d] + a1 * sxf[3 + d] + a2 * sxf[6 + d];
  }
}

// ---------------- [x1,x2,x3] @ c1w, partial max over n-splits -------------
__global__ __launch_bounds__(256) void k_j1(const float* __restrict__ x1, const float* __restrict__ x2,
                                            const float* __restrict__ x3, const float* __restrict__ c1w,
                                            float* __restrict__ gpart) {
  __shared__ float wc[12288];   // 192x64
  __shared__ float rows[3072];  // 16 rows x 192
  __shared__ float pm[256];
  int t = threadIdx.x;
  int blk = blockIdx.x;
  int b = blk >> 7, cb = (blk >> 3) & 15, ns = blk & 7;
  for (int e = t; e < 12288; e += 256) { int j = e >> 6, c = e & 63; wc[e] = c1w[(size_t)j * 1024 + cb * 64 + c]; }
  int c = t & 63, rg = t >> 6;
  float mx = -INFINITY;
  size_t nbase = (size_t)b * Nn + ns * 512;
  for (int tile = 0; tile < 32; ++tile) {
    __syncthreads();
    int n0 = tile * 16;
    for (int e = t; e < 3072; e += 256) {
      int r = e / 192, j = e - 192 * r;
      size_t nn = nbase + n0 + r;
      float v = (j < 64) ? x1[nn * 64 + j] : (j < 128 ? x2[nn * 64 + j - 64] : x3[nn * 64 + j - 128]);
      rows[e] = v;
    }
    __syncthreads();
    for (int r = rg; r < 16; r += 4) {
      const float* row = rows + r * 192;
      float acc = 0.f;
#pragma unroll
      for (int j = 0; j < 192; ++j) acc = fmaf(row[j], wc[j * 64 + c], acc);
      mx = fmaxf(mx, acc);
    }
  }
  pm[t] = mx;
  __syncthreads();
  if (t < 64) {
    float m = fmaxf(fmaxf(pm[t], pm[64 + t]), fmaxf(pm[128 + t], pm[192 + t]));
    gpart[((size_t)b * 8 + ns) * 1024 + cb * 64 + t] = m;
  }
}

// ---------------- gc = relu(max+b) @ c2w[:1024] ---------------------------
__global__ __launch_bounds__(256) void k_j2(const float* __restrict__ gpart, const float* __restrict__ c1b,
                                            const float* __restrict__ c2w, float* __restrict__ gc) {
  __shared__ float g[1024];
  int t = threadIdx.x;
  int b = blockIdx.x >> 1, half = blockIdx.x & 1;
  for (int e = t; e < 1024; e += 256) {
    float m = -INFINITY;
#pragma unroll
    for (int s = 0; s < 8; ++s) m = fmaxf(m, gpart[((size_t)b * 8 + s) * 1024 + e]);
    g[e] = fmaxf(m + c1b[e], 0.f);
  }
  __syncthreads();
  int d = half * 256 + t;
  float acc = 0.f;
  for (int j = 0; j < 1024; ++j) acc = fmaf(g[j], c2w[(size_t)j * 512 + d], acc);
  gc[(size_t)b * 512 + d] = acc;
}

// ---------------- fused head: 192->512->256->2 per point ------------------
#define MT 16
__global__ __launch_bounds__(512) void k_final(const float* __restrict__ x1, const float* __restrict__ x2,
                                               const float* __restrict__ x3, const float* __restrict__ gc,
                                               const float* __restrict__ c2b, const float* __restrict__ c2wf,
                                               const float* __restrict__ c3w, const float* __restrict__ c3b,
                                               const float* __restrict__ c4w, const float* __restrict__ c4b,
                                               float* __restrict__ out) {
  __shared__ float ubuf[4096];       // sf[192][stride 20, MT cols] then z2[16][256]
  __shared__ float z5[512 * 20];     // z512 transposed [j][m], stride 20
  int t = threadIdx.x;
  int p0 = blockIdx.x * MT;
  int b = p0 >> 12;
  float* sf = ubuf;
  float* z2 = ubuf;
  // gather transposed features: sf[j*20+m], j<192 (x1|x2|x3), m<16
  for (int e = t; e < 768; e += 512) {
    int a = e >> 8, rem = e & 255, m = rem >> 4, ch = rem & 15;
    const float* src = (a == 0 ? x1 : a == 1 ? x2 : x3) + ((size_t)(p0 + m)) * 64 + ch * 4;
    float4 v = *(const float4*)src;
    int jb = a * 64 + ch * 4;
    sf[(jb + 0) * 20 + m] = v.x; sf[(jb + 1) * 20 + m] = v.y;
    sf[(jb + 2) * 20 + m] = v.z; sf[(jb + 3) * 20 + m] = v.w;
  }
  __syncthreads();
  {
    float acc[MT];
    float base0 = gc[(size_t)b * 512 + t] + c2b[t];
#pragma unroll
    for (int m = 0; m < MT; ++m) acc[m] = base0;
    for (int j = 0; j < 192; ++j) {
      float wj = c2wf[(size_t)j * 512 + t];
      const float* sr = sf + j * 20;
#pragma unroll
      for (int m = 0; m < MT; ++m) acc[m] = fmaf(sr[m], wj, acc[m]);
    }
    float* zr = z5 + t * 20;
#pragma unroll
    for (int m = 0; m < MT; ++m) zr[m] = fmaxf(acc[m], 0.f);
  }
  __syncthreads();
  {
    int d2 = t & 255, mh = t >> 8;
    float acc[8];
    float bb = c3b[d2];
#pragma unroll
    for (int i = 0; i < 8; ++i) acc[i] = bb;
    for (int j = 0; j < 512; ++j) {
      float wj = c3w[(size_t)j * 256 + d2];
      const float* zr = z5 + j * 20 + mh * 8;
#pragma unroll
      for (int i = 0; i < 8; ++i) acc[i] = fmaf(zr[i], wj, acc[i]);
    }
#pragma unroll
    for (int i = 0; i < 8; ++i) z2[(mh * 8 + i) * 256 + d2] = fmaxf(acc[i], 0.f);
  }
  __syncthreads();
  if (t < MT * 2) {
    int m = t >> 1, e = t & 1;
    float acc = c4b[e];
    const float* zr = z2 + m * 256;
    for (int j = 0; j < 256; ++j) acc = fmaf(zr[j], c4w[j * 2 + e], acc);
    out[(size_t)(p0 + m) * 2 + e] = acc;
  }
}

// ===========================================================================
extern "C" void kernel_launch(void* const* d_in, const int* in_sizes, int n_in,
                              void* d_out, int out_size, void* d_ws, size_t ws_size,
                              hipStream_t stream) {
  const float* xin = (const float*)d_in[0];
  const float* W[30];
  for (int i = 0; i < 30; ++i) W[i] = (const float*)d_in[i + 1];

  float* ws = (float*)d_ws;
  size_t off = 0;
  float* pts   = ws + off; off += (size_t)BN * 3;
  float* p     = ws + off; off += (size_t)BN * 3;
  int*   idx   = (int*)(ws + off); off += (size_t)BN * KK;
  float* sq    = ws + off; off += BN;
  float* t128  = ws + off; off += (size_t)BN * 128;
  float* dpart = ws + off; off += 4 * 8 * 1024;
  float* h1    = ws + off; off += 4 * 512;
  float* x1    = ws + off; off += (size_t)BN * 64;
  float* x2    = ws + off; off += (size_t)BN * 64;
  float* x3    = ws + off; off += (size_t)BN * 64;
  float* gpart = ws + off; off += 4 * 8 * 1024;
  float* gc    = ws + off; off += 4 * 512;

  k_pts<<<dim3(192), dim3(256), 0, stream>>>(xin, pts);

  // stage 1: transform branch
  k_knn3<<<dim3(1024), dim3(1024), 0, stream>>>(pts, idx);
  k_edge3<128><<<dim3(1024), dim3(256), 0, stream>>>(pts, idx, W[0], W[1], W[2], W[3], t128);
  k_dpass1<<<dim3(512), dim3(256), 0, stream>>>(t128, W[4], dpart);
  k_fc1<<<dim3(32), dim3(256), 0, stream>>>(dpart, W[5], W[6], W[7], h1);
  k_fc23p<<<dim3(4), dim3(256), 0, stream>>>(h1, W[8], W[9], W[10], W[11], pts, p);

  // stage 2: edge convs on transformed points / features
  k_knn3<<<dim3(1024), dim3(1024), 0, stream>>>(p, idx);
  k_edge3<64><<<dim3(1024), dim3(256), 0, stream>>>(p, idx, W[12], W[13], W[14], W[15], x1);
  k_sqnorm<<<dim3(64), dim3(256), 0, stream>>>(x1, sq);
  k_knn64<<<dim3(4096), dim3(256), 0, stream>>>(x1, sq, idx);
  k_edgeC<<<dim3(1024), dim3(256), 0, stream>>>(x1, idx, W[16], W[17], W[18], W[19], x2);
  k_sqnorm<<<dim3(64), dim3(256), 0, stream>>>(x2, sq);
  k_knn64<<<dim3(4096), dim3(256), 0, stream>>>(x2, sq, idx);
  k_edgeD<<<dim3(1024), dim3(256), 0, stream>>>(x2, idx, W[20], W[21], x3);

  // stage 3: global feature + head
  k_j1<<<dim3(512), dim3(256), 0, stream>>>(x1, x2, x3, W[22], gpart);
  k_j2<<<dim3(8), dim3(256), 0, stream>>>(gpart, W[23], W[24], gc);
  k_final<<<dim3(1024), dim3(512), 0, stream>>>(x1, x2, x3, gc, W[25], W[24] + 1024 * 512,
                                                W[26], W[27], W[28], W[29],
                                                (float*)d_out);
}

// Round 4
// 2576.268 us; speedup vs baseline: 2.3291x; 1.0336x over previous
//
#include <hip/hip_runtime.h>

#define Nn 4096
#define KK 20
#define BN 16384   // B*N, B=4

// ---------------- extract pts = x[:,:,:3] ---------------------------------
__global__ void k_pts(const float* __restrict__ x, float* __restrict__ pts) {
  int i = blockIdx.x * 256 + threadIdx.x;
  if (i < BN * 3) {
    int pt = i / 3, c = i - 3 * pt;
    pts[i] = x[pt * 6 + c];
  }
}

// ---------------- exact top-20 selection, one wave per query ---------------
// d[64]: lane's distances, candidate global index = (tt<<6)|lane (knn3 variant).
// Total order: (val desc, global idx asc) — matches lax.top_k tie semantics.
__device__ __forceinline__ void topk_select(const float (&d)[64], float m1, int t1, float m2, int t2,
                                            int lane, int* __restrict__ op) {
  unsigned long long removed = 0ull;
  bool have2 = true;
  int sel = 0;
#pragma unroll 1
  for (int k = 0; k < 20; ++k) {
    float v = m1; int ci = (t1 << 6) | lane;
#pragma unroll
    for (int off = 32; off; off >>= 1) {
      float ov = __shfl_xor(v, off, 64);
      int   oi = __shfl_xor(ci, off, 64);
      if (ov > v || (ov == v && oi < ci)) { v = ov; ci = oi; }
    }
    if (k == lane) sel = ci;
    if ((ci & 63) == lane && (ci >> 6) == t1) {
      removed |= 1ull << t1;
      if (have2) { m1 = m2; t1 = t2; have2 = false; }
      else {
        m1 = -INFINITY; t1 = 0; m2 = -INFINITY; t2 = 0;
#pragma unroll
        for (int tt = 0; tt < 64; ++tt) {
          if (!((removed >> tt) & 1ull)) {
            float dv = d[tt];
            if (dv > m1) { m2 = m1; t2 = t1; m1 = dv; t1 = tt; }
            else if (dv > m2) { m2 = dv; t2 = tt; }
          }
        }
        have2 = true;
      }
    }
  }
  if (lane < 20) op[lane] = sel;
}

// variant for k_sel: candidate global index = (tt>>2)*256 + lane*4 + (tt&3)
__device__ __forceinline__ int gi_map(int tt, int lane) {
  return ((tt >> 2) << 8) | (lane << 2) | (tt & 3);
}
__device__ __forceinline__ void topk_select2(const float (&d)[64], float m1, int t1, float m2, int t2,
                                             int lane, int* __restrict__ op) {
  unsigned long long removed = 0ull;
  bool have2 = true;
  int sel = 0;
#pragma unroll 1
  for (int k = 0; k < 20; ++k) {
    float v = m1; int ci = gi_map(t1, lane);
#pragma unroll
    for (int off = 32; off; off >>= 1) {
      float ov = __shfl_xor(v, off, 64);
      int   oi = __shfl_xor(ci, off, 64);
      if (ov > v || (ov == v && oi < ci)) { v = ov; ci = oi; }
    }
    if (k == lane) sel = ci;
    if (ci == gi_map(t1, lane)) {     // this lane's current best won
      removed |= 1ull << t1;
      if (have2) { m1 = m2; t1 = t2; have2 = false; }
      else {
        m1 = -INFINITY; t1 = 0; m2 = -INFINITY; t2 = 0;
#pragma unroll
        for (int tt = 0; tt < 64; ++tt) {
          if (!((removed >> tt) & 1ull)) {
            float dv = d[tt];
            if (dv > m1) { m2 = m1; t2 = t1; m1 = dv; t1 = tt; }
            else if (dv > m2) { m2 = dv; t2 = tt; }
          }
        }
        have2 = true;
      }
    }
  }
  if (lane < 20) op[lane] = sel;
}

// ---------------- kNN, C=3: 1024 thr = 16 waves = 16 queries --------------
__global__ __launch_bounds__(1024) void k_knn3(const float* __restrict__ src, int* __restrict__ idx) {
  __shared__ float tile[Nn * 3];   // 48 KB: whole batch's points
  int t = threadIdx.x;
  int wave = t >> 6, lane = t & 63;
  int g = blockIdx.x * 16 + wave;
  int b = g >> 12, n = g & (Nn - 1);
  const float* base = src + (size_t)b * Nn * 3;
  for (int e = t; e < Nn * 3; e += 1024) tile[e] = base[e];
  __syncthreads();
  float qx = tile[n * 3 + 0], qy = tile[n * 3 + 1], qz = tile[n * 3 + 2];
  float qsq = qx * qx + qy * qy + qz * qz;
  float d[64];
  float m1 = -INFINITY, m2 = -INFINITY; int t1 = 0, t2 = 0;
#pragma unroll
  for (int tt = 0; tt < 64; ++tt) {
    int c = (tt << 6) + lane;
    float mx = tile[c * 3], my = tile[c * 3 + 1], mz = tile[c * 3 + 2];
    float msq = mx * mx + my * my + mz * mz;
    float dd = 2.0f * (qx * mx + qy * my + qz * mz) - qsq - msq;
    d[tt] = dd;
    if (dd > m1) { m2 = m1; t2 = t1; m1 = dd; t1 = tt; }
    else if (dd > m2) { m2 = dd; t2 = tt; }
  }
  topk_select(d, m1, t1, m2, t2, lane, idx + (size_t)g * KK);
}

// ---------------- sq norms for 64-dim features ----------------------------
__global__ void k_sqnorm(const float* __restrict__ src, float* __restrict__ out) {
  int g = blockIdx.x * 256 + threadIdx.x;
  if (g >= BN) return;
  const float4* r = (const float4*)(src + (size_t)g * 64);
  float s = 0.f;
#pragma unroll
  for (int j = 0; j < 16; ++j) { float4 v = r[j]; s += v.x * v.x + v.y * v.y + v.z * v.z + v.w * v.w; }
  out[g] = s;
}

// ---------------- distance GEMM, one batch: D = 2 X X^T - sq - sq^T -------
// 128x128 tile per block, 256 thr, 8x8 micro-tile (rows ty+16i, cols tx+16j).
// LDS stride 33 -> bank = (row + k) % 32: a-frag 4 distinct banks (broadcast),
// b-frag 16 distinct banks; conflict-free.
__global__ __launch_bounds__(256) void k_dist(const float* __restrict__ X, const float* __restrict__ sq,
                                              int b, float* __restrict__ D) {
  __shared__ float As[128 * 33];
  __shared__ float Bs[128 * 33];
  int t = threadIdx.x;
  int tx = t & 15, ty = t >> 4;
  int bx = blockIdx.x & 31, by = blockIdx.x >> 5;
  const float* Xb = X + (size_t)b * Nn * 64;
  float acc[8][8];
#pragma unroll
  for (int i = 0; i < 8; ++i)
#pragma unroll
    for (int j = 0; j < 8; ++j) acc[i][j] = 0.f;

  int sr = t >> 3, sc4 = t & 7;   // staging: 32 rows/pass, 8 float4 per row
  for (int kc = 0; kc < 2; ++kc) {
    __syncthreads();
#pragma unroll
    for (int pass = 0; pass < 4; ++pass) {
      int r = sr + pass * 32;
      float4 va = *(const float4*)(Xb + (size_t)(by * 128 + r) * 64 + kc * 32 + sc4 * 4);
      float4 vb = *(const float4*)(Xb + (size_t)(bx * 128 + r) * 64 + kc * 32 + sc4 * 4);
      float* ap = As + r * 33 + sc4 * 4;
      ap[0] = va.x; ap[1] = va.y; ap[2] = va.z; ap[3] = va.w;
      float* bp = Bs + r * 33 + sc4 * 4;
      bp[0] = vb.x; bp[1] = vb.y; bp[2] = vb.z; bp[3] = vb.w;
    }
    __syncthreads();
#pragma unroll
    for (int k = 0; k < 32; ++k) {
      float a[8], bb[8];
#pragma unroll
      for (int i = 0; i < 8; ++i) a[i] = As[(ty + 16 * i) * 33 + k];
#pragma unroll
      for (int j = 0; j < 8; ++j) bb[j] = Bs[(tx + 16 * j) * 33 + k];
#pragma unroll
      for (int i = 0; i < 8; ++i)
#pragma unroll
        for (int j = 0; j < 8; ++j) acc[i][j] = fmaf(a[i], bb[j], acc[i][j]);
    }
  }
  const float* sqb = sq + b * Nn;
  float sqq[8], sqc[8];
#pragma unroll
  for (int i = 0; i < 8; ++i) sqq[i] = sqb[by * 128 + ty + 16 * i];
#pragma unroll
  for (int j = 0; j < 8; ++j) sqc[j] = sqb[bx * 128 + tx + 16 * j];
#pragma unroll
  for (int i = 0; i < 8; ++i) {
    float* dr = D + (size_t)(by * 128 + ty + 16 * i) * 4096 + bx * 128 + tx;
#pragma unroll
    for (int j = 0; j < 8; ++j) dr[16 * j] = 2.0f * acc[i][j] - sqq[i] - sqc[j];
  }
}

// ---------------- top-20 over precomputed D rows, wave per query ----------
__global__ __launch_bounds__(256) void k_sel(const float* __restrict__ D, int b, int* __restrict__ idx) {
  int t = threadIdx.x;
  int wave = t >> 6, lane = t & 63;
  int q = blockIdx.x * 4 + wave;           // 0..4095 within batch
  const float* row = D + (size_t)q * 4096;
  float d[64];
  float m1 = -INFINITY, m2 = -INFINITY; int t1 = 0, t2 = 0;
#pragma unroll
  for (int i = 0; i < 16; ++i) {
    float4 v = *(const float4*)(row + i * 256 + lane * 4);
    float vv[4] = {v.x, v.y, v.z, v.w};
#pragma unroll
    for (int j = 0; j < 4; ++j) {
      int tt = i * 4 + j;
      float dd = vv[j];
      d[tt] = dd;
      if (dd > m1) { m2 = m1; t2 = t1; m1 = dd; t1 = tt; }
      else if (dd > m2) { m2 = dd; t2 = tt; }
    }
  }
  topk_select2(d, m1, t1, m2, t2, lane, idx + (size_t)(b * Nn + q) * KK);
}

// ---------------- edge conv, CF=3, 6->64->OUT, max over K -----------------
template <int OUT>
__global__ __launch_bounds__(256) void k_edge3(const float* __restrict__ fin, const int* __restrict__ idx,
                                               const float* __restrict__ w1, const float* __restrict__ b1,
                                               const float* __restrict__ w2, const float* __restrict__ b2,
                                               float* __restrict__ fout) {
  __shared__ float sw1[384];
  __shared__ float sw2[64 * OUT];
  __shared__ float sb1[64], sb2[OUT];
  __shared__ float scen[3];
  __shared__ float ccon[64];
  __shared__ int   sidx[20];
  __shared__ float dn[60];
  __shared__ float y1[1280];
  __shared__ float pm[256];
  int t = threadIdx.x;
  for (int e = t; e < 384; e += 256) sw1[e] = w1[e];
  for (int e = t; e < 64 * OUT; e += 256) sw2[e] = w2[e];
  if (t < 64) sb1[t] = b1[t];
  if (t < OUT) sb2[t] = b2[t];
  int p0 = blockIdx.x * 16;
  int b = p0 >> 12;
  const float* fb = fin + (size_t)b * Nn * 3;
  for (int it = 0; it < 16; ++it) {
    int pt = p0 + it;
    __syncthreads();
    if (t < 20) sidx[t] = idx[(size_t)pt * KK + t];
    if (t >= 32 && t < 35) scen[t - 32] = fin[(size_t)pt * 3 + t - 32];
    __syncthreads();
    if (t < 60) { int k = t / 3, j = t - 3 * k; dn[t] = fb[(size_t)sidx[k] * 3 + j] - scen[j]; }
    if (t >= 64 && t < 128) { int c = t - 64; ccon[c] = scen[0] * sw1[c] + scen[1] * sw1[64 + c] + scen[2] * sw1[128 + c]; }
    __syncthreads();
    for (int o = t; o < 1280; o += 256) {
      int k = o >> 6, c = o & 63;
      float acc = sb1[c] + ccon[c];
      acc = fmaf(dn[k * 3 + 0], sw1[192 + c], acc);
      acc = fmaf(dn[k * 3 + 1], sw1[256 + c], acc);
      acc = fmaf(dn[k * 3 + 2], sw1[320 + c], acc);
      y1[o] = fmaxf(acc, 0.f);
    }
    __syncthreads();
    {
      constexpr int GR = 256 / OUT;
      int c = t & (OUT - 1), kg = t / OUT;
      float mx = -INFINITY;
      for (int k = kg; k < 20; k += GR) {
        const float* yk = y1 + (k << 6);
        float acc = 0.f;
#pragma unroll
        for (int j = 0; j < 64; ++j) acc = fmaf(yk[j], sw2[j * OUT + c], acc);
        mx = fmaxf(mx, acc);
      }
      pm[t] = mx;
    }
    __syncthreads();
    if (t < OUT) {
      float m = pm[t];
#pragma unroll
      for (int gr = 1; gr < 256 / OUT; ++gr) m = fmaxf(m, pm[gr * OUT + t]);
      fout[(size_t)pt * OUT + t] = fmaxf(m + sb2[t], 0.f);
    }
  }
}

// ---------------- edge conv, CF=64, 128->64->64, max over K ---------------
__global__ __launch_bounds__(256) void k_edgeC(const float* __restrict__ xin, const int* __restrict__ idx,
                                               const float* __restrict__ w1, const float* __restrict__ b1,
                                               const float* __restrict__ w2, const float* __restrict__ b2,
                                               float* __restrict__ xout) {
  __shared__ float sw1[8192];
  __shared__ float sw2[4096];
  __shared__ float sb1[64], sb2[64];
  __shared__ float scen[64], ccon[64];
  __shared__ int   sidx[20];
  __shared__ float dn[1280];
  __shared__ float y1[1280];
  __shared__ float pm[256];
  int t = threadIdx.x;
  for (int e = t; e < 8192; e += 256) sw1[e] = w1[e];
  for (int e = t; e < 4096; e += 256) sw2[e] = w2[e];
  if (t < 64) { sb1[t] = b1[t]; sb2[t] = b2[t]; }
  int p0 = blockIdx.x * 16;
  int b = p0 >> 12;
  const float* xbp = xin + (size_t)b * Nn * 64;
  for (int it = 0; it < 16; ++it) {
    int pt = p0 + it;
    __syncthreads();
    if (t < 20) sidx[t] = idx[(size_t)pt * KK + t];
    if (t >= 32 && t < 96) scen[t - 32] = xin[(size_t)pt * 64 + t - 32];
    __syncthreads();
    for (int e = t; e < 1280; e += 256) { int k = e >> 6, j = e & 63; dn[e] = xbp[(size_t)sidx[k] * 64 + j] - scen[j]; }
    if (t < 64) {
      float a = 0.f;
#pragma unroll
      for (int j = 0; j < 64; ++j) a = fmaf(scen[j], sw1[j * 64 + t], a);
      ccon[t] = a;
    }
    __syncthreads();
    for (int o = t; o < 1280; o += 256) {
      int k = o >> 6, c = o & 63;
      float acc = sb1[c] + ccon[c];
      const float* dk = dn + (k << 6);
#pragma unroll
      for (int j = 0; j < 64; ++j) acc = fmaf(dk[j], sw1[(64 + j) * 64 + c], acc);
      y1[o] = fmaxf(acc, 0.f);
    }
    __syncthreads();
    {
      int c = t & 63, kg = t >> 6;
      float mx = -INFINITY;
      for (int k = kg; k < 20; k += 4) {
        const float* yk = y1 + (k << 6);
        float acc = 0.f;
#pragma unroll
        for (int j = 0; j < 64; ++j) acc = fmaf(yk[j], sw2[j * 64 + c], acc);
        mx = fmaxf(mx, acc);
      }
      pm[t] = mx;
    }
    __syncthreads();
    if (t < 64) {
      float m = fmaxf(fmaxf(pm[t], pm[64 + t]), fmaxf(pm[128 + t], pm[192 + t]));
      xout[(size_t)pt * 64 + t] = fmaxf(m + sb2[t], 0.f);
    }
  }
}

// ---------------- edge conv, CF=64, 128->64 single, max over K ------------
__global__ __launch_bounds__(256) void k_edgeD(const float* __restrict__ xin, const int* __restrict__ idx,
                                               const float* __restrict__ w1, const float* __restrict__ b1,
                                               float* __restrict__ xout) {
  __shared__ float sw1[8192];
  __shared__ float sb1[64];
  __shared__ float scen[64], ccon[64];
  __shared__ int   sidx[20];
  __shared__ float dn[1280];
  __shared__ float zb[1280];
  int t = threadIdx.x;
  for (int e = t; e < 8192; e += 256) sw1[e] = w1[e];
  if (t < 64) sb1[t] = b1[t];
  int p0 = blockIdx.x * 16;
  int b = p0 >> 12;
  const float* xbp = xin + (size_t)b * Nn * 64;
  for (int it = 0; it < 16; ++it) {
    int pt = p0 + it;
    __syncthreads();
    if (t < 20) sidx[t] = idx[(size_t)pt * KK + t];
    if (t >= 32 && t < 96) scen[t - 32] = xin[(size_t)pt * 64 + t - 32];
    __syncthreads();
    for (int e = t; e < 1280; e += 256) { int k = e >> 6, j = e & 63; dn[e] = xbp[(size_t)sidx[k] * 64 + j] - scen[j]; }
    if (t < 64) {
      float a = 0.f;
#pragma unroll
      for (int j = 0; j < 64; ++j) a = fmaf(scen[j], sw1[j * 64 + t], a);
      ccon[t] = a;
    }
    __syncthreads();
    for (int o = t; o < 1280; o += 256) {
      int k = o >> 6, c = o & 63;
      float acc = ccon[c];
      const float* dk = dn + (k << 6);
#pragma unroll
      for (int j = 0; j < 64; ++j) acc = fmaf(dk[j], sw1[(64 + j) * 64 + c], acc);
      zb[o] = acc;
    }
    __syncthreads();
    if (t < 64) {
      float m = -INFINITY;
#pragma unroll
      for (int k = 0; k < 20; ++k) m = fmaxf(m, zb[(k << 6) + t]);
      xout[(size_t)pt * 64 + t] = fmaxf(m + sb1[t], 0.f);
    }
  }
}

// ---------------- t @ tw3, partial max over n-splits ----------------------
__global__ __launch_bounds__(256) void k_dpass1(const float* __restrict__ t128, const float* __restrict__ w3,
                                                float* __restrict__ dpart) {
  __shared__ float wc[8192];    // [j][c] 128x64
  __shared__ float rows[4096];  // 32 rows x 128
  __shared__ float pm[256];
  int t = threadIdx.x;
  int blk = blockIdx.x;
  int b = blk >> 7, cb = (blk >> 3) & 15, ns = blk & 7;
  for (int e = t; e < 8192; e += 256) { int j = e >> 6, c = e & 63; wc[e] = w3[(size_t)j * 1024 + cb * 64 + c]; }
  int c = t & 63, rg = t >> 6;
  float mx = -INFINITY;
  const float* tbase = t128 + ((size_t)b * Nn + ns * 512) * 128;
  for (int tile = 0; tile < 16; ++tile) {
    __syncthreads();
    const float4* src = (const float4*)(tbase + (size_t)tile * 32 * 128);
    float4* dst = (float4*)rows;
#pragma unroll
    for (int e = 0; e < 4; ++e) dst[t + 256 * e] = src[t + 256 * e];
    __syncthreads();
    for (int r = rg; r < 32; r += 4) {
      const float* row = rows + r * 128;
      float acc = 0.f;
#pragma unroll
      for (int j = 0; j < 128; ++j) acc = fmaf(row[j], wc[j * 64 + c], acc);
      mx = fmaxf(mx, acc);
    }
  }
  pm[t] = mx;
  __syncthreads();
  if (t < 64) {
    float m = fmaxf(fmaxf(pm[t], pm[64 + t]), fmaxf(pm[128 + t], pm[192 + t]));
    dpart[((size_t)b * 8 + ns) * 1024 + cb * 64 + t] = m;
  }
}

// ---------------- reduce partials + fc1 (1024->512) -----------------------
__global__ __launch_bounds__(256) void k_fc1(const float* __restrict__ dpart, const float* __restrict__ tb3,
                                             const float* __restrict__ tfw1, const float* __restrict__ tfb1,
                                             float* __restrict__ h1) {
  __shared__ float tv[1024];
  __shared__ float ps[256];
  int t = threadIdx.x;
  int b = blockIdx.x >> 3, cb = blockIdx.x & 7;
  for (int e = t; e < 1024; e += 256) {
    float m = -INFINITY;
#pragma unroll
    for (int s = 0; s < 8; ++s) m = fmaxf(m, dpart[((size_t)b * 8 + s) * 1024 + e]);
    tv[e] = fmaxf(m + tb3[e], 0.f);
  }
  __syncthreads();
  int c = cb * 64 + (t & 63), jg = t >> 6;
  float acc = 0.f;
  for (int j = jg * 256; j < jg * 256 + 256; ++j) acc = fmaf(tv[j], tfw1[(size_t)j * 512 + c], acc);
  ps[t] = acc;
  __syncthreads();
  if (t < 64) {
    float a = ps[t] + ps[64 + t] + ps[128 + t] + ps[192 + t] + tfb1[cb * 64 + t];
    h1[(size_t)b * 512 + cb * 64 + t] = fmaxf(a, 0.f);
  }
}

// ---------------- fc2, fc3 (transform), apply p = pts @ xf ----------------
__global__ __launch_bounds__(256) void k_fc23p(const float* __restrict__ h1, const float* __restrict__ tfw2,
                                               const float* __restrict__ tfb2, const float* __restrict__ txw,
                                               const float* __restrict__ txb, const float* __restrict__ pts,
                                               float* __restrict__ p) {
  __shared__ float sh1[512];
  __shared__ float h2[256];
  __shared__ float sxf[9];
  int t = threadIdx.x;
  int b = blockIdx.x;
  for (int e = t; e < 512; e += 256) sh1[e] = h1[(size_t)b * 512 + e];
  __syncthreads();
  {
    float acc = tfb2[t];
    for (int j = 0; j < 512; ++j) acc = fmaf(sh1[j], tfw2[(size_t)j * 256 + t], acc);
    h2[t] = fmaxf(acc, 0.f);
  }
  __syncthreads();
  if (t < 9) {
    float acc = txb[t];
    for (int j = 0; j < 256; ++j) acc = fmaf(h2[j], txw[j * 9 + t], acc);
    sxf[t] = acc;
  }
  __syncthreads();
  for (int n = t; n < Nn; n += 256) {
    const float* pr = pts + ((size_t)b * Nn + n) * 3;
    float a0 = pr[0], a1 = pr[1], a2 = pr[2];
    float* po = p + ((size_t)b * Nn + n) * 3;
#pragma unroll
    for (int d = 0; d < 3; ++d) po[d] = a0 * sxf[d] + a1 * sxf[3 + d] + a2 * sxf[6 + d];
  }
}

// ---------------- [x1,x2,x3] @ c1w, partial max over n-splits -------------
__global__ __launch_bounds__(256) void k_j1(const float* __restrict__ x1, const float* __restrict__ x2,
                                            const float* __restrict__ x3, const float* __restrict__ c1w,
                                            float* __restrict__ gpart) {
  __shared__ float wc[12288];   // 192x64
  __shared__ float rows[3072];  // 16 rows x 192
  __shared__ float pm[256];
  int t = threadIdx.x;
  int blk = blockIdx.x;
  int b = blk >> 7, cb = (blk >> 3) & 15, ns = blk & 7;
  for (int e = t; e < 12288; e += 256) { int j = e >> 6, c = e & 63; wc[e] = c1w[(size_t)j * 1024 + cb * 64 + c]; }
  int c = t & 63, rg = t >> 6;
  float mx = -INFINITY;
  size_t nbase = (size_t)b * Nn + ns * 512;
  for (int tile = 0; tile < 32; ++tile) {
    __syncthreads();
    int n0 = tile * 16;
    for (int e = t; e < 3072; e += 256) {
      int r = e / 192, j = e - 192 * r;
      size_t nn = nbase + n0 + r;
      float v = (j < 64) ? x1[nn * 64 + j] : (j < 128 ? x2[nn * 64 + j - 64] : x3[nn * 64 + j - 128]);
      rows[e] = v;
    }
    __syncthreads();
    for (int r = rg; r < 16; r += 4) {
      const float* row = rows + r * 192;
      float acc = 0.f;
#pragma unroll
      for (int j = 0; j < 192; ++j) acc = fmaf(row[j], wc[j * 64 + c], acc);
      mx = fmaxf(mx, acc);
    }
  }
  pm[t] = mx;
  __syncthreads();
  if (t < 64) {
    float m = fmaxf(fmaxf(pm[t], pm[64 + t]), fmaxf(pm[128 + t], pm[192 + t]));
    gpart[((size_t)b * 8 + ns) * 1024 + cb * 64 + t] = m;
  }
}

// ---------------- gc = relu(max+b) @ c2w[:1024] ---------------------------
__global__ __launch_bounds__(256) void k_j2(const float* __restrict__ gpart, const float* __restrict__ c1b,
                                            const float* __restrict__ c2w, float* __restrict__ gc) {
  __shared__ float g[1024];
  int t = threadIdx.x;
  int b = blockIdx.x >> 1, half = blockIdx.x & 1;
  for (int e = t; e < 1024; e += 256) {
    float m = -INFINITY;
#pragma unroll
    for (int s = 0; s < 8; ++s) m = fmaxf(m, gpart[((size_t)b * 8 + s) * 1024 + e]);
    g[e] = fmaxf(m + c1b[e], 0.f);
  }
  __syncthreads();
  int d = half * 256 + t;
  float acc = 0.f;
  for (int j = 0; j < 1024; ++j) acc = fmaf(g[j], c2w[(size_t)j * 512 + d], acc);
  gc[(size_t)b * 512 + d] = acc;
}

// ---------------- fused head: 192->512->256->2 per point ------------------
#define MT 16
__global__ __launch_bounds__(512) void k_final(const float* __restrict__ x1, const float* __restrict__ x2,
                                               const float* __restrict__ x3, const float* __restrict__ gc,
                                               const float* __restrict__ c2b, const float* __restrict__ c2wf,
                                               const float* __restrict__ c3w, const float* __restrict__ c3b,
                                               const float* __restrict__ c4w, const float* __restrict__ c4b,
                                               float* __restrict__ out) {
  __shared__ float ubuf[4096];       // sf[192][stride 20, MT cols] then z2[16][256]
  __shared__ float z5[512 * 20];     // z512 transposed [j][m], stride 20
  int t = threadIdx.x;
  int p0 = blockIdx.x * MT;
  int b = p0 >> 12;
  float* sf = ubuf;
  float* z2 = ubuf;
  // gather transposed features: sf[j*20+m], j<192 (x1|x2|x3), m<16
  for (int e = t; e < 768; e += 512) {
    int a = e >> 8, rem = e & 255, m = rem >> 4, ch = rem & 15;
    const float* src = (a == 0 ? x1 : a == 1 ? x2 : x3) + ((size_t)(p0 + m)) * 64 + ch * 4;
    float4 v = *(const float4*)src;
    int jb = a * 64 + ch * 4;
    sf[(jb + 0) * 20 + m] = v.x; sf[(jb + 1) * 20 + m] = v.y;
    sf[(jb + 2) * 20 + m] = v.z; sf[(jb + 3) * 20 + m] = v.w;
  }
  __syncthreads();
  {
    float acc[MT];
    float base0 = gc[(size_t)b * 512 + t] + c2b[t];
#pragma unroll
    for (int m = 0; m < MT; ++m) acc[m] = base0;
    for (int j = 0; j < 192; ++j) {
      float wj = c2wf[(size_t)j * 512 + t];
      const float* sr = sf + j * 20;
#pragma unroll
      for (int m = 0; m < MT; ++m) acc[m] = fmaf(sr[m], wj, acc[m]);
    }
    float* zr = z5 + t * 20;
#pragma unroll
    for (int m = 0; m < MT; ++m) zr[m] = fmaxf(acc[m], 0.f);
  }
  __syncthreads();
  {
    int d2 = t & 255, mh = t >> 8;
    float acc[8];
    float bb = c3b[d2];
#pragma unroll
    for (int i = 0; i < 8; ++i) acc[i] = bb;
    for (int j = 0; j < 512; ++j) {
      float wj = c3w[(size_t)j * 256 + d2];
      const float* zr = z5 + j * 20 + mh * 8;
#pragma unroll
      for (int i = 0; i < 8; ++i) acc[i] = fmaf(zr[i], wj, acc[i]);
    }
#pragma unroll
    for (int i = 0; i < 8; ++i) z2[(mh * 8 + i) * 256 + d2] = fmaxf(acc[i], 0.f);
  }
  __syncthreads();
  if (t < MT * 2) {
    int m = t >> 1, e = t & 1;
    float acc = c4b[e];
    const float* zr = z2 + m * 256;
    for (int j = 0; j < 256; ++j) acc = fmaf(zr[j], c4w[j * 2 + e], acc);
    out[(size_t)(p0 + m) * 2 + e] = acc;
  }
}

// ===========================================================================
extern "C" void kernel_launch(void* const* d_in, const int* in_sizes, int n_in,
                              void* d_out, int out_size, void* d_ws, size_t ws_size,
                              hipStream_t stream) {
  const float* xin = (const float*)d_in[0];
  const float* W[30];
  for (int i = 0; i < 30; ++i) W[i] = (const float*)d_in[i + 1];

  float* ws = (float*)d_ws;
  size_t off = 0;
  float* pts   = ws + off; off += (size_t)BN * 3;
  float* p     = ws + off; off += (size_t)BN * 3;
  int*   idx   = (int*)(ws + off); off += (size_t)BN * KK;
  float* sq    = ws + off; off += BN;
  float* t128  = ws + off; off += (size_t)BN * 128;
  float* dpart = ws + off; off += 4 * 8 * 1024;
  float* h1    = ws + off; off += 4 * 512;
  float* x1    = ws + off; off += (size_t)BN * 64;
  float* x2    = ws + off; off += (size_t)BN * 64;
  float* x3    = ws + off; off += (size_t)BN * 64;
  float* gpart = ws + off; off += 4 * 8 * 1024;
  float* gc    = ws + off; off += 4 * 512;
  float* Dbuf  = ws + off; off += (size_t)Nn * Nn;   // 64 MB, reused per batch

  k_pts<<<dim3(192), dim3(256), 0, stream>>>(xin, pts);

  // stage 1: transform branch
  k_knn3<<<dim3(1024), dim3(1024), 0, stream>>>(pts, idx);
  k_edge3<128><<<dim3(1024), dim3(256), 0, stream>>>(pts, idx, W[0], W[1], W[2], W[3], t128);
  k_dpass1<<<dim3(512), dim3(256), 0, stream>>>(t128, W[4], dpart);
  k_fc1<<<dim3(32), dim3(256), 0, stream>>>(dpart, W[5], W[6], W[7], h1);
  k_fc23p<<<dim3(4), dim3(256), 0, stream>>>(h1, W[8], W[9], W[10], W[11], pts, p);

  // stage 2: edge convs on transformed points / features
  k_knn3<<<dim3(1024), dim3(1024), 0, stream>>>(p, idx);
  k_edge3<64><<<dim3(1024), dim3(256), 0, stream>>>(p, idx, W[12], W[13], W[14], W[15], x1);
  k_sqnorm<<<dim3(64), dim3(256), 0, stream>>>(x1, sq);
  for (int b = 0; b < 4; ++b) {
    k_dist<<<dim3(1024), dim3(256), 0, stream>>>(x1, sq, b, Dbuf);
    k_sel<<<dim3(1024), dim3(256), 0, stream>>>(Dbuf, b, idx);
  }
  k_edgeC<<<dim3(1024), dim3(256), 0, stream>>>(x1, idx, W[16], W[17], W[18], W[19], x2);
  k_sqnorm<<<dim3(64), dim3(256), 0, stream>>>(x2, sq);
  for (int b = 0; b < 4; ++b) {
    k_dist<<<dim3(1024), dim3(256), 0, stream>>>(x2, sq, b, Dbuf);
    k_sel<<<dim3(1024), dim3(256), 0, stream>>>(Dbuf, b, idx);
  }
  k_edgeD<<<dim3(1024), dim3(256), 0, stream>>>(x2, idx, W[20], W[21], x3);

  // stage 3: global feature + head
  k_j1<<<dim3(512), dim3(256), 0, stream>>>(x1, x2, x3, W[22], gpart);
  k_j2<<<dim3(8), dim3(256), 0, stream>>>(gpart, W[23], W[24], gc);
  k_final<<<dim3(1024), dim3(512), 0, stream>>>(x1, x2, x3, gc, W[25], W[24] + 1024 * 512,
                                                W[26], W[27], W[28], W[29],
                                                (float*)d_out);
}

// Round 5
// 2119.287 us; speedup vs baseline: 2.8313x; 1.2156x over previous
//
#include <hip/hip_runtime.h>

#define Nn 4096
#define KK 20
#define BN 16384   // B*N, B=4

typedef __attribute__((ext_vector_type(8))) short bf16x8;
typedef __attribute__((ext_vector_type(4))) float f32x4;

__device__ __forceinline__ unsigned short f2bf(float f) {
  unsigned int x = __float_as_uint(f);
  return (unsigned short)((x + 0x7fffu + ((x >> 16) & 1u)) >> 16);
}

// ---------------- extract pts = x[:,:,:3] ---------------------------------
__global__ void k_pts(const float* __restrict__ x, float* __restrict__ pts) {
  int i = blockIdx.x * 256 + threadIdx.x;
  if (i < BN * 3) {
    int pt = i / 3, c = i - 3 * pt;
    pts[i] = x[pt * 6 + c];
  }
}

// ---------------- weight convert+transpose to bf16: dst[n*K+k]=src[(row0+k)*ldn+n]
__global__ void k_cvtT(const float* __restrict__ src, unsigned short* __restrict__ dst,
                       int N, int K, int ldn, int row0) {
  int i = blockIdx.x * 256 + threadIdx.x;
  if (i >= N * K) return;
  int n = i / K, k = i - n * K;
  dst[i] = f2bf(src[(size_t)(row0 + k) * ldn + n]);
}

// ---------------- xcat bf16 [pt][192] = [x1|x2|x3] ------------------------
__global__ void k_cat(const float* __restrict__ x1, const float* __restrict__ x2,
                      const float* __restrict__ x3, unsigned short* __restrict__ xcat) {
  int i = blockIdx.x * 256 + threadIdx.x;   // < BN*192
  int pt = i / 192, j = i - pt * 192;
  float v = (j < 64) ? x1[pt * 64 + j] : (j < 128 ? x2[pt * 64 + j - 64] : x3[pt * 64 + j - 128]);
  xcat[i] = f2bf(v);
}

// ---------------- exact top-20 selection, one wave per query ---------------
__device__ __forceinline__ void topk_select(const float (&d)[64], float m1, int t1, float m2, int t2,
                                            int lane, int* __restrict__ op) {
  unsigned long long removed = 0ull;
  bool have2 = true;
  int sel = 0;
#pragma unroll 1
  for (int k = 0; k < 20; ++k) {
    float v = m1; int ci = (t1 << 6) | lane;
#pragma unroll
    for (int off = 32; off; off >>= 1) {
      float ov = __shfl_xor(v, off, 64);
      int   oi = __shfl_xor(ci, off, 64);
      if (ov > v || (ov == v && oi < ci)) { v = ov; ci = oi; }
    }
    if (k == lane) sel = ci;
    if ((ci & 63) == lane && (ci >> 6) == t1) {
      removed |= 1ull << t1;
      if (have2) { m1 = m2; t1 = t2; have2 = false; }
      else {
        m1 = -INFINITY; t1 = 0; m2 = -INFINITY; t2 = 0;
#pragma unroll
        for (int tt = 0; tt < 64; ++tt) {
          if (!((removed >> tt) & 1ull)) {
            float dv = d[tt];
            if (dv > m1) { m2 = m1; t2 = t1; m1 = dv; t1 = tt; }
            else if (dv > m2) { m2 = dv; t2 = tt; }
          }
        }
        have2 = true;
      }
    }
  }
  if (lane < 20) op[lane] = sel;
}

__device__ __forceinline__ int gi_map(int tt, int lane) {
  return ((tt >> 2) << 8) | (lane << 2) | (tt & 3);
}
__device__ __forceinline__ void topk_select2(const float (&d)[64], float m1, int t1, float m2, int t2,
                                             int lane, int* __restrict__ op) {
  unsigned long long removed = 0ull;
  bool have2 = true;
  int sel = 0;
#pragma unroll 1
  for (int k = 0; k < 20; ++k) {
    float v = m1; int ci = gi_map(t1, lane);
#pragma unroll
    for (int off = 32; off; off >>= 1) {
      float ov = __shfl_xor(v, off, 64);
      int   oi = __shfl_xor(ci, off, 64);
      if (ov > v || (ov == v && oi < ci)) { v = ov; ci = oi; }
    }
    if (k == lane) sel = ci;
    if (ci == gi_map(t1, lane)) {
      removed |= 1ull << t1;
      if (have2) { m1 = m2; t1 = t2; have2 = false; }
      else {
        m1 = -INFINITY; t1 = 0; m2 = -INFINITY; t2 = 0;
#pragma unroll
        for (int tt = 0; tt < 64; ++tt) {
          if (!((removed >> tt) & 1ull)) {
            float dv = d[tt];
            if (dv > m1) { m2 = m1; t2 = t1; m1 = dv; t1 = tt; }
            else if (dv > m2) { m2 = dv; t2 = tt; }
          }
        }
        have2 = true;
      }
    }
  }
  if (lane < 20) op[lane] = sel;
}

// ---------------- kNN, C=3 ------------------------------------------------
__global__ __launch_bounds__(1024) void k_knn3(const float* __restrict__ src, int* __restrict__ idx) {
  __shared__ float tile[Nn * 3];
  int t = threadIdx.x;
  int wave = t >> 6, lane = t & 63;
  int g = blockIdx.x * 16 + wave;
  int b = g >> 12, n = g & (Nn - 1);
  const float* base = src + (size_t)b * Nn * 3;
  for (int e = t; e < Nn * 3; e += 1024) tile[e] = base[e];
  __syncthreads();
  float qx = tile[n * 3 + 0], qy = tile[n * 3 + 1], qz = tile[n * 3 + 2];
  float qsq = qx * qx + qy * qy + qz * qz;
  float d[64];
  float m1 = -INFINITY, m2 = -INFINITY; int t1 = 0, t2 = 0;
#pragma unroll
  for (int tt = 0; tt < 64; ++tt) {
    int c = (tt << 6) + lane;
    float mx = tile[c * 3], my = tile[c * 3 + 1], mz = tile[c * 3 + 2];
    float msq = mx * mx + my * my + mz * mz;
    float dd = 2.0f * (qx * mx + qy * my + qz * mz) - qsq - msq;
    d[tt] = dd;
    if (dd > m1) { m2 = m1; t2 = t1; m1 = dd; t1 = tt; }
    else if (dd > m2) { m2 = dd; t2 = tt; }
  }
  topk_select(d, m1, t1, m2, t2, lane, idx + (size_t)g * KK);
}

// ---------------- sq norms ------------------------------------------------
__global__ void k_sqnorm(const float* __restrict__ src, float* __restrict__ out) {
  int g = blockIdx.x * 256 + threadIdx.x;
  if (g >= BN) return;
  const float4* r = (const float4*)(src + (size_t)g * 64);
  float s = 0.f;
#pragma unroll
  for (int j = 0; j < 16; ++j) { float4 v = r[j]; s += v.x * v.x + v.y * v.y + v.z * v.z + v.w * v.w; }
  out[g] = s;
}

// ---------------- distance GEMM (fp32, vectorized LDS) --------------------
// m-major k-contiguous tiles, stride 36 floats; float4 LDS reads.
__global__ __launch_bounds__(256) void k_dist(const float* __restrict__ X, const float* __restrict__ sq,
                                              int b, float* __restrict__ D) {
  __shared__ float As[128 * 36];
  __shared__ float Bs[128 * 36];
  int t = threadIdx.x;
  int tx = t & 15, ty = (t >> 4) & 3;   // within-wave roles (64-lane wave: ty 0..3)
  int bx = blockIdx.x & 31, by = blockIdx.x >> 5;
  const float* Xb = X + (size_t)b * Nn * 64;
  float acc[8][8];
#pragma unroll
  for (int i = 0; i < 8; ++i)
#pragma unroll
    for (int j = 0; j < 8; ++j) acc[i][j] = 0.f;

  for (int kc = 0; kc < 2; ++kc) {
    __syncthreads();
#pragma unroll
    for (int e = 0; e < 4; ++e) {
      int f = t + 256 * e;            // 0..1023
      int row = f >> 3, c4 = f & 7;
      float4 va = *(const float4*)(Xb + (size_t)(by * 128 + row) * 64 + kc * 32 + c4 * 4);
      float4 vb = *(const float4*)(Xb + (size_t)(bx * 128 + row) * 64 + kc * 32 + c4 * 4);
      *(float4*)(As + row * 36 + c4 * 4) = va;
      *(float4*)(Bs + row * 36 + c4 * 4) = vb;
    }
    __syncthreads();
#pragma unroll
    for (int k4 = 0; k4 < 8; ++k4) {
      float4 a4[8];
#pragma unroll
      for (int i = 0; i < 8; ++i) a4[i] = *(const float4*)(As + (ty + 16 * i) * 36 + k4 * 4);
#pragma unroll
      for (int j = 0; j < 8; ++j) {
        float4 b4 = *(const float4*)(Bs + (tx + 16 * j) * 36 + k4 * 4);
#pragma unroll
        for (int i = 0; i < 8; ++i) {
          acc[i][j] = fmaf(a4[i].x, b4.x, acc[i][j]);
          acc[i][j] = fmaf(a4[i].y, b4.y, acc[i][j]);
          acc[i][j] = fmaf(a4[i].z, b4.z, acc[i][j]);
          acc[i][j] = fmaf(a4[i].w, b4.w, acc[i][j]);
        }
      }
    }
  }
  int tyg = t >> 4;   // 0..15 across block for output rows
  (void)tyg;
  const float* sqb = sq + b * Nn;
  int ty8 = t >> 4;   // 0..15
  float sqq[8], sqc[8];
#pragma unroll
  for (int i = 0; i < 8; ++i) sqq[i] = sqb[by * 128 + (ty8 & 3) + 16 * i + (ty8 >> 2) * 4];
#pragma unroll
  for (int j = 0; j < 8; ++j) sqc[j] = sqb[bx * 128 + tx + 16 * j];
  // NOTE: compute rows must match acc rows: row = ty + 16*i where ty=(t>>4)&3 ... but
  // waves 0..3 of the block all have ty in 0..3 — rows must be disambiguated per wave.
  // Use wave id to offset ty: full-row id = ty + 4*wv.
  int wv = t >> 6;
#pragma unroll
  for (int i = 0; i < 8; ++i) {
    int rowl = ty + 16 * i;           // row used in compute (per-wave)
    (void)rowl;
  }
  // recompute with wave-disambiguated rows: redo sqq and stores using ty_full
  int ty_full = ty + 4 * wv;          // 0..15 unique across block? NO: compute used ty only.
  (void)ty_full;
  // --- Correct epilogue: compute rows were (ty + 16*i) per wave; all 4 waves used the
  // same rows, which would be wrong. To avoid that, compute itself must differ per wave.
  // We folded wave id into ty at the top via tx/ty derivation below (see launch note).
#pragma unroll
  for (int i = 0; i < 8; ++i) {
    float* dr = D + (size_t)(by * 128 + ty + 16 * i) * 4096 + bx * 128 + tx;
    float sqi = sqb[by * 128 + ty + 16 * i];
#pragma unroll
    for (int j = 0; j < 8; ++j) dr[16 * j] = 2.0f * acc[i][j] - sqi - sqc[j];
  }
}

// The above k_dist has a wave-role hazard (ty only 0..3). Use this corrected version.
__global__ __launch_bounds__(256) void k_dist2(const float* __restrict__ X, const float* __restrict__ sq,
                                               int b, float* __restrict__ D) {
  __shared__ float As[128 * 36];
  __shared__ float Bs[128 * 36];
  int t = threadIdx.x;
  int tx = t & 15, ty = t >> 4;       // ty 0..15 across block (4 per wave)
  int bx = blockIdx.x & 31, by = blockIdx.x >> 5;
  const float* Xb = X + (size_t)b * Nn * 64;
  float acc[8][8];
#pragma unroll
  for (int i = 0; i < 8; ++i)
#pragma unroll
    for (int j = 0; j < 8; ++j) acc[i][j] = 0.f;

  for (int kc = 0; kc < 2; ++kc) {
    __syncthreads();
#pragma unroll
    for (int e = 0; e < 4; ++e) {
      int f = t + 256 * e;
      int row = f >> 3, c4 = f & 7;
      float4 va = *(const float4*)(Xb + (size_t)(by * 128 + row) * 64 + kc * 32 + c4 * 4);
      float4 vb = *(const float4*)(Xb + (size_t)(bx * 128 + row) * 64 + kc * 32 + c4 * 4);
      *(float4*)(As + row * 36 + c4 * 4) = va;
      *(float4*)(Bs + row * 36 + c4 * 4) = vb;
    }
    __syncthreads();
#pragma unroll
    for (int k4 = 0; k4 < 8; ++k4) {
      float4 a4[8];
#pragma unroll
      for (int i = 0; i < 8; ++i) a4[i] = *(const float4*)(As + (ty + 16 * i) * 36 + k4 * 4);
#pragma unroll
      for (int j = 0; j < 8; ++j) {
        float4 b4 = *(const float4*)(Bs + (tx + 16 * j) * 36 + k4 * 4);
#pragma unroll
        for (int i = 0; i < 8; ++i) {
          acc[i][j] = fmaf(a4[i].x, b4.x, acc[i][j]);
          acc[i][j] = fmaf(a4[i].y, b4.y, acc[i][j]);
          acc[i][j] = fmaf(a4[i].z, b4.z, acc[i][j]);
          acc[i][j] = fmaf(a4[i].w, b4.w, acc[i][j]);
        }
      }
    }
  }
  const float* sqb = sq + b * Nn;
  float sqc[8];
#pragma unroll
  for (int j = 0; j < 8; ++j) sqc[j] = sqb[bx * 128 + tx + 16 * j];
#pragma unroll
  for (int i = 0; i < 8; ++i) {
    float sqi = sqb[by * 128 + ty + 16 * i];
    float* dr = D + (size_t)(by * 128 + ty + 16 * i) * 4096 + bx * 128 + tx;
#pragma unroll
    for (int j = 0; j < 8; ++j) dr[16 * j] = 2.0f * acc[i][j] - sqi - sqc[j];
  }
}

// ---------------- top-20 over D rows --------------------------------------
__global__ __launch_bounds__(256) void k_sel(const float* __restrict__ D, int b, int* __restrict__ idx) {
  int t = threadIdx.x;
  int wave = t >> 6, lane = t & 63;
  int q = blockIdx.x * 4 + wave;
  const float* row = D + (size_t)q * 4096;
  float d[64];
  float m1 = -INFINITY, m2 = -INFINITY; int t1 = 0, t2 = 0;
#pragma unroll
  for (int i = 0; i < 16; ++i) {
    float4 v = *(const float4*)(row + i * 256 + lane * 4);
    float vv[4] = {v.x, v.y, v.z, v.w};
#pragma unroll
    for (int j = 0; j < 4; ++j) {
      int tt = i * 4 + j;
      float dd = vv[j];
      d[tt] = dd;
      if (dd > m1) { m2 = m1; t2 = t1; m1 = dd; t1 = tt; }
      else if (dd > m2) { m2 = dd; t2 = tt; }
    }
  }
  topk_select2(d, m1, t1, m2, t2, lane, idx + (size_t)(b * Nn + q) * KK);
}

// ---------------- edge conv, CF=3, 6->64->OUT -----------------------------
template <int OUT>
__global__ __launch_bounds__(256) void k_edge3(const float* __restrict__ fin, const int* __restrict__ idx,
                                               const float* __restrict__ w1, const float* __restrict__ b1,
                                               const float* __restrict__ w2, const float* __restrict__ b2,
                                               float* __restrict__ fout) {
  __shared__ float sw1[384];
  __shared__ float sw2[64 * OUT];
  __shared__ float sb1[64], sb2[OUT];
  __shared__ float scen[3];
  __shared__ float ccon[64];
  __shared__ int   sidx[20];
  __shared__ float dn[60];
  __shared__ float y1[1280];
  __shared__ float pm[256];
  int t = threadIdx.x;
  for (int e = t; e < 384; e += 256) sw1[e] = w1[e];
  for (int e = t; e < 64 * OUT; e += 256) sw2[e] = w2[e];
  if (t < 64) sb1[t] = b1[t];
  if (t < OUT) sb2[t] = b2[t];
  int p0 = blockIdx.x * 16;
  int b = p0 >> 12;
  const float* fb = fin + (size_t)b * Nn * 3;
  for (int it = 0; it < 16; ++it) {
    int pt = p0 + it;
    __syncthreads();
    if (t < 20) sidx[t] = idx[(size_t)pt * KK + t];
    if (t >= 32 && t < 35) scen[t - 32] = fin[(size_t)pt * 3 + t - 32];
    __syncthreads();
    if (t < 60) { int k = t / 3, j = t - 3 * k; dn[t] = fb[(size_t)sidx[k] * 3 + j] - scen[j]; }
    if (t >= 64 && t < 128) { int c = t - 64; ccon[c] = scen[0] * sw1[c] + scen[1] * sw1[64 + c] + scen[2] * sw1[128 + c]; }
    __syncthreads();
    for (int o = t; o < 1280; o += 256) {
      int k = o >> 6, c = o & 63;
      float acc = sb1[c] + ccon[c];
      acc = fmaf(dn[k * 3 + 0], sw1[192 + c], acc);
      acc = fmaf(dn[k * 3 + 1], sw1[256 + c], acc);
      acc = fmaf(dn[k * 3 + 2], sw1[320 + c], acc);
      y1[o] = fmaxf(acc, 0.f);
    }
    __syncthreads();
    {
      constexpr int GR = 256 / OUT;
      int c = t & (OUT - 1), kg = t / OUT;
      float mx = -INFINITY;
      for (int k = kg; k < 20; k += GR) {
        const float* yk = y1 + (k << 6);
        float acc = 0.f;
#pragma unroll
        for (int j = 0; j < 64; ++j) acc = fmaf(yk[j], sw2[j * OUT + c], acc);
        mx = fmaxf(mx, acc);
      }
      pm[t] = mx;
    }
    __syncthreads();
    if (t < OUT) {
      float m = pm[t];
#pragma unroll
      for (int gr = 1; gr < 256 / OUT; ++gr) m = fmaxf(m, pm[gr * OUT + t]);
      fout[(size_t)pt * OUT + t] = fmaxf(m + sb2[t], 0.f);
    }
  }
}

// ---------------- edge conv, CF=64, 128->64->64 ---------------------------
__global__ __launch_bounds__(256) void k_edgeC(const float* __restrict__ xin, const int* __restrict__ idx,
                                               const float* __restrict__ w1, const float* __restrict__ b1,
                                               const float* __restrict__ w2, const float* __restrict__ b2,
                                               float* __restrict__ xout) {
  __shared__ float sw1[8192];
  __shared__ float sw2[4096];
  __shared__ float sb1[64], sb2[64];
  __shared__ float scen[64], ccon[64];
  __shared__ int   sidx[20];
  __shared__ float dn[1280];
  __shared__ float y1[1280];
  __shared__ float pm[256];
  int t = threadIdx.x;
  for (int e = t; e < 8192; e += 256) sw1[e] = w1[e];
  for (int e = t; e < 4096; e += 256) sw2[e] = w2[e];
  if (t < 64) { sb1[t] = b1[t]; sb2[t] = b2[t]; }
  int p0 = blockIdx.x * 16;
  int b = p0 >> 12;
  const float* xbp = xin + (size_t)b * Nn * 64;
  for (int it = 0; it < 16; ++it) {
    int pt = p0 + it;
    __syncthreads();
    if (t < 20) sidx[t] = idx[(size_t)pt * KK + t];
    if (t >= 32 && t < 96) scen[t - 32] = xin[(size_t)pt * 64 + t - 32];
    __syncthreads();
    for (int e = t; e < 1280; e += 256) { int k = e >> 6, j = e & 63; dn[e] = xbp[(size_t)sidx[k] * 64 + j] - scen[j]; }
    if (t < 64) {
      float a = 0.f;
#pragma unroll
      for (int j = 0; j < 64; ++j) a = fmaf(scen[j], sw1[j * 64 + t], a);
      ccon[t] = a;
    }
    __syncthreads();
    for (int o = t; o < 1280; o += 256) {
      int k = o >> 6, c = o & 63;
      float acc = sb1[c] + ccon[c];
      const float* dk = dn + (k << 6);
#pragma unroll
      for (int j = 0; j < 64; ++j) acc = fmaf(dk[j], sw1[(64 + j) * 64 + c], acc);
      y1[o] = fmaxf(acc, 0.f);
    }
    __syncthreads();
    {
      int c = t & 63, kg = t >> 6;
      float mx = -INFINITY;
      for (int k = kg; k < 20; k += 4) {
        const float* yk = y1 + (k << 6);
        float acc = 0.f;
#pragma unroll
        for (int j = 0; j < 64; ++j) acc = fmaf(yk[j], sw2[j * 64 + c], acc);
        mx = fmaxf(mx, acc);
      }
      pm[t] = mx;
    }
    __syncthreads();
    if (t < 64) {
      float m = fmaxf(fmaxf(pm[t], pm[64 + t]), fmaxf(pm[128 + t], pm[192 + t]));
      xout[(size_t)pt * 64 + t] = fmaxf(m + sb2[t], 0.f);
    }
  }
}

// ---------------- edge conv, CF=64, 128->64 single ------------------------
__global__ __launch_bounds__(256) void k_edgeD(const float* __restrict__ xin, const int* __restrict__ idx,
                                               const float* __restrict__ w1, const float* __restrict__ b1,
                                               float* __restrict__ xout) {
  __shared__ float sw1[8192];
  __shared__ float sb1[64];
  __shared__ float scen[64], ccon[64];
  __shared__ int   sidx[20];
  __shared__ float dn[1280];
  __shared__ float zb[1280];
  int t = threadIdx.x;
  for (int e = t; e < 8192; e += 256) sw1[e] = w1[e];
  if (t < 64) sb1[t] = b1[t];
  int p0 = blockIdx.x * 16;
  int b = p0 >> 12;
  const float* xbp = xin + (size_t)b * Nn * 64;
  for (int it = 0; it < 16; ++it) {
    int pt = p0 + it;
    __syncthreads();
    if (t < 20) sidx[t] = idx[(size_t)pt * KK + t];
    if (t >= 32 && t < 96) scen[t - 32] = xin[(size_t)pt * 64 + t - 32];
    __syncthreads();
    for (int e = t; e < 1280; e += 256) { int k = e >> 6, j = e & 63; dn[e] = xbp[(size_t)sidx[k] * 64 + j] - scen[j]; }
    if (t < 64) {
      float a = 0.f;
#pragma unroll
      for (int j = 0; j < 64; ++j) a = fmaf(scen[j], sw1[j * 64 + t], a);
      ccon[t] = a;
    }
    __syncthreads();
    for (int o = t; o < 1280; o += 256) {
      int k = o >> 6, c = o & 63;
      float acc = ccon[c];
      const float* dk = dn + (k << 6);
#pragma unroll
      for (int j = 0; j < 64; ++j) acc = fmaf(dk[j], sw1[(64 + j) * 64 + c], acc);
      zb[o] = acc;
    }
    __syncthreads();
    if (t < 64) {
      float m = -INFINITY;
#pragma unroll
      for (int k = 0; k < 20; ++k) m = fmaxf(m, zb[(k << 6) + t]);
      xout[(size_t)pt * 64 + t] = fmaxf(m + sb1[t], 0.f);
    }
  }
}

// ---------------- t @ tw3, partial max (fp32 — feeds kNN-sensitive branch)
__global__ __launch_bounds__(256) void k_dpass1(const float* __restrict__ t128, const float* __restrict__ w3,
                                                float* __restrict__ dpart) {
  __shared__ float wc[8192];
  __shared__ float rows[4096];
  __shared__ float pm[256];
  int t = threadIdx.x;
  int blk = blockIdx.x;
  int b = blk >> 7, cb = (blk >> 3) & 15, ns = blk & 7;
  for (int e = t; e < 8192; e += 256) { int j = e >> 6, c = e & 63; wc[e] = w3[(size_t)j * 1024 + cb * 64 + c]; }
  int c = t & 63, rg = t >> 6;
  float mx = -INFINITY;
  const float* tbase = t128 + ((size_t)b * Nn + ns * 512) * 128;
  for (int tile = 0; tile < 16; ++tile) {
    __syncthreads();
    const float4* src = (const float4*)(tbase + (size_t)tile * 32 * 128);
    float4* dst = (float4*)rows;
#pragma unroll
    for (int e = 0; e < 4; ++e) dst[t + 256 * e] = src[t + 256 * e];
    __syncthreads();
    for (int r = rg; r < 32; r += 4) {
      const float* row = rows + r * 128;
      float acc = 0.f;
#pragma unroll
      for (int j = 0; j < 128; ++j) acc = fmaf(row[j], wc[j * 64 + c], acc);
      mx = fmaxf(mx, acc);
    }
  }
  pm[t] = mx;
  __syncthreads();
  if (t < 64) {
    float m = fmaxf(fmaxf(pm[t], pm[64 + t]), fmaxf(pm[128 + t], pm[192 + t]));
    dpart[((size_t)b * 8 + ns) * 1024 + cb * 64 + t] = m;
  }
}

// ---------------- reduce partials + fc1 -----------------------------------
__global__ __launch_bounds__(256) void k_fc1(const float* __restrict__ dpart, const float* __restrict__ tb3,
                                             const float* __restrict__ tfw1, const float* __restrict__ tfb1,
                                             float* __restrict__ h1) {
  __shared__ float tv[1024];
  __shared__ float ps[256];
  int t = threadIdx.x;
  int b = blockIdx.x >> 3, cb = blockIdx.x & 7;
  for (int e = t; e < 1024; e += 256) {
    float m = -INFINITY;
#pragma unroll
    for (int s = 0; s < 8; ++s) m = fmaxf(m, dpart[((size_t)b * 8 + s) * 1024 + e]);
    tv[e] = fmaxf(m + tb3[e], 0.f);
  }
  __syncthreads();
  int c = cb * 64 + (t & 63), jg = t >> 6;
  float acc = 0.f;
  for (int j = jg * 256; j < jg * 256 + 256; ++j) acc = fmaf(tv[j], tfw1[(size_t)j * 512 + c], acc);
  ps[t] = acc;
  __syncthreads();
  if (t < 64) {
    float a = ps[t] + ps[64 + t] + ps[128 + t] + ps[192 + t] + tfb1[cb * 64 + t];
    h1[(size_t)b * 512 + cb * 64 + t] = fmaxf(a, 0.f);
  }
}

// ---------------- fc2, fc3, apply p = pts @ xf ----------------------------
__global__ __launch_bounds__(256) void k_fc23p(const float* __restrict__ h1, const float* __restrict__ tfw2,
                                               const float* __restrict__ tfb2, const float* __restrict__ txw,
                                               const float* __restrict__ txb, const float* __restrict__ pts,
                                               float* __restrict__ p) {
  __shared__ float sh1[512];
  __shared__ float h2[256];
  __shared__ float sxf[9];
  int t = threadIdx.x;
  int b = blockIdx.x;
  for (int e = t; e < 512; e += 256) sh1[e] = h1[(size_t)b * 512 + e];
  __syncthreads();
  {
    float acc = tfb2[t];
    for (int j = 0; j < 512; ++j) acc = fmaf(sh1[j], tfw2[(size_t)j * 256 + t], acc);
    h2[t] = fmaxf(acc, 0.f);
  }
  __syncthreads();
  if (t < 9) {
    float acc = txb[t];
    for (int j = 0; j < 256; ++j) acc = fmaf(h2[j], txw[j * 9 + t], acc);
    sxf[t] = acc;
  }
  __syncthreads();
  for (int n = t; n < Nn; n += 256) {
    const float* pr = pts + ((size_t)b * Nn + n) * 3;
    float a0 = pr[0], a1 = pr[1], a2 = pr[2];
    float* po = p + ((size_t)b * Nn + n) * 3;
#pragma unroll
    for (int d = 0; d < 3; ++d) po[d] = a0 * sxf[d] + a1 * sxf[3 + d] + a2 * sxf[6 + d];
  }
}

// ---------------- MFMA max-GEMM: gpart = max over rows of xcat @ c1w ------
// block 256 = 4 waves; grid (b,ns,cb); wave handles 16 cols over 512 points.
template <int K>
__global__ __launch_bounds__(256) void k_mgemm(const unsigned short* __restrict__ A,   // [BN][K] bf16
                                               const unsigned short* __restrict__ WT,  // [1024][K] bf16
                                               float* __restrict__ outp) {             // [4][8][1024]
  constexpr int KS = K / 32;
  int t = threadIdx.x;
  int wv = t >> 6, lane = t & 63;
  int quad = lane >> 4, l16 = lane & 15;
  int blk = blockIdx.x;
  int b = blk >> 7, cb = (blk >> 3) & 15, ns = blk & 7;
  int n0 = cb * 64 + wv * 16;
  bf16x8 bfr[KS];
  const unsigned short* wrow = WT + (size_t)(n0 + l16) * K + quad * 8;
#pragma unroll
  for (int s = 0; s < KS; ++s) bfr[s] = *(const bf16x8*)(wrow + s * 32);
  const unsigned short* Ab = A + ((size_t)b * Nn + ns * 512 + l16) * K + quad * 8;
  float rmax = -INFINITY;
#pragma unroll 2
  for (int mt = 0; mt < 32; ++mt) {
    const unsigned short* ar = Ab + (size_t)mt * 16 * K;
    f32x4 acc = {0.f, 0.f, 0.f, 0.f};
#pragma unroll
    for (int s = 0; s < KS; ++s) {
      bf16x8 af = *(const bf16x8*)(ar + s * 32);
      acc = __builtin_amdgcn_mfma_f32_16x16x32_bf16(af, bfr[s], acc, 0, 0, 0);
    }
    rmax = fmaxf(rmax, fmaxf(fmaxf(acc[0], acc[1]), fmaxf(acc[2], acc[3])));
  }
  rmax = fmaxf(rmax, __shfl_xor(rmax, 16, 64));
  rmax = fmaxf(rmax, __shfl_xor(rmax, 32, 64));
  if (quad == 0) outp[((size_t)b * 8 + ns) * 1024 + n0 + l16] = rmax;
}

// ---------------- gc = relu(max+b) @ c2w[:1024] (fp32) --------------------
__global__ __launch_bounds__(256) void k_j2(const float* __restrict__ gpart, const float* __restrict__ c1b,
                                            const float* __restrict__ c2w, float* __restrict__ gc) {
  __shared__ float g[1024];
  int t = threadIdx.x;
  int b = blockIdx.x >> 1, half = blockIdx.x & 1;
  for (int e = t; e < 1024; e += 256) {
    float m = -INFINITY;
#pragma unroll
    for (int s = 0; s < 8; ++s) m = fmaxf(m, gpart[((size_t)b * 8 + s) * 1024 + e]);
    g[e] = fmaxf(m + c1b[e], 0.f);
  }
  __syncthreads();
  int d = half * 256 + t;
  float acc = 0.f;
  for (int j = 0; j < 1024; ++j) acc = fmaf(g[j], c2w[(size_t)j * 512 + d], acc);
  gc[(size_t)b * 512 + d] = acc;
}

// ---------------- fused MFMA head: 192->512->256->2 per 16 points ---------
__global__ __launch_bounds__(256) void k_final(const unsigned short* __restrict__ xcat,
                                               const float* __restrict__ gc,
                                               const float* __restrict__ c2b,
                                               const unsigned short* __restrict__ c2wT,  // [512][192]
                                               const unsigned short* __restrict__ c3wT,  // [256][512]
                                               const float* __restrict__ c3b,
                                               const float* __restrict__ c4w, const float* __restrict__ c4b,
                                               float* __restrict__ out) {
  __shared__ unsigned short z5[16 * 520];   // bf16, stride 520 (pad 8)
  __shared__ float z2[16 * 260];            // fp32, stride 260 (pad 4)
  int t = threadIdx.x;
  int wv = t >> 6, lane = t & 63;
  int quad = lane >> 4, l16 = lane & 15;
  int p0 = blockIdx.x * 16;
  int b = p0 >> 12;
  // GEMM1 A-frags (shared across n-tiles)
  bf16x8 a1[6];
  const unsigned short* ar = xcat + (size_t)(p0 + l16) * 192 + quad * 8;
#pragma unroll
  for (int s = 0; s < 6; ++s) a1[s] = *(const bf16x8*)(ar + s * 32);
#pragma unroll 1
  for (int ntw = 0; ntw < 8; ++ntw) {
    int col = wv * 128 + ntw * 16 + l16;
    float bias = gc[(size_t)b * 512 + col] + c2b[col];
    f32x4 acc = {bias, bias, bias, bias};
    const unsigned short* wr = c2wT + (size_t)col * 192 + quad * 8;
#pragma unroll
    for (int s = 0; s < 6; ++s) {
      bf16x8 bfr = *(const bf16x8*)(wr + s * 32);
      acc = __builtin_amdgcn_mfma_f32_16x16x32_bf16(a1[s], bfr, acc, 0, 0, 0);
    }
#pragma unroll
    for (int r = 0; r < 4; ++r)
      z5[(quad * 4 + r) * 520 + col] = f2bf(fmaxf(acc[r], 0.f));
  }
  __syncthreads();
  // GEMM2 A-frags from z5 (16 k-steps)
  bf16x8 a2[16];
#pragma unroll
  for (int s = 0; s < 16; ++s) a2[s] = *(const bf16x8*)(z5 + l16 * 520 + s * 32 + quad * 8);
#pragma unroll 1
  for (int ntw = 0; ntw < 4; ++ntw) {
    int col = wv * 64 + ntw * 16 + l16;
    float bias = c3b[col];
    f32x4 acc = {bias, bias, bias, bias};
    const unsigned short* wr = c3wT + (size_t)col * 512 + quad * 8;
#pragma unroll
    for (int s = 0; s < 16; ++s) {
      bf16x8 bfr = *(const bf16x8*)(wr + s * 32);
      acc = __builtin_amdgcn_mfma_f32_16x16x32_bf16(a2[s], bfr, acc, 0, 0, 0);
    }
#pragma unroll
    for (int r = 0; r < 4; ++r)
      z2[(quad * 4 + r) * 260 + col] = fmaxf(acc[r], 0.f);
  }
  __syncthreads();
  if (t < 32) {
    int m = t >> 1, e = t & 1;
    float acc = c4b[e];
    const float* zr = z2 + m * 260;
    for (int j = 0; j < 256; ++j) acc = fmaf(zr[j], c4w[j * 2 + e], acc);
    out[(size_t)(p0 + m) * 2 + e] = acc;
  }
}

// ===========================================================================
extern "C" void kernel_launch(void* const* d_in, const int* in_sizes, int n_in,
                              void* d_out, int out_size, void* d_ws, size_t ws_size,
                              hipStream_t stream) {
  const float* xin = (const float*)d_in[0];
  const float* W[30];
  for (int i = 0; i < 30; ++i) W[i] = (const float*)d_in[i + 1];

  float* ws = (float*)d_ws;
  size_t off = 0;
  float* pts   = ws + off; off += (size_t)BN * 3;
  float* p     = ws + off; off += (size_t)BN * 3;
  int*   idx   = (int*)(ws + off); off += (size_t)BN * KK;
  float* sq    = ws + off; off += BN;
  float* t128  = ws + off; off += (size_t)BN * 128;
  float* dpart = ws + off; off += 4 * 8 * 1024;
  float* h1    = ws + off; off += 4 * 512;
  float* x1    = ws + off; off += (size_t)BN * 64;
  float* x2    = ws + off; off += (size_t)BN * 64;
  float* x3    = ws + off; off += (size_t)BN * 64;
  float* gpart = ws + off; off += 4 * 8 * 1024;
  float* gc    = ws + off; off += 4 * 512;
  unsigned short* xcat = (unsigned short*)(ws + off); off += (size_t)BN * 96;   // BN*192 bf16
  unsigned short* c1wT = (unsigned short*)(ws + off); off += 98304;             // 1024*192 bf16
  unsigned short* c2wT = (unsigned short*)(ws + off); off += 49152;             // 512*192 bf16
  unsigned short* c3wT = (unsigned short*)(ws + off); off += 65536;             // 256*512 bf16
  float* Dbuf  = ws + off; off += (size_t)Nn * Nn;

  // weight conversions (independent of activations)
  k_cvtT<<<dim3(768), dim3(256), 0, stream>>>(W[22], c1wT, 1024, 192, 1024, 0);
  k_cvtT<<<dim3(384), dim3(256), 0, stream>>>(W[24], c2wT, 512, 192, 512, 1024);
  k_cvtT<<<dim3(512), dim3(256), 0, stream>>>(W[26], c3wT, 256, 512, 256, 0);

  k_pts<<<dim3(192), dim3(256), 0, stream>>>(xin, pts);

  // stage 1: transform branch (all fp32 — feeds kNN)
  k_knn3<<<dim3(1024), dim3(1024), 0, stream>>>(pts, idx);
  k_edge3<128><<<dim3(1024), dim3(256), 0, stream>>>(pts, idx, W[0], W[1], W[2], W[3], t128);
  k_dpass1<<<dim3(512), dim3(256), 0, stream>>>(t128, W[4], dpart);
  k_fc1<<<dim3(32), dim3(256), 0, stream>>>(dpart, W[5], W[6], W[7], h1);
  k_fc23p<<<dim3(4), dim3(256), 0, stream>>>(h1, W[8], W[9], W[10], W[11], pts, p);

  // stage 2
  k_knn3<<<dim3(1024), dim3(1024), 0, stream>>>(p, idx);
  k_edge3<64><<<dim3(1024), dim3(256), 0, stream>>>(p, idx, W[12], W[13], W[14], W[15], x1);
  k_sqnorm<<<dim3(64), dim3(256), 0, stream>>>(x1, sq);
  for (int b = 0; b < 4; ++b) {
    k_dist2<<<dim3(1024), dim3(256), 0, stream>>>(x1, sq, b, Dbuf);
    k_sel<<<dim3(1024), dim3(256), 0, stream>>>(Dbuf, b, idx);
  }
  k_edgeC<<<dim3(1024), dim3(256), 0, stream>>>(x1, idx, W[16], W[17], W[18], W[19], x2);
  k_sqnorm<<<dim3(64), dim3(256), 0, stream>>>(x2, sq);
  for (int b = 0; b < 4; ++b) {
    k_dist2<<<dim3(1024), dim3(256), 0, stream>>>(x2, sq, b, Dbuf);
    k_sel<<<dim3(1024), dim3(256), 0, stream>>>(Dbuf, b, idx);
  }
  k_edgeD<<<dim3(1024), dim3(256), 0, stream>>>(x2, idx, W[20], W[21], x3);

  // stage 3: bf16 activations + MFMA GEMMs
  k_cat<<<dim3(12288), dim3(256), 0, stream>>>(x1, x2, x3, xcat);
  k_mgemm<192><<<dim3(512), dim3(256), 0, stream>>>(xcat, c1wT, gpart);
  k_j2<<<dim3(8), dim3(256), 0, stream>>>(gpart, W[23], W[24], gc);
  k_final<<<dim3(1024), dim3(256), 0, stream>>>(xcat, gc, W[25], c2wT, c3wT,
                                                W[27], W[28], W[29], (float*)d_out);
}

// Round 7
// 2069.516 us; speedup vs baseline: 2.8994x; 1.0240x over previous
//
#include <hip/hip_runtime.h>

#define Nn 4096
#define KK 20
#define BN 16384   // B*N, B=4

typedef __attribute__((ext_vector_type(8))) short bf16x8;
typedef __attribute__((ext_vector_type(4))) float f32x4;

__device__ __forceinline__ unsigned short f2bf(float f) {
  unsigned int x = __float_as_uint(f);
  return (unsigned short)((x + 0x7fffu + ((x >> 16) & 1u)) >> 16);
}
__device__ __forceinline__ float bf2f(unsigned short u) {
  return __uint_as_float(((unsigned int)u) << 16);
}

// ---------------- extract pts = x[:,:,:3] ---------------------------------
__global__ void k_pts(const float* __restrict__ x, float* __restrict__ pts) {
  int i = blockIdx.x * 256 + threadIdx.x;
  if (i < BN * 3) {
    int pt = i / 3, c = i - 3 * pt;
    pts[i] = x[pt * 6 + c];
  }
}

// ---------------- weight convert+transpose to bf16 ------------------------
__global__ void k_cvtT(const float* __restrict__ src, unsigned short* __restrict__ dst,
                       int N, int K, int ldn, int row0) {
  int i = blockIdx.x * 256 + threadIdx.x;
  if (i >= N * K) return;
  int n = i / K, k = i - n * K;
  dst[i] = f2bf(src[(size_t)(row0 + k) * ldn + n]);
}

// ---------------- transpose + 3-way bf16 split ----------------------------
__global__ void k_cvtT3(const float* __restrict__ src, unsigned short* __restrict__ h,
                        unsigned short* __restrict__ m, unsigned short* __restrict__ l,
                        int N, int K, int ldn) {
  int i = blockIdx.x * 256 + threadIdx.x;
  if (i >= N * K) return;
  int n = i / K, k = i - n * K;
  float x = src[(size_t)k * ldn + n];
  unsigned short hh = f2bf(x); float xh = bf2f(hh);
  unsigned short mm = f2bf(x - xh); float xm = bf2f(mm);
  unsigned short ll = f2bf(x - xh - xm);
  h[i] = hh; m[i] = mm; l[i] = ll;
}

// ---------------- 3-way bf16 split (row-major passthrough) ----------------
__global__ void k_split3(const float* __restrict__ src, unsigned short* __restrict__ h,
                         unsigned short* __restrict__ m, unsigned short* __restrict__ l, int n) {
  int i = blockIdx.x * 256 + threadIdx.x;
  if (i >= n) return;
  float x = src[i];
  unsigned short hh = f2bf(x); float xh = bf2f(hh);
  unsigned short mm = f2bf(x - xh); float xm = bf2f(mm);
  unsigned short ll = f2bf(x - xh - xm);
  h[i] = hh; m[i] = mm; l[i] = ll;
}

// ---------------- xcat bf16 [pt][192] = [x1|x2|x3] ------------------------
__global__ void k_cat(const float* __restrict__ x1, const float* __restrict__ x2,
                      const float* __restrict__ x3, unsigned short* __restrict__ xcat) {
  int i = blockIdx.x * 256 + threadIdx.x;
  int pt = i / 192, j = i - pt * 192;
  float v = (j < 64) ? x1[pt * 64 + j] : (j < 128 ? x2[pt * 64 + j - 64] : x3[pt * 64 + j - 128]);
  xcat[i] = f2bf(v);
}

// ---------------- exact top-20 selection, one wave per query ---------------
__device__ __forceinline__ void topk_select(const float (&d)[64], float m1, int t1, float m2, int t2,
                                            int lane, int* __restrict__ op) {
  unsigned long long removed = 0ull;
  bool have2 = true;
  int sel = 0;
#pragma unroll 1
  for (int k = 0; k < 20; ++k) {
    float v = m1; int ci = (t1 << 6) | lane;
#pragma unroll
    for (int off = 32; off; off >>= 1) {
      float ov = __shfl_xor(v, off, 64);
      int   oi = __shfl_xor(ci, off, 64);
      if (ov > v || (ov == v && oi < ci)) { v = ov; ci = oi; }
    }
    if (k == lane) sel = ci;
    if ((ci & 63) == lane && (ci >> 6) == t1) {
      removed |= 1ull << t1;
      if (have2) { m1 = m2; t1 = t2; have2 = false; }
      else {
        m1 = -INFINITY; t1 = 0; m2 = -INFINITY; t2 = 0;
#pragma unroll
        for (int tt = 0; tt < 64; ++tt) {
          if (!((removed >> tt) & 1ull)) {
            float dv = d[tt];
            if (dv > m1) { m2 = m1; t2 = t1; m1 = dv; t1 = tt; }
            else if (dv > m2) { m2 = dv; t2 = tt; }
          }
        }
        have2 = true;
      }
    }
  }
  if (lane < 20) op[lane] = sel;
}

__device__ __forceinline__ int gi_map(int tt, int lane) {
  return ((tt >> 2) << 8) | (lane << 2) | (tt & 3);
}
__device__ __forceinline__ void topk_select2(const float (&d)[64], float m1, int t1, float m2, int t2,
                                             int lane, int* __restrict__ op) {
  unsigned long long removed = 0ull;
  bool have2 = true;
  int sel = 0;
#pragma unroll 1
  for (int k = 0; k < 20; ++k) {
    float v = m1; int ci = gi_map(t1, lane);
#pragma unroll
    for (int off = 32; off; off >>= 1) {
      float ov = __shfl_xor(v, off, 64);
      int   oi = __shfl_xor(ci, off, 64);
      if (ov > v || (ov == v && oi < ci)) { v = ov; ci = oi; }
    }
    if (k == lane) sel = ci;
    if (ci == gi_map(t1, lane)) {
      removed |= 1ull << t1;
      if (have2) { m1 = m2; t1 = t2; have2 = false; }
      else {
        m1 = -INFINITY; t1 = 0; m2 = -INFINITY; t2 = 0;
#pragma unroll
        for (int tt = 0; tt < 64; ++tt) {
          if (!((removed >> tt) & 1ull)) {
            float dv = d[tt];
            if (dv > m1) { m2 = m1; t2 = t1; m1 = dv; t1 = tt; }
            else if (dv > m2) { m2 = dv; t2 = tt; }
          }
        }
        have2 = true;
      }
    }
  }
  if (lane < 20) op[lane] = sel;
}

// ---------------- kNN, C=3 ------------------------------------------------
__global__ __launch_bounds__(1024) void k_knn3(const float* __restrict__ src, int* __restrict__ idx) {
  __shared__ float tile[Nn * 3];
  int t = threadIdx.x;
  int wave = t >> 6, lane = t & 63;
  int g = blockIdx.x * 16 + wave;
  int b = g >> 12, n = g & (Nn - 1);
  const float* base = src + (size_t)b * Nn * 3;
  for (int e = t; e < Nn * 3; e += 1024) tile[e] = base[e];
  __syncthreads();
  float qx = tile[n * 3 + 0], qy = tile[n * 3 + 1], qz = tile[n * 3 + 2];
  float qsq = qx * qx + qy * qy + qz * qz;
  float d[64];
  float m1 = -INFINITY, m2 = -INFINITY; int t1 = 0, t2 = 0;
#pragma unroll
  for (int tt = 0; tt < 64; ++tt) {
    int c = (tt << 6) + lane;
    float mx = tile[c * 3], my = tile[c * 3 + 1], mz = tile[c * 3 + 2];
    float msq = mx * mx + my * my + mz * mz;
    float dd = 2.0f * (qx * mx + qy * my + qz * mz) - qsq - msq;
    d[tt] = dd;
    if (dd > m1) { m2 = m1; t2 = t1; m1 = dd; t1 = tt; }
    else if (dd > m2) { m2 = dd; t2 = tt; }
  }
  topk_select(d, m1, t1, m2, t2, lane, idx + (size_t)g * KK);
}

// ---------------- sq norms ------------------------------------------------
__global__ void k_sqnorm(const float* __restrict__ src, float* __restrict__ out) {
  int g = blockIdx.x * 256 + threadIdx.x;
  if (g >= BN) return;
  const float4* r = (const float4*)(src + (size_t)g * 64);
  float s = 0.f;
#pragma unroll
  for (int j = 0; j < 16; ++j) { float4 v = r[j]; s += v.x * v.x + v.y * v.y + v.z * v.z + v.w * v.w; }
  out[g] = s;
}

// ---------------- distance GEMM via 3-split bf16 MFMA ---------------------
// D = 2 X X^T - sq - sq^T, per batch. 64x64 block tile, wave = 2x2 16x16 tiles.
// 6 cross-product MFMAs (hh,hm,mh,hl,lh,mm) -> rel err ~2^-26.
__global__ __launch_bounds__(256) void k_dist3s(const unsigned short* __restrict__ Xh,
                                                const unsigned short* __restrict__ Xm,
                                                const unsigned short* __restrict__ Xl,
                                                const float* __restrict__ sq,
                                                int b, float* __restrict__ D) {
  int t = threadIdx.x;
  int wv = t >> 6, lane = t & 63;
  int quad = lane >> 4, l16 = lane & 15;
  int wx = wv & 1, wy = wv >> 1;
  int bx = blockIdx.x & 63, by = blockIdx.x >> 6;
  const size_t base = (size_t)b * Nn * 64;
  int ra0 = by * 64 + wy * 32;
  int cb0 = bx * 64 + wx * 32;
  f32x4 acc[2][2];
  f32x4 zz = {0.f, 0.f, 0.f, 0.f};
#pragma unroll
  for (int i = 0; i < 2; ++i)
#pragma unroll
    for (int j = 0; j < 2; ++j) acc[i][j] = zz;
#pragma unroll
  for (int ks = 0; ks < 2; ++ks) {
    int ko = ks * 32 + quad * 8;
    bf16x8 ah[2], am[2], al[2], bh[2], bm[2], bl[2];
#pragma unroll
    for (int ti = 0; ti < 2; ++ti) {
      size_t ra = base + (size_t)(ra0 + ti * 16 + l16) * 64 + ko;
      ah[ti] = *(const bf16x8*)(Xh + ra);
      am[ti] = *(const bf16x8*)(Xm + ra);
      al[ti] = *(const bf16x8*)(Xl + ra);
      size_t rb = base + (size_t)(cb0 + ti * 16 + l16) * 64 + ko;
      bh[ti] = *(const bf16x8*)(Xh + rb);
      bm[ti] = *(const bf16x8*)(Xm + rb);
      bl[ti] = *(const bf16x8*)(Xl + rb);
    }
#pragma unroll
    for (int ti = 0; ti < 2; ++ti)
#pragma unroll
      for (int tj = 0; tj < 2; ++tj) {
        f32x4 a = acc[ti][tj];
        a = __builtin_amdgcn_mfma_f32_16x16x32_bf16(ah[ti], bh[tj], a, 0, 0, 0);
        a = __builtin_amdgcn_mfma_f32_16x16x32_bf16(ah[ti], bm[tj], a, 0, 0, 0);
        a = __builtin_amdgcn_mfma_f32_16x16x32_bf16(am[ti], bh[tj], a, 0, 0, 0);
        a = __builtin_amdgcn_mfma_f32_16x16x32_bf16(ah[ti], bl[tj], a, 0, 0, 0);
        a = __builtin_amdgcn_mfma_f32_16x16x32_bf16(al[ti], bh[tj], a, 0, 0, 0);
        a = __builtin_amdgcn_mfma_f32_16x16x32_bf16(am[ti], bm[tj], a, 0, 0, 0);
        acc[ti][tj] = a;
      }
  }
  const float* sqb = sq + b * Nn;
#pragma unroll
  for (int ti = 0; ti < 2; ++ti) {
    int row0 = ra0 + ti * 16 + quad * 4;
#pragma unroll
    for (int tj = 0; tj < 2; ++tj) {
      int col = cb0 + tj * 16 + l16;
      float sqc = sqb[col];
#pragma unroll
      for (int r = 0; r < 4; ++r)
        D[(size_t)(row0 + r) * 4096 + col] = 2.0f * acc[ti][tj][r] - sqb[row0 + r] - sqc;
    }
  }
}

// ---------------- top-20 over D rows --------------------------------------
__global__ __launch_bounds__(256) void k_sel(const float* __restrict__ D, int b, int* __restrict__ idx) {
  int t = threadIdx.x;
  int wave = t >> 6, lane = t & 63;
  int q = blockIdx.x * 4 + wave;
  const float* row = D + (size_t)q * 4096;
  float d[64];
  float m1 = -INFINITY, m2 = -INFINITY; int t1 = 0, t2 = 0;
#pragma unroll
  for (int i = 0; i < 16; ++i) {
    float4 v = *(const float4*)(row + i * 256 + lane * 4);
    float vv[4] = {v.x, v.y, v.z, v.w};
#pragma unroll
    for (int j = 0; j < 4; ++j) {
      int tt = i * 4 + j;
      float dd = vv[j];
      d[tt] = dd;
      if (dd > m1) { m2 = m1; t2 = t1; m1 = dd; t1 = tt; }
      else if (dd > m2) { m2 = dd; t2 = tt; }
    }
  }
  topk_select2(d, m1, t1, m2, t2, lane, idx + (size_t)(b * Nn + q) * KK);
}

// ---------------- edge conv, CF=3, 6->64->OUT -----------------------------
template <int OUT>
__global__ __launch_bounds__(256) void k_edge3(const float* __restrict__ fin, const int* __restrict__ idx,
                                               const float* __restrict__ w1, const float* __restrict__ b1,
                                               const float* __restrict__ w2, const float* __restrict__ b2,
                                               float* __restrict__ fout) {
  __shared__ float sw1[384];
  __shared__ float sw2[64 * OUT];
  __shared__ float sb1[64], sb2[OUT];
  __shared__ float scen[3];
  __shared__ float ccon[64];
  __shared__ int   sidx[20];
  __shared__ float dn[60];
  __shared__ float y1[1280];
  __shared__ float pm[256];
  int t = threadIdx.x;
  for (int e = t; e < 384; e += 256) sw1[e] = w1[e];
  for (int e = t; e < 64 * OUT; e += 256) sw2[e] = w2[e];
  if (t < 64) sb1[t] = b1[t];
  if (t < OUT) sb2[t] = b2[t];
  int p0 = blockIdx.x * 16;
  int b = p0 >> 12;
  const float* fb = fin + (size_t)b * Nn * 3;
  for (int it = 0; it < 16; ++it) {
    int pt = p0 + it;
    __syncthreads();
    if (t < 20) sidx[t] = idx[(size_t)pt * KK + t];
    if (t >= 32 && t < 35) scen[t - 32] = fin[(size_t)pt * 3 + t - 32];
    __syncthreads();
    if (t < 60) { int k = t / 3, j = t - 3 * k; dn[t] = fb[(size_t)sidx[k] * 3 + j] - scen[j]; }
    if (t >= 64 && t < 128) { int c = t - 64; ccon[c] = scen[0] * sw1[c] + scen[1] * sw1[64 + c] + scen[2] * sw1[128 + c]; }
    __syncthreads();
    for (int o = t; o < 1280; o += 256) {
      int k = o >> 6, c = o & 63;
      float acc = sb1[c] + ccon[c];
      acc = fmaf(dn[k * 3 + 0], sw1[192 + c], acc);
      acc = fmaf(dn[k * 3 + 1], sw1[256 + c], acc);
      acc = fmaf(dn[k * 3 + 2], sw1[320 + c], acc);
      y1[o] = fmaxf(acc, 0.f);
    }
    __syncthreads();
    {
      constexpr int GR = 256 / OUT;
      int c = t & (OUT - 1), kg = t / OUT;
      float mx = -INFINITY;
      for (int k = kg; k < 20; k += GR) {
        const float* yk = y1 + (k << 6);
        float acc = 0.f;
#pragma unroll
        for (int j = 0; j < 64; ++j) acc = fmaf(yk[j], sw2[j * OUT + c], acc);
        mx = fmaxf(mx, acc);
      }
      pm[t] = mx;
    }
    __syncthreads();
    if (t < OUT) {
      float m = pm[t];
#pragma unroll
      for (int gr = 1; gr < 256 / OUT; ++gr) m = fmaxf(m, pm[gr * OUT + t]);
      fout[(size_t)pt * OUT + t] = fmaxf(m + sb2[t], 0.f);
    }
  }
}

// ---------------- edge conv, CF=64, 128->64->64 ---------------------------
__global__ __launch_bounds__(256) void k_edgeC(const float* __restrict__ xin, const int* __restrict__ idx,
                                               const float* __restrict__ w1, const float* __restrict__ b1,
                                               const float* __restrict__ w2, const float* __restrict__ b2,
                                               float* __restrict__ xout) {
  __shared__ float sw1[8192];
  __shared__ float sw2[4096];
  __shared__ float sb1[64], sb2[64];
  __shared__ float scen[64], ccon[64];
  __shared__ int   sidx[20];
  __shared__ float dn[1280];
  __shared__ float y1[1280];
  __shared__ float pm[256];
  int t = threadIdx.x;
  for (int e = t; e < 8192; e += 256) sw1[e] = w1[e];
  for (int e = t; e < 4096; e += 256) sw2[e] = w2[e];
  if (t < 64) { sb1[t] = b1[t]; sb2[t] = b2[t]; }
  int p0 = blockIdx.x * 16;
  int b = p0 >> 12;
  const float* xbp = xin + (size_t)b * Nn * 64;
  for (int it = 0; it < 16; ++it) {
    int pt = p0 + it;
    __syncthreads();
    if (t < 20) sidx[t] = idx[(size_t)pt * KK + t];
    if (t >= 32 && t < 96) scen[t - 32] = xin[(size_t)pt * 64 + t - 32];
    __syncthreads();
    for (int e = t; e < 1280; e += 256) { int k = e >> 6, j = e & 63; dn[e] = xbp[(size_t)sidx[k] * 64 + j] - scen[j]; }
    if (t < 64) {
      float a = 0.f;
#pragma unroll
      for (int j = 0; j < 64; ++j) a = fmaf(scen[j], sw1[j * 64 + t], a);
      ccon[t] = a;
    }
    __syncthreads();
    for (int o = t; o < 1280; o += 256) {
      int k = o >> 6, c = o & 63;
      float acc = sb1[c] + ccon[c];
      const float* dk = dn + (k << 6);
#pragma unroll
      for (int j = 0; j < 64; ++j) acc = fmaf(dk[j], sw1[(64 + j) * 64 + c], acc);
      y1[o] = fmaxf(acc, 0.f);
    }
    __syncthreads();
    {
      int c = t & 63, kg = t >> 6;
      float mx = -INFINITY;
      for (int k = kg; k < 20; k += 4) {
        const float* yk = y1 + (k << 6);
        float acc = 0.f;
#pragma unroll
        for (int j = 0; j < 64; ++j) acc = fmaf(yk[j], sw2[j * 64 + c], acc);
        mx = fmaxf(mx, acc);
      }
      pm[t] = mx;
    }
    __syncthreads();
    if (t < 64) {
      float m = fmaxf(fmaxf(pm[t], pm[64 + t]), fmaxf(pm[128 + t], pm[192 + t]));
      xout[(size_t)pt * 64 + t] = fmaxf(m + sb2[t], 0.f);
    }
  }
}

// ---------------- edgeD prep: Md[64][128] = [Wc-Wd | Wd] ------------------
__global__ void k_prepD(const float* __restrict__ w1, float* __restrict__ Md) {
  int i = blockIdx.x * 256 + threadIdx.x;
  if (i >= 8192) return;
  int j = i >> 7, c = i & 127;
  Md[i] = (c < 64) ? (w1[j * 64 + c] - w1[(64 + j) * 64 + c]) : w1[(64 + j) * 64 + (c - 64)];
}

// ---------------- uv = x2 @ Md (fp32 dense, register-chunked) -------------
__global__ __launch_bounds__(256) void k_uv(const float* __restrict__ x2, const float* __restrict__ Md,
                                            float* __restrict__ uv) {
  __shared__ float sM[8192];     // 64x128
  __shared__ float sx[64 * 68];
  int t = threadIdx.x;
  for (int e = t; e < 8192; e += 256) sM[e] = Md[e];
  int p0 = blockIdx.x * 64;
  for (int e = t; e < 1024; e += 256) {
    int r = e >> 4, c4 = e & 15;
    *(float4*)(sx + r * 68 + c4 * 4) = *(const float4*)(x2 + (size_t)(p0 + r) * 64 + c4 * 4);
  }
  __syncthreads();
  int c = t & 127, rg = t >> 7;
  float accv[32];
#pragma unroll
  for (int r = 0; r < 32; ++r) accv[r] = 0.f;
#pragma unroll
  for (int jc = 0; jc < 8; ++jc) {
    float mreg[8];
#pragma unroll
    for (int q = 0; q < 8; ++q) mreg[q] = sM[(jc * 8 + q) * 128 + c];
#pragma unroll
    for (int r = 0; r < 32; ++r) {
      const float* xr = sx + (rg * 32 + r) * 68 + jc * 8;
      float4 a = *(const float4*)xr, bb = *(const float4*)(xr + 4);
      float s = accv[r];
      s = fmaf(a.x, mreg[0], s); s = fmaf(a.y, mreg[1], s);
      s = fmaf(a.z, mreg[2], s); s = fmaf(a.w, mreg[3], s);
      s = fmaf(bb.x, mreg[4], s); s = fmaf(bb.y, mreg[5], s);
      s = fmaf(bb.z, mreg[6], s); s = fmaf(bb.w, mreg[7], s);
      accv[r] = s;
    }
  }
#pragma unroll
  for (int r = 0; r < 32; ++r)
    uv[(size_t)(p0 + rg * 32 + r) * 128 + c] = accv[r];
}

// ---------------- x3 = relu(u + max_k v_nk + b1) --------------------------
// FIX(R7): idx holds WITHIN-BATCH neighbor ids; uv is indexed by global point
// id -> add batch base (p>>12)*Nn. (R6 bug: batches 1-3 read batch-0 rows.)
__global__ __launch_bounds__(256) void k_gmax(const float* __restrict__ uv, const int* __restrict__ idx,
                                              const float* __restrict__ b1, float* __restrict__ x3) {
  __shared__ int sidx[4][20];
  int t = threadIdx.x;
  int pl = t >> 6, c = t & 63;
  int p0 = blockIdx.x * 4;
  if (t < 80) sidx[t / 20][t % 20] = idx[(size_t)(p0 + t / 20) * KK + (t % 20)];
  __syncthreads();
  int p = p0 + pl;
  size_t nbase = (size_t)(p >> 12) * Nn;   // batch base for neighbor ids
  float u = uv[(size_t)p * 128 + c];
  float m = -INFINITY;
#pragma unroll
  for (int k = 0; k < 20; ++k) m = fmaxf(m, uv[(nbase + sidx[pl][k]) * 128 + 64 + c]);
  x3[(size_t)p * 64 + c] = fmaxf(u + m + b1[c], 0.f);
}

// ---------------- reduce partials + fc1 -----------------------------------
__global__ __launch_bounds__(256) void k_fc1(const float* __restrict__ dpart, const float* __restrict__ tb3,
                                             const float* __restrict__ tfw1, const float* __restrict__ tfb1,
                                             float* __restrict__ h1) {
  __shared__ float tv[1024];
  __shared__ float ps[256];
  int t = threadIdx.x;
  int b = blockIdx.x >> 3, cb = blockIdx.x & 7;
  for (int e = t; e < 1024; e += 256) {
    float m = -INFINITY;
#pragma unroll
    for (int s = 0; s < 8; ++s) m = fmaxf(m, dpart[((size_t)b * 8 + s) * 1024 + e]);
    tv[e] = fmaxf(m + tb3[e], 0.f);
  }
  __syncthreads();
  int c = cb * 64 + (t & 63), jg = t >> 6;
  float acc = 0.f;
  for (int j = jg * 256; j < jg * 256 + 256; ++j) acc = fmaf(tv[j], tfw1[(size_t)j * 512 + c], acc);
  ps[t] = acc;
  __syncthreads();
  if (t < 64) {
    float a = ps[t] + ps[64 + t] + ps[128 + t] + ps[192 + t] + tfb1[cb * 64 + t];
    h1[(size_t)b * 512 + cb * 64 + t] = fmaxf(a, 0.f);
  }
}

// ---------------- fc2, fc3, apply p = pts @ xf ----------------------------
__global__ __launch_bounds__(256) void k_fc23p(const float* __restrict__ h1, const float* __restrict__ tfw2,
                                               const float* __restrict__ tfb2, const float* __restrict__ txw,
                                               const float* __restrict__ txb, const float* __restrict__ pts,
                                               float* __restrict__ p) {
  __shared__ float sh1[512];
  __shared__ float h2[256];
  __shared__ float sxf[9];
  int t = threadIdx.x;
  int b = blockIdx.x;
  for (int e = t; e < 512; e += 256) sh1[e] = h1[(size_t)b * 512 + e];
  __syncthreads();
  {
    float acc = tfb2[t];
    for (int j = 0; j < 512; ++j) acc = fmaf(sh1[j], tfw2[(size_t)j * 256 + t], acc);
    h2[t] = fmaxf(acc, 0.f);
  }
  __syncthreads();
  if (t < 9) {
    float acc = txb[t];
    for (int j = 0; j < 256; ++j) acc = fmaf(h2[j], txw[j * 9 + t], acc);
    sxf[t] = acc;
  }
  __syncthreads();
  for (int n = t; n < Nn; n += 256) {
    const float* pr = pts + ((size_t)b * Nn + n) * 3;
    float a0 = pr[0], a1 = pr[1], a2 = pr[2];
    float* po = p + ((size_t)b * Nn + n) * 3;
#pragma unroll
    for (int d = 0; d < 3; ++d) po[d] = a0 * sxf[d] + a1 * sxf[3 + d] + a2 * sxf[6 + d];
  }
}

// ---------------- MFMA max-GEMM (bf16, post-kNN path) ---------------------
template <int K>
__global__ __launch_bounds__(256) void k_mgemm(const unsigned short* __restrict__ A,
                                               const unsigned short* __restrict__ WT,
                                               float* __restrict__ outp) {
  constexpr int KS = K / 32;
  int t = threadIdx.x;
  int wv = t >> 6, lane = t & 63;
  int quad = lane >> 4, l16 = lane & 15;
  int blk = blockIdx.x;
  int b = blk >> 7, cb = (blk >> 3) & 15, ns = blk & 7;
  int n0 = cb * 64 + wv * 16;
  bf16x8 bfr[KS];
  const unsigned short* wrow = WT + (size_t)(n0 + l16) * K + quad * 8;
#pragma unroll
  for (int s = 0; s < KS; ++s) bfr[s] = *(const bf16x8*)(wrow + s * 32);
  const unsigned short* Ab = A + ((size_t)b * Nn + ns * 512 + l16) * K + quad * 8;
  float rmax = -INFINITY;
#pragma unroll 2
  for (int mt = 0; mt < 32; ++mt) {
    const unsigned short* ar = Ab + (size_t)mt * 16 * K;
    f32x4 acc = {0.f, 0.f, 0.f, 0.f};
#pragma unroll
    for (int s = 0; s < KS; ++s) {
      bf16x8 af = *(const bf16x8*)(ar + s * 32);
      acc = __builtin_amdgcn_mfma_f32_16x16x32_bf16(af, bfr[s], acc, 0, 0, 0);
    }
    rmax = fmaxf(rmax, fmaxf(fmaxf(acc[0], acc[1]), fmaxf(acc[2], acc[3])));
  }
  rmax = fmaxf(rmax, __shfl_xor(rmax, 16, 64));
  rmax = fmaxf(rmax, __shfl_xor(rmax, 32, 64));
  if (quad == 0) outp[((size_t)b * 8 + ns) * 1024 + n0 + l16] = rmax;
}

// ---------------- MFMA max-GEMM, 3-split exact (t128 @ w3) ----------------
template <int K>
__global__ __launch_bounds__(256) void k_mgemm3s(const unsigned short* __restrict__ Ah,
                                                 const unsigned short* __restrict__ Am,
                                                 const unsigned short* __restrict__ Al,
                                                 const unsigned short* __restrict__ Bh,
                                                 const unsigned short* __restrict__ Bm,
                                                 const unsigned short* __restrict__ Bl,
                                                 float* __restrict__ outp) {
  constexpr int KS = K / 32;
  int t = threadIdx.x;
  int wv = t >> 6, lane = t & 63;
  int quad = lane >> 4, l16 = lane & 15;
  int blk = blockIdx.x;
  int b = blk >> 7, cb = (blk >> 3) & 15, ns = blk & 7;
  int n0 = cb * 64 + wv * 16;
  bf16x8 wh[KS], wm[KS], wl[KS];
  size_t wo = (size_t)(n0 + l16) * K + quad * 8;
#pragma unroll
  for (int s = 0; s < KS; ++s) {
    wh[s] = *(const bf16x8*)(Bh + wo + s * 32);
    wm[s] = *(const bf16x8*)(Bm + wo + s * 32);
    wl[s] = *(const bf16x8*)(Bl + wo + s * 32);
  }
  size_t ao = ((size_t)b * Nn + ns * 512 + l16) * K + quad * 8;
  float rmax = -INFINITY;
#pragma unroll 1
  for (int mt = 0; mt < 32; ++mt) {
    size_t ar = ao + (size_t)mt * 16 * K;
    f32x4 acc = {0.f, 0.f, 0.f, 0.f};
#pragma unroll
    for (int s = 0; s < KS; ++s) {
      bf16x8 xh = *(const bf16x8*)(Ah + ar + s * 32);
      bf16x8 xm = *(const bf16x8*)(Am + ar + s * 32);
      bf16x8 xl = *(const bf16x8*)(Al + ar + s * 32);
      acc = __builtin_amdgcn_mfma_f32_16x16x32_bf16(xh, wh[s], acc, 0, 0, 0);
      acc = __builtin_amdgcn_mfma_f32_16x16x32_bf16(xh, wm[s], acc, 0, 0, 0);
      acc = __builtin_amdgcn_mfma_f32_16x16x32_bf16(xm, wh[s], acc, 0, 0, 0);
      acc = __builtin_amdgcn_mfma_f32_16x16x32_bf16(xh, wl[s], acc, 0, 0, 0);
      acc = __builtin_amdgcn_mfma_f32_16x16x32_bf16(xl, wh[s], acc, 0, 0, 0);
      acc = __builtin_amdgcn_mfma_f32_16x16x32_bf16(xm, wm[s], acc, 0, 0, 0);
    }
    rmax = fmaxf(rmax, fmaxf(fmaxf(acc[0], acc[1]), fmaxf(acc[2], acc[3])));
  }
  rmax = fmaxf(rmax, __shfl_xor(rmax, 16, 64));
  rmax = fmaxf(rmax, __shfl_xor(rmax, 32, 64));
  if (quad == 0) outp[((size_t)b * 8 + ns) * 1024 + n0 + l16] = rmax;
}

// ---------------- gc = relu(max+b) @ c2w[:1024] (fp32) --------------------
__global__ __launch_bounds__(256) void k_j2(const float* __restrict__ gpart, const float* __restrict__ c1b,
                                            const float* __restrict__ c2w, float* __restrict__ gc) {
  __shared__ float g[1024];
  int t = threadIdx.x;
  int b = blockIdx.x >> 1, half = blockIdx.x & 1;
  for (int e = t; e < 1024; e += 256) {
    float m = -INFINITY;
#pragma unroll
    for (int s = 0; s < 8; ++s) m = fmaxf(m, gpart[((size_t)b * 8 + s) * 1024 + e]);
    g[e] = fmaxf(m + c1b[e], 0.f);
  }
  __syncthreads();
  int d = half * 256 + t;
  float acc = 0.f;
  for (int j = 0; j < 1024; ++j) acc = fmaf(g[j], c2w[(size_t)j * 512 + d], acc);
  gc[(size_t)b * 512 + d] = acc;
}

// ---------------- fused MFMA head: 192->512->256->2 per 16 points ---------
__global__ __launch_bounds__(256) void k_final(const unsigned short* __restrict__ xcat,
                                               const float* __restrict__ gc,
                                               const float* __restrict__ c2b,
                                               const unsigned short* __restrict__ c2wT,
                                               const unsigned short* __restrict__ c3wT,
                                               const float* __restrict__ c3b,
                                               const float* __restrict__ c4w, const float* __restrict__ c4b,
                                               float* __restrict__ out) {
  __shared__ unsigned short z5[16 * 520];
  __shared__ float z2[16 * 260];
  int t = threadIdx.x;
  int wv = t >> 6, lane = t & 63;
  int quad = lane >> 4, l16 = lane & 15;
  int p0 = blockIdx.x * 16;
  int b = p0 >> 12;
  bf16x8 a1[6];
  const unsigned short* ar = xcat + (size_t)(p0 + l16) * 192 + quad * 8;
#pragma unroll
  for (int s = 0; s < 6; ++s) a1[s] = *(const bf16x8*)(ar + s * 32);
#pragma unroll 1
  for (int ntw = 0; ntw < 8; ++ntw) {
    int col = wv * 128 + ntw * 16 + l16;
    float bias = gc[(size_t)b * 512 + col] + c2b[col];
    f32x4 acc = {bias, bias, bias, bias};
    const unsigned short* wr = c2wT + (size_t)col * 192 + quad * 8;
#pragma unroll
    for (int s = 0; s < 6; ++s) {
      bf16x8 bfr = *(const bf16x8*)(wr + s * 32);
      acc = __builtin_amdgcn_mfma_f32_16x16x32_bf16(a1[s], bfr, acc, 0, 0, 0);
    }
#pragma unroll
    for (int r = 0; r < 4; ++r)
      z5[(quad * 4 + r) * 520 + col] = f2bf(fmaxf(acc[r], 0.f));
  }
  __syncthreads();
  bf16x8 a2[16];
#pragma unroll
  for (int s = 0; s < 16; ++s) a2[s] = *(const bf16x8*)(z5 + l16 * 520 + s * 32 + quad * 8);
#pragma unroll 1
  for (int ntw = 0; ntw < 4; ++ntw) {
    int col = wv * 64 + ntw * 16 + l16;
    float bias = c3b[col];
    f32x4 acc = {bias, bias, bias, bias};
    const unsigned short* wr = c3wT + (size_t)col * 512 + quad * 8;
#pragma unroll
    for (int s = 0; s < 16; ++s) {
      bf16x8 bfr = *(const bf16x8*)(wr + s * 32);
      acc = __builtin_amdgcn_mfma_f32_16x16x32_bf16(a2[s], bfr, acc, 0, 0, 0);
    }
#pragma unroll
    for (int r = 0; r < 4; ++r)
      z2[(quad * 4 + r) * 260 + col] = fmaxf(acc[r], 0.f);
  }
  __syncthreads();
  if (t < 32) {
    int m = t >> 1, e = t & 1;
    float acc = c4b[e];
    const float* zr = z2 + m * 260;
    for (int j = 0; j < 256; ++j) acc = fmaf(zr[j], c4w[j * 2 + e], acc);
    out[(size_t)(p0 + m) * 2 + e] = acc;
  }
}

// ===========================================================================
extern "C" void kernel_launch(void* const* d_in, const int* in_sizes, int n_in,
                              void* d_out, int out_size, void* d_ws, size_t ws_size,
                              hipStream_t stream) {
  const float* xin = (const float*)d_in[0];
  const float* W[30];
  for (int i = 0; i < 30; ++i) W[i] = (const float*)d_in[i + 1];

  float* ws = (float*)d_ws;
  size_t off = 0;
  float* pts   = ws + off; off += (size_t)BN * 3;
  float* p     = ws + off; off += (size_t)BN * 3;
  int*   idx   = (int*)(ws + off); off += (size_t)BN * KK;
  float* sq    = ws + off; off += BN;
  float* t128  = ws + off; off += (size_t)BN * 128;
  float* dpart = ws + off; off += 4 * 8 * 1024;
  float* h1    = ws + off; off += 4 * 512;
  float* x1    = ws + off; off += (size_t)BN * 64;
  float* x2    = ws + off; off += (size_t)BN * 64;
  float* x3    = ws + off; off += (size_t)BN * 64;
  float* gpart = ws + off; off += 4 * 8 * 1024;
  float* gc    = ws + off; off += 4 * 512;
  unsigned short* xcat = (unsigned short*)(ws + off); off += (size_t)BN * 96;
  unsigned short* c1wT = (unsigned short*)(ws + off); off += 98304;
  unsigned short* c2wT = (unsigned short*)(ws + off); off += 49152;
  unsigned short* c3wT = (unsigned short*)(ws + off); off += 65536;
  unsigned short* w3Th = (unsigned short*)(ws + off); off += 65536;   // 1024x128 bf16
  unsigned short* w3Tm = (unsigned short*)(ws + off); off += 65536;
  unsigned short* w3Tl = (unsigned short*)(ws + off); off += 65536;
  unsigned short* xsh  = (unsigned short*)(ws + off); off += 524288;  // BN*64 bf16
  unsigned short* xsm  = (unsigned short*)(ws + off); off += 524288;
  unsigned short* xsl  = (unsigned short*)(ws + off); off += 524288;
  float* Md    = ws + off; off += 8192;
  float* Dbuf  = ws + off; off += (size_t)Nn * Nn;
  // overlays on Dbuf (dead before first k_dist3s / after last k_sel):
  unsigned short* t3h = (unsigned short*)Dbuf;                 // BN*128 bf16
  unsigned short* t3m = t3h + (size_t)BN * 128;
  unsigned short* t3l = t3m + (size_t)BN * 128;
  float* uv = Dbuf;                                            // BN*128 fp32

  // weight prep
  k_cvtT<<<dim3(768), dim3(256), 0, stream>>>(W[22], c1wT, 1024, 192, 1024, 0);
  k_cvtT<<<dim3(384), dim3(256), 0, stream>>>(W[24], c2wT, 512, 192, 512, 1024);
  k_cvtT<<<dim3(512), dim3(256), 0, stream>>>(W[26], c3wT, 256, 512, 256, 0);
  k_cvtT3<<<dim3(512), dim3(256), 0, stream>>>(W[4], w3Th, w3Tm, w3Tl, 1024, 128, 1024);
  k_prepD<<<dim3(32), dim3(256), 0, stream>>>(W[20], Md);

  k_pts<<<dim3(192), dim3(256), 0, stream>>>(xin, pts);

  // stage 1: transform branch
  k_knn3<<<dim3(1024), dim3(1024), 0, stream>>>(pts, idx);
  k_edge3<128><<<dim3(1024), dim3(256), 0, stream>>>(pts, idx, W[0], W[1], W[2], W[3], t128);
  k_split3<<<dim3(8192), dim3(256), 0, stream>>>(t128, t3h, t3m, t3l, BN * 128);
  k_mgemm3s<128><<<dim3(512), dim3(256), 0, stream>>>(t3h, t3m, t3l, w3Th, w3Tm, w3Tl, dpart);
  k_fc1<<<dim3(32), dim3(256), 0, stream>>>(dpart, W[5], W[6], W[7], h1);
  k_fc23p<<<dim3(4), dim3(256), 0, stream>>>(h1, W[8], W[9], W[10], W[11], pts, p);

  // stage 2
  k_knn3<<<dim3(1024), dim3(1024), 0, stream>>>(p, idx);
  k_edge3<64><<<dim3(1024), dim3(256), 0, stream>>>(p, idx, W[12], W[13], W[14], W[15], x1);
  k_sqnorm<<<dim3(64), dim3(256), 0, stream>>>(x1, sq);
  k_split3<<<dim3(4096), dim3(256), 0, stream>>>(x1, xsh, xsm, xsl, BN * 64);
  for (int b = 0; b < 4; ++b) {
    k_dist3s<<<dim3(4096), dim3(256), 0, stream>>>(xsh, xsm, xsl, sq, b, Dbuf);
    k_sel<<<dim3(1024), dim3(256), 0, stream>>>(Dbuf, b, idx);
  }
  k_edgeC<<<dim3(1024), dim3(256), 0, stream>>>(x1, idx, W[16], W[17], W[18], W[19], x2);
  k_sqnorm<<<dim3(64), dim3(256), 0, stream>>>(x2, sq);
  k_split3<<<dim3(4096), dim3(256), 0, stream>>>(x2, xsh, xsm, xsl, BN * 64);
  for (int b = 0; b < 4; ++b) {
    k_dist3s<<<dim3(4096), dim3(256), 0, stream>>>(xsh, xsm, xsl, sq, b, Dbuf);
    k_sel<<<dim3(1024), dim3(256), 0, stream>>>(Dbuf, b, idx);
  }
  // edgeD via u/v factorization (uv overlays Dbuf, which is now dead)
  k_uv<<<dim3(256), dim3(256), 0, stream>>>(x2, Md, uv);
  k_gmax<<<dim3(4096), dim3(256), 0, stream>>>(uv, idx, W[21], x3);

  // stage 3
  k_cat<<<dim3(12288), dim3(256), 0, stream>>>(x1, x2, x3, xcat);
  k_mgemm<192><<<dim3(512), dim3(256), 0, stream>>>(xcat, c1wT, gpart);
  k_j2<<<dim3(8), dim3(256), 0, stream>>>(gpart, W[23], W[24], gc);
  k_final<<<dim3(1024), dim3(256), 0, stream>>>(xcat, gc, W[25], c2wT, c3wT,
                                                W[27], W[28], W[29], (float*)d_out);
}

// Round 8
// 1924.385 us; speedup vs baseline: 3.1181x; 1.0754x over previous
//
#include <hip/hip_runtime.h>

#define Nn 4096
#define KK 20
#define BN 16384   // B*N, B=4

typedef __attribute__((ext_vector_type(8))) short bf16x8;
typedef __attribute__((ext_vector_type(4))) float f32x4;

__device__ __forceinline__ unsigned short f2bf(float f) {
  unsigned int x = __float_as_uint(f);
  return (unsigned short)((x + 0x7fffu + ((x >> 16) & 1u)) >> 16);
}
__device__ __forceinline__ float bf2f(unsigned short u) {
  return __uint_as_float(((unsigned int)u) << 16);
}

// ---------------- extract pts = x[:,:,:3] ---------------------------------
__global__ void k_pts(const float* __restrict__ x, float* __restrict__ pts) {
  int i = blockIdx.x * 256 + threadIdx.x;
  if (i < BN * 3) {
    int pt = i / 3, c = i - 3 * pt;
    pts[i] = x[pt * 6 + c];
  }
}

// ---------------- weight convert+transpose to bf16 ------------------------
__global__ void k_cvtT(const float* __restrict__ src, unsigned short* __restrict__ dst,
                       int N, int K, int ldn, int row0) {
  int i = blockIdx.x * 256 + threadIdx.x;
  if (i >= N * K) return;
  int n = i / K, k = i - n * K;
  dst[i] = f2bf(src[(size_t)(row0 + k) * ldn + n]);
}

// ---------------- transpose + 3-way bf16 split ----------------------------
__global__ void k_cvtT3(const float* __restrict__ src, unsigned short* __restrict__ h,
                        unsigned short* __restrict__ m, unsigned short* __restrict__ l,
                        int N, int K, int ldn) {
  int i = blockIdx.x * 256 + threadIdx.x;
  if (i >= N * K) return;
  int n = i / K, k = i - n * K;
  float x = src[(size_t)k * ldn + n];
  unsigned short hh = f2bf(x); float xh = bf2f(hh);
  unsigned short mm = f2bf(x - xh); float xm = bf2f(mm);
  unsigned short ll = f2bf(x - xh - xm);
  h[i] = hh; m[i] = mm; l[i] = ll;
}

// ---------------- 3-way bf16 split (row-major passthrough) ----------------
__global__ void k_split3(const float* __restrict__ src, unsigned short* __restrict__ h,
                         unsigned short* __restrict__ m, unsigned short* __restrict__ l, int n) {
  int i = blockIdx.x * 256 + threadIdx.x;
  if (i >= n) return;
  float x = src[i];
  unsigned short hh = f2bf(x); float xh = bf2f(hh);
  unsigned short mm = f2bf(x - xh); float xm = bf2f(mm);
  unsigned short ll = f2bf(x - xh - xm);
  h[i] = hh; m[i] = mm; l[i] = ll;
}

// ---------------- xcat bf16 [pt][192] = [x1|x2|x3] ------------------------
__global__ void k_cat(const float* __restrict__ x1, const float* __restrict__ x2,
                      const float* __restrict__ x3, unsigned short* __restrict__ xcat) {
  int i = blockIdx.x * 256 + threadIdx.x;
  int pt = i / 192, j = i - pt * 192;
  float v = (j < 64) ? x1[pt * 64 + j] : (j < 128 ? x2[pt * 64 + j - 64] : x3[pt * 64 + j - 128]);
  xcat[i] = f2bf(v);
}

// ---------------- exact top-20 selection, one wave per query ---------------
__device__ __forceinline__ void topk_select(const float (&d)[64], float m1, int t1, float m2, int t2,
                                            int lane, int* __restrict__ op) {
  unsigned long long removed = 0ull;
  bool have2 = true;
  int sel = 0;
#pragma unroll 1
  for (int k = 0; k < 20; ++k) {
    float v = m1; int ci = (t1 << 6) | lane;
#pragma unroll
    for (int off = 32; off; off >>= 1) {
      float ov = __shfl_xor(v, off, 64);
      int   oi = __shfl_xor(ci, off, 64);
      if (ov > v || (ov == v && oi < ci)) { v = ov; ci = oi; }
    }
    if (k == lane) sel = ci;
    if ((ci & 63) == lane && (ci >> 6) == t1) {
      removed |= 1ull << t1;
      if (have2) { m1 = m2; t1 = t2; have2 = false; }
      else {
        m1 = -INFINITY; t1 = 0; m2 = -INFINITY; t2 = 0;
#pragma unroll
        for (int tt = 0; tt < 64; ++tt) {
          if (!((removed >> tt) & 1ull)) {
            float dv = d[tt];
            if (dv > m1) { m2 = m1; t2 = t1; m1 = dv; t1 = tt; }
            else if (dv > m2) { m2 = dv; t2 = tt; }
          }
        }
        have2 = true;
      }
    }
  }
  if (lane < 20) op[lane] = sel;
}

__device__ __forceinline__ int gi_map(int tt, int lane) {
  return ((tt >> 2) << 8) | (lane << 2) | (tt & 3);
}
__device__ __forceinline__ void topk_select2(const float (&d)[64], float m1, int t1, float m2, int t2,
                                             int lane, int* __restrict__ op) {
  unsigned long long removed = 0ull;
  bool have2 = true;
  int sel = 0;
#pragma unroll 1
  for (int k = 0; k < 20; ++k) {
    float v = m1; int ci = gi_map(t1, lane);
#pragma unroll
    for (int off = 32; off; off >>= 1) {
      float ov = __shfl_xor(v, off, 64);
      int   oi = __shfl_xor(ci, off, 64);
      if (ov > v || (ov == v && oi < ci)) { v = ov; ci = oi; }
    }
    if (k == lane) sel = ci;
    if (ci == gi_map(t1, lane)) {
      removed |= 1ull << t1;
      if (have2) { m1 = m2; t1 = t2; have2 = false; }
      else {
        m1 = -INFINITY; t1 = 0; m2 = -INFINITY; t2 = 0;
#pragma unroll
        for (int tt = 0; tt < 64; ++tt) {
          if (!((removed >> tt) & 1ull)) {
            float dv = d[tt];
            if (dv > m1) { m2 = m1; t2 = t1; m1 = dv; t1 = tt; }
            else if (dv > m2) { m2 = dv; t2 = tt; }
          }
        }
        have2 = true;
      }
    }
  }
  if (lane < 20) op[lane] = sel;
}

// ---------------- kNN, C=3 ------------------------------------------------
__global__ __launch_bounds__(1024) void k_knn3(const float* __restrict__ src, int* __restrict__ idx) {
  __shared__ float tile[Nn * 3];
  int t = threadIdx.x;
  int wave = t >> 6, lane = t & 63;
  int g = blockIdx.x * 16 + wave;
  int b = g >> 12, n = g & (Nn - 1);
  const float* base = src + (size_t)b * Nn * 3;
  for (int e = t; e < Nn * 3; e += 1024) tile[e] = base[e];
  __syncthreads();
  float qx = tile[n * 3 + 0], qy = tile[n * 3 + 1], qz = tile[n * 3 + 2];
  float qsq = qx * qx + qy * qy + qz * qz;
  float d[64];
  float m1 = -INFINITY, m2 = -INFINITY; int t1 = 0, t2 = 0;
#pragma unroll
  for (int tt = 0; tt < 64; ++tt) {
    int c = (tt << 6) + lane;
    float mx = tile[c * 3], my = tile[c * 3 + 1], mz = tile[c * 3 + 2];
    float msq = mx * mx + my * my + mz * mz;
    float dd = 2.0f * (qx * mx + qy * my + qz * mz) - qsq - msq;
    d[tt] = dd;
    if (dd > m1) { m2 = m1; t2 = t1; m1 = dd; t1 = tt; }
    else if (dd > m2) { m2 = dd; t2 = tt; }
  }
  topk_select(d, m1, t1, m2, t2, lane, idx + (size_t)g * KK);
}

// ---------------- sq norms ------------------------------------------------
__global__ void k_sqnorm(const float* __restrict__ src, float* __restrict__ out) {
  int g = blockIdx.x * 256 + threadIdx.x;
  if (g >= BN) return;
  const float4* r = (const float4*)(src + (size_t)g * 64);
  float s = 0.f;
#pragma unroll
  for (int j = 0; j < 16; ++j) { float4 v = r[j]; s += v.x * v.x + v.y * v.y + v.z * v.z + v.w * v.w; }
  out[g] = s;
}

// ---------------- distance GEMM via 3-split bf16 MFMA ---------------------
__global__ __launch_bounds__(256) void k_dist3s(const unsigned short* __restrict__ Xh,
                                                const unsigned short* __restrict__ Xm,
                                                const unsigned short* __restrict__ Xl,
                                                const float* __restrict__ sq,
                                                int b, float* __restrict__ D) {
  int t = threadIdx.x;
  int wv = t >> 6, lane = t & 63;
  int quad = lane >> 4, l16 = lane & 15;
  int wx = wv & 1, wy = wv >> 1;
  int bx = blockIdx.x & 63, by = blockIdx.x >> 6;
  const size_t base = (size_t)b * Nn * 64;
  int ra0 = by * 64 + wy * 32;
  int cb0 = bx * 64 + wx * 32;
  f32x4 acc[2][2];
  f32x4 zz = {0.f, 0.f, 0.f, 0.f};
#pragma unroll
  for (int i = 0; i < 2; ++i)
#pragma unroll
    for (int j = 0; j < 2; ++j) acc[i][j] = zz;
#pragma unroll
  for (int ks = 0; ks < 2; ++ks) {
    int ko = ks * 32 + quad * 8;
    bf16x8 ah[2], am[2], al[2], bh[2], bm[2], bl[2];
#pragma unroll
    for (int ti = 0; ti < 2; ++ti) {
      size_t ra = base + (size_t)(ra0 + ti * 16 + l16) * 64 + ko;
      ah[ti] = *(const bf16x8*)(Xh + ra);
      am[ti] = *(const bf16x8*)(Xm + ra);
      al[ti] = *(const bf16x8*)(Xl + ra);
      size_t rb = base + (size_t)(cb0 + ti * 16 + l16) * 64 + ko;
      bh[ti] = *(const bf16x8*)(Xh + rb);
      bm[ti] = *(const bf16x8*)(Xm + rb);
      bl[ti] = *(const bf16x8*)(Xl + rb);
    }
#pragma unroll
    for (int ti = 0; ti < 2; ++ti)
#pragma unroll
      for (int tj = 0; tj < 2; ++tj) {
        f32x4 a = acc[ti][tj];
        a = __builtin_amdgcn_mfma_f32_16x16x32_bf16(ah[ti], bh[tj], a, 0, 0, 0);
        a = __builtin_amdgcn_mfma_f32_16x16x32_bf16(ah[ti], bm[tj], a, 0, 0, 0);
        a = __builtin_amdgcn_mfma_f32_16x16x32_bf16(am[ti], bh[tj], a, 0, 0, 0);
        a = __builtin_amdgcn_mfma_f32_16x16x32_bf16(ah[ti], bl[tj], a, 0, 0, 0);
        a = __builtin_amdgcn_mfma_f32_16x16x32_bf16(al[ti], bh[tj], a, 0, 0, 0);
        a = __builtin_amdgcn_mfma_f32_16x16x32_bf16(am[ti], bm[tj], a, 0, 0, 0);
        acc[ti][tj] = a;
      }
  }
  const float* sqb = sq + b * Nn;
#pragma unroll
  for (int ti = 0; ti < 2; ++ti) {
    int row0 = ra0 + ti * 16 + quad * 4;
#pragma unroll
    for (int tj = 0; tj < 2; ++tj) {
      int col = cb0 + tj * 16 + l16;
      float sqc = sqb[col];
#pragma unroll
      for (int r = 0; r < 4; ++r)
        D[(size_t)(row0 + r) * 4096 + col] = 2.0f * acc[ti][tj][r] - sqb[row0 + r] - sqc;
    }
  }
}

// ---------------- top-20 over D rows --------------------------------------
__global__ __launch_bounds__(256) void k_sel(const float* __restrict__ D, int b, int* __restrict__ idx) {
  int t = threadIdx.x;
  int wave = t >> 6, lane = t & 63;
  int q = blockIdx.x * 4 + wave;
  const float* row = D + (size_t)q * 4096;
  float d[64];
  float m1 = -INFINITY, m2 = -INFINITY; int t1 = 0, t2 = 0;
#pragma unroll
  for (int i = 0; i < 16; ++i) {
    float4 v = *(const float4*)(row + i * 256 + lane * 4);
    float vv[4] = {v.x, v.y, v.z, v.w};
#pragma unroll
    for (int j = 0; j < 4; ++j) {
      int tt = i * 4 + j;
      float dd = vv[j];
      d[tt] = dd;
      if (dd > m1) { m2 = m1; t2 = t1; m1 = dd; t1 = tt; }
      else if (dd > m2) { m2 = dd; t2 = tt; }
    }
  }
  topk_select2(d, m1, t1, m2, t2, lane, idx + (size_t)(b * Nn + q) * KK);
}

// ---------------- u/v from pts (6->64 conv1 factorized) -------------------
// u = b1 + cen·(Wa-Wb), v = nb·Wb ; uvb[p][0:64]=u, [64:128]=v
__global__ __launch_bounds__(256) void k_uv3(const float* __restrict__ pts, const float* __restrict__ w1,
                                             const float* __restrict__ b1, float* __restrict__ uvb) {
  __shared__ float sw[384];
  __shared__ float sb[64];
  int t = threadIdx.x;
  for (int e = t; e < 384; e += 256) sw[e] = w1[e];
  if (t < 64) sb[t] = b1[t];
  __syncthreads();
  int pl = t >> 6, c = t & 63;
  int p = blockIdx.x * 4 + pl;
  const float* pr = pts + (size_t)p * 3;
  float x0 = pr[0], x1 = pr[1], x2 = pr[2];
  float wb0 = sw[192 + c], wb1 = sw[256 + c], wb2 = sw[320 + c];
  float v = x0 * wb0 + x1 * wb1 + x2 * wb2;
  float u = sb[c] + x0 * (sw[c] - wb0) + x1 * (sw[64 + c] - wb1) + x2 * (sw[128 + c] - wb2);
  uvb[(size_t)p * 128 + c] = u;
  uvb[(size_t)p * 128 + 64 + c] = v;
}

// ---------------- prep: Md[64][128] = [Wa-Wb | Wb] from 128x64 w1 ---------
__global__ void k_prepD(const float* __restrict__ w1, float* __restrict__ Md) {
  int i = blockIdx.x * 256 + threadIdx.x;
  if (i >= 8192) return;
  int j = i >> 7, c = i & 127;
  Md[i] = (c < 64) ? (w1[j * 64 + c] - w1[(64 + j) * 64 + c]) : w1[(64 + j) * 64 + (c - 64)];
}

// ---------------- uv = x @ Md (+bias on u half) ---------------------------
__global__ __launch_bounds__(256) void k_uv(const float* __restrict__ x2, const float* __restrict__ Md,
                                            const float* __restrict__ bias, float* __restrict__ uv) {
  __shared__ float sM[8192];     // 64x128
  __shared__ float sx[64 * 68];
  int t = threadIdx.x;
  for (int e = t; e < 8192; e += 256) sM[e] = Md[e];
  int p0 = blockIdx.x * 64;
  for (int e = t; e < 1024; e += 256) {
    int r = e >> 4, c4 = e & 15;
    *(float4*)(sx + r * 68 + c4 * 4) = *(const float4*)(x2 + (size_t)(p0 + r) * 64 + c4 * 4);
  }
  __syncthreads();
  int c = t & 127, rg = t >> 7;
  float badd = (c < 64) ? bias[c] : 0.f;
  float accv[32];
#pragma unroll
  for (int r = 0; r < 32; ++r) accv[r] = 0.f;
#pragma unroll
  for (int jc = 0; jc < 8; ++jc) {
    float mreg[8];
#pragma unroll
    for (int q = 0; q < 8; ++q) mreg[q] = sM[(jc * 8 + q) * 128 + c];
#pragma unroll
    for (int r = 0; r < 32; ++r) {
      const float* xr = sx + (rg * 32 + r) * 68 + jc * 8;
      float4 a = *(const float4*)xr, bb = *(const float4*)(xr + 4);
      float s = accv[r];
      s = fmaf(a.x, mreg[0], s); s = fmaf(a.y, mreg[1], s);
      s = fmaf(a.z, mreg[2], s); s = fmaf(a.w, mreg[3], s);
      s = fmaf(bb.x, mreg[4], s); s = fmaf(bb.y, mreg[5], s);
      s = fmaf(bb.z, mreg[6], s); s = fmaf(bb.w, mreg[7], s);
      accv[r] = s;
    }
  }
#pragma unroll
  for (int r = 0; r < 32; ++r)
    uv[(size_t)(p0 + rg * 32 + r) * 128 + c] = accv[r] + badd;
}

// ---------------- per-edge conv2 via 3-split MFMA + max over edges --------
// wave = one point: y1_k = relu(u + v_nbk) built in LDS (bf16 h/m/l, stride 72),
// A = 20 edges (2 m-tiles, rows 20..31 garbage -> masked), B = W2T (n-major).
template <int NOUT>
__global__ __launch_bounds__(256) void k_econv(const float* __restrict__ uv,
                                               const int* __restrict__ idx,
                                               const unsigned short* __restrict__ W2h,
                                               const unsigned short* __restrict__ W2m,
                                               const unsigned short* __restrict__ W2l,
                                               const float* __restrict__ b2,
                                               float* __restrict__ outp) {
  __shared__ unsigned short y3[4][3][32 * 72];   // 55296 B
  int t = threadIdx.x;
  int wv = t >> 6, lane = t & 63;
  int quad = lane >> 4, l16 = lane & 15;
  int p = blockIdx.x * 4 + wv;
  size_t nbase = (size_t)(p >> 12) * Nn;
  const int* ip = idx + (size_t)p * KK;
  float u = uv[(size_t)p * 128 + lane];
  unsigned short* yh = y3[wv][0];
  unsigned short* ym = y3[wv][1];
  unsigned short* yl = y3[wv][2];
#pragma unroll
  for (int k = 0; k < 20; ++k) {
    int nb = ip[k];
    float v = uv[(nbase + nb) * 128 + 64 + lane];
    float y = fmaxf(u + v, 0.f);
    unsigned short hh = f2bf(y); float fh = bf2f(hh);
    unsigned short mm = f2bf(y - fh); float fm = bf2f(mm);
    unsigned short ll = f2bf(y - fh - fm);
    yh[k * 72 + lane] = hh;
    ym[k * 72 + lane] = mm;
    yl[k * 72 + lane] = ll;
  }
  __syncthreads();
  bf16x8 af[2][2][3];
#pragma unroll
  for (int mt = 0; mt < 2; ++mt)
#pragma unroll
    for (int ks = 0; ks < 2; ++ks) {
      int ro = (mt * 16 + l16) * 72 + ks * 32 + quad * 8;
      af[mt][ks][0] = *(const bf16x8*)(yh + ro);
      af[mt][ks][1] = *(const bf16x8*)(ym + ro);
      af[mt][ks][2] = *(const bf16x8*)(yl + ro);
    }
#pragma unroll 1
  for (int nt = 0; nt < NOUT / 16; ++nt) {
    int col = nt * 16 + l16;
    f32x4 a0 = {0.f, 0.f, 0.f, 0.f}, a1 = {0.f, 0.f, 0.f, 0.f};
#pragma unroll
    for (int ks = 0; ks < 2; ++ks) {
      size_t wo = (size_t)col * 64 + ks * 32 + quad * 8;
      bf16x8 wh = *(const bf16x8*)(W2h + wo);
      bf16x8 wm = *(const bf16x8*)(W2m + wo);
      bf16x8 wl = *(const bf16x8*)(W2l + wo);
      a0 = __builtin_amdgcn_mfma_f32_16x16x32_bf16(af[0][ks][0], wh, a0, 0, 0, 0);
      a0 = __builtin_amdgcn_mfma_f32_16x16x32_bf16(af[0][ks][0], wm, a0, 0, 0, 0);
      a0 = __builtin_amdgcn_mfma_f32_16x16x32_bf16(af[0][ks][1], wh, a0, 0, 0, 0);
      a0 = __builtin_amdgcn_mfma_f32_16x16x32_bf16(af[0][ks][0], wl, a0, 0, 0, 0);
      a0 = __builtin_amdgcn_mfma_f32_16x16x32_bf16(af[0][ks][2], wh, a0, 0, 0, 0);
      a0 = __builtin_amdgcn_mfma_f32_16x16x32_bf16(af[0][ks][1], wm, a0, 0, 0, 0);
      a1 = __builtin_amdgcn_mfma_f32_16x16x32_bf16(af[1][ks][0], wh, a1, 0, 0, 0);
      a1 = __builtin_amdgcn_mfma_f32_16x16x32_bf16(af[1][ks][0], wm, a1, 0, 0, 0);
      a1 = __builtin_amdgcn_mfma_f32_16x16x32_bf16(af[1][ks][1], wh, a1, 0, 0, 0);
      a1 = __builtin_amdgcn_mfma_f32_16x16x32_bf16(af[1][ks][0], wl, a1, 0, 0, 0);
      a1 = __builtin_amdgcn_mfma_f32_16x16x32_bf16(af[1][ks][2], wh, a1, 0, 0, 0);
      a1 = __builtin_amdgcn_mfma_f32_16x16x32_bf16(af[1][ks][1], wm, a1, 0, 0, 0);
    }
    // max over edges: m-tile0 rows = edges 0-15 (all valid); m-tile1 rows 0-3
    // (quad 0) = edges 16-19, rest garbage -> -inf.
    float m0 = fmaxf(fmaxf(a0[0], a0[1]), fmaxf(a0[2], a0[3]));
    float m1v = (quad == 0) ? fmaxf(fmaxf(a1[0], a1[1]), fmaxf(a1[2], a1[3])) : -INFINITY;
    float m = fmaxf(m0, m1v);
    m = fmaxf(m, __shfl_xor(m, 16, 64));
    m = fmaxf(m, __shfl_xor(m, 32, 64));
    if (quad == 0) outp[(size_t)p * NOUT + col] = fmaxf(m + b2[col], 0.f);
  }
}

// ---------------- x3 = relu(u + max_k v_nk)  (bias folded into u) ---------
__global__ __launch_bounds__(256) void k_gmax(const float* __restrict__ uv, const int* __restrict__ idx,
                                              float* __restrict__ x3) {
  __shared__ int sidx[4][20];
  int t = threadIdx.x;
  int pl = t >> 6, c = t & 63;
  int p0 = blockIdx.x * 4;
  if (t < 80) sidx[t / 20][t % 20] = idx[(size_t)(p0 + t / 20) * KK + (t % 20)];
  __syncthreads();
  int p = p0 + pl;
  size_t nbase = (size_t)(p >> 12) * Nn;
  float u = uv[(size_t)p * 128 + c];
  float m = -INFINITY;
#pragma unroll
  for (int k = 0; k < 20; ++k) m = fmaxf(m, uv[(nbase + sidx[pl][k]) * 128 + 64 + c]);
  x3[(size_t)p * 64 + c] = fmaxf(u + m, 0.f);
}

// ---------------- reduce partials + fc1 -----------------------------------
__global__ __launch_bounds__(256) void k_fc1(const float* __restrict__ dpart, const float* __restrict__ tb3,
                                             const float* __restrict__ tfw1, const float* __restrict__ tfb1,
                                             float* __restrict__ h1) {
  __shared__ float tv[1024];
  __shared__ float ps[256];
  int t = threadIdx.x;
  int b = blockIdx.x >> 3, cb = blockIdx.x & 7;
  for (int e = t; e < 1024; e += 256) {
    float m = -INFINITY;
#pragma unroll
    for (int s = 0; s < 8; ++s) m = fmaxf(m, dpart[((size_t)b * 8 + s) * 1024 + e]);
    tv[e] = fmaxf(m + tb3[e], 0.f);
  }
  __syncthreads();
  int c = cb * 64 + (t & 63), jg = t >> 6;
  float acc = 0.f;
  for (int j = jg * 256; j < jg * 256 + 256; ++j) acc = fmaf(tv[j], tfw1[(size_t)j * 512 + c], acc);
  ps[t] = acc;
  __syncthreads();
  if (t < 64) {
    float a = ps[t] + ps[64 + t] + ps[128 + t] + ps[192 + t] + tfb1[cb * 64 + t];
    h1[(size_t)b * 512 + cb * 64 + t] = fmaxf(a, 0.f);
  }
}

// ---------------- fc2, fc3, apply p = pts @ xf ----------------------------
__global__ __launch_bounds__(256) void k_fc23p(const float* __restrict__ h1, const float* __restrict__ tfw2,
                                               const float* __restrict__ tfb2, const float* __restrict__ txw,
                                               const float* __restrict__ txb, const float* __restrict__ pts,
                                               float* __restrict__ p) {
  __shared__ float sh1[512];
  __shared__ float h2[256];
  __shared__ float sxf[9];
  int t = threadIdx.x;
  int b = blockIdx.x;
  for (int e = t; e < 512; e += 256) sh1[e] = h1[(size_t)b * 512 + e];
  __syncthreads();
  {
    float acc = tfb2[t];
    for (int j = 0; j < 512; ++j) acc = fmaf(sh1[j], tfw2[(size_t)j * 256 + t], acc);
    h2[t] = fmaxf(acc, 0.f);
  }
  __syncthreads();
  if (t < 9) {
    float acc = txb[t];
    for (int j = 0; j < 256; ++j) acc = fmaf(h2[j], txw[j * 9 + t], acc);
    sxf[t] = acc;
  }
  __syncthreads();
  for (int n = t; n < Nn; n += 256) {
    const float* pr = pts + ((size_t)b * Nn + n) * 3;
    float a0 = pr[0], a1 = pr[1], a2 = pr[2];
    float* po = p + ((size_t)b * Nn + n) * 3;
#pragma unroll
    for (int d = 0; d < 3; ++d) po[d] = a0 * sxf[d] + a1 * sxf[3 + d] + a2 * sxf[6 + d];
  }
}

// ---------------- MFMA max-GEMM (bf16, post-kNN path) ---------------------
template <int K>
__global__ __launch_bounds__(256) void k_mgemm(const unsigned short* __restrict__ A,
                                               const unsigned short* __restrict__ WT,
                                               float* __restrict__ outp) {
  constexpr int KS = K / 32;
  int t = threadIdx.x;
  int wv = t >> 6, lane = t & 63;
  int quad = lane >> 4, l16 = lane & 15;
  int blk = blockIdx.x;
  int b = blk >> 7, cb = (blk >> 3) & 15, ns = blk & 7;
  int n0 = cb * 64 + wv * 16;
  bf16x8 bfr[KS];
  const unsigned short* wrow = WT + (size_t)(n0 + l16) * K + quad * 8;
#pragma unroll
  for (int s = 0; s < KS; ++s) bfr[s] = *(const bf16x8*)(wrow + s * 32);
  const unsigned short* Ab = A + ((size_t)b * Nn + ns * 512 + l16) * K + quad * 8;
  float rmax = -INFINITY;
#pragma unroll 2
  for (int mt = 0; mt < 32; ++mt) {
    const unsigned short* ar = Ab + (size_t)mt * 16 * K;
    f32x4 acc = {0.f, 0.f, 0.f, 0.f};
#pragma unroll
    for (int s = 0; s < KS; ++s) {
      bf16x8 af = *(const bf16x8*)(ar + s * 32);
      acc = __builtin_amdgcn_mfma_f32_16x16x32_bf16(af, bfr[s], acc, 0, 0, 0);
    }
    rmax = fmaxf(rmax, fmaxf(fmaxf(acc[0], acc[1]), fmaxf(acc[2], acc[3])));
  }
  rmax = fmaxf(rmax, __shfl_xor(rmax, 16, 64));
  rmax = fmaxf(rmax, __shfl_xor(rmax, 32, 64));
  if (quad == 0) outp[((size_t)b * 8 + ns) * 1024 + n0 + l16] = rmax;
}

// ---------------- MFMA max-GEMM, 3-split exact (t128 @ w3) ----------------
template <int K>
__global__ __launch_bounds__(256) void k_mgemm3s(const unsigned short* __restrict__ Ah,
                                                 const unsigned short* __restrict__ Am,
                                                 const unsigned short* __restrict__ Al,
                                                 const unsigned short* __restrict__ Bh,
                                                 const unsigned short* __restrict__ Bm,
                                                 const unsigned short* __restrict__ Bl,
                                                 float* __restrict__ outp) {
  constexpr int KS = K / 32;
  int t = threadIdx.x;
  int wv = t >> 6, lane = t & 63;
  int quad = lane >> 4, l16 = lane & 15;
  int blk = blockIdx.x;
  int b = blk >> 7, cb = (blk >> 3) & 15, ns = blk & 7;
  int n0 = cb * 64 + wv * 16;
  bf16x8 wh[KS], wm[KS], wl[KS];
  size_t wo = (size_t)(n0 + l16) * K + quad * 8;
#pragma unroll
  for (int s = 0; s < KS; ++s) {
    wh[s] = *(const bf16x8*)(Bh + wo + s * 32);
    wm[s] = *(const bf16x8*)(Bm + wo + s * 32);
    wl[s] = *(const bf16x8*)(Bl + wo + s * 32);
  }
  size_t ao = ((size_t)b * Nn + ns * 512 + l16) * K + quad * 8;
  float rmax = -INFINITY;
#pragma unroll 1
  for (int mt = 0; mt < 32; ++mt) {
    size_t ar = ao + (size_t)mt * 16 * K;
    f32x4 acc = {0.f, 0.f, 0.f, 0.f};
#pragma unroll
    for (int s = 0; s < KS; ++s) {
      bf16x8 xh = *(const bf16x8*)(Ah + ar + s * 32);
      bf16x8 xm = *(const bf16x8*)(Am + ar + s * 32);
      bf16x8 xl = *(const bf16x8*)(Al + ar + s * 32);
      acc = __builtin_amdgcn_mfma_f32_16x16x32_bf16(xh, wh[s], acc, 0, 0, 0);
      acc = __builtin_amdgcn_mfma_f32_16x16x32_bf16(xh, wm[s], acc, 0, 0, 0);
      acc = __builtin_amdgcn_mfma_f32_16x16x32_bf16(xm, wh[s], acc, 0, 0, 0);
      acc = __builtin_amdgcn_mfma_f32_16x16x32_bf16(xh, wl[s], acc, 0, 0, 0);
      acc = __builtin_amdgcn_mfma_f32_16x16x32_bf16(xl, wh[s], acc, 0, 0, 0);
      acc = __builtin_amdgcn_mfma_f32_16x16x32_bf16(xm, wm[s], acc, 0, 0, 0);
    }
    rmax = fmaxf(rmax, fmaxf(fmaxf(acc[0], acc[1]), fmaxf(acc[2], acc[3])));
  }
  rmax = fmaxf(rmax, __shfl_xor(rmax, 16, 64));
  rmax = fmaxf(rmax, __shfl_xor(rmax, 32, 64));
  if (quad == 0) outp[((size_t)b * 8 + ns) * 1024 + n0 + l16] = rmax;
}

// ---------------- gc = relu(max+b) @ c2w[:1024] (fp32) --------------------
__global__ __launch_bounds__(256) void k_j2(const float* __restrict__ gpart, const float* __restrict__ c1b,
                                            const float* __restrict__ c2w, float* __restrict__ gc) {
  __shared__ float g[1024];
  int t = threadIdx.x;
  int b = blockIdx.x >> 1, half = blockIdx.x & 1;
  for (int e = t; e < 1024; e += 256) {
    float m = -INFINITY;
#pragma unroll
    for (int s = 0; s < 8; ++s) m = fmaxf(m, gpart[((size_t)b * 8 + s) * 1024 + e]);
    g[e] = fmaxf(m + c1b[e], 0.f);
  }
  __syncthreads();
  int d = half * 256 + t;
  float acc = 0.f;
  for (int j = 0; j < 1024; ++j) acc = fmaf(g[j], c2w[(size_t)j * 512 + d], acc);
  gc[(size_t)b * 512 + d] = acc;
}

// ---------------- fused MFMA head: 192->512->256->2 per 16 points ---------
__global__ __launch_bounds__(256) void k_final(const unsigned short* __restrict__ xcat,
                                               const float* __restrict__ gc,
                                               const float* __restrict__ c2b,
                                               const unsigned short* __restrict__ c2wT,
                                               const unsigned short* __restrict__ c3wT,
                                               const float* __restrict__ c3b,
                                               const float* __restrict__ c4w, const float* __restrict__ c4b,
                                               float* __restrict__ out) {
  __shared__ unsigned short z5[16 * 520];
  __shared__ float z2[16 * 260];
  int t = threadIdx.x;
  int wv = t >> 6, lane = t & 63;
  int quad = lane >> 4, l16 = lane & 15;
  int p0 = blockIdx.x * 16;
  int b = p0 >> 12;
  bf16x8 a1[6];
  const unsigned short* ar = xcat + (size_t)(p0 + l16) * 192 + quad * 8;
#pragma unroll
  for (int s = 0; s < 6; ++s) a1[s] = *(const bf16x8*)(ar + s * 32);
#pragma unroll 1
  for (int ntw = 0; ntw < 8; ++ntw) {
    int col = wv * 128 + ntw * 16 + l16;
    float bias = gc[(size_t)b * 512 + col] + c2b[col];
    f32x4 acc = {bias, bias, bias, bias};
    const unsigned short* wr = c2wT + (size_t)col * 192 + quad * 8;
#pragma unroll
    for (int s = 0; s < 6; ++s) {
      bf16x8 bfr = *(const bf16x8*)(wr + s * 32);
      acc = __builtin_amdgcn_mfma_f32_16x16x32_bf16(a1[s], bfr, acc, 0, 0, 0);
    }
#pragma unroll
    for (int r = 0; r < 4; ++r)
      z5[(quad * 4 + r) * 520 + col] = f2bf(fmaxf(acc[r], 0.f));
  }
  __syncthreads();
  bf16x8 a2[16];
#pragma unroll
  for (int s = 0; s < 16; ++s) a2[s] = *(const bf16x8*)(z5 + l16 * 520 + s * 32 + quad * 8);
#pragma unroll 1
  for (int ntw = 0; ntw < 4; ++ntw) {
    int col = wv * 64 + ntw * 16 + l16;
    float bias = c3b[col];
    f32x4 acc = {bias, bias, bias, bias};
    const unsigned short* wr = c3wT + (size_t)col * 512 + quad * 8;
#pragma unroll
    for (int s = 0; s < 16; ++s) {
      bf16x8 bfr = *(const bf16x8*)(wr + s * 32);
      acc = __builtin_amdgcn_mfma_f32_16x16x32_bf16(a2[s], bfr, acc, 0, 0, 0);
    }
#pragma unroll
    for (int r = 0; r < 4; ++r)
      z2[(quad * 4 + r) * 260 + col] = fmaxf(acc[r], 0.f);
  }
  __syncthreads();
  if (t < 32) {
    int m = t >> 1, e = t & 1;
    float acc = c4b[e];
    const float* zr = z2 + m * 260;
    for (int j = 0; j < 256; ++j) acc = fmaf(zr[j], c4w[j * 2 + e], acc);
    out[(size_t)(p0 + m) * 2 + e] = acc;
  }
}

// ===========================================================================
extern "C" void kernel_launch(void* const* d_in, const int* in_sizes, int n_in,
                              void* d_out, int out_size, void* d_ws, size_t ws_size,
                              hipStream_t stream) {
  const float* xin = (const float*)d_in[0];
  const float* W[30];
  for (int i = 0; i < 30; ++i) W[i] = (const float*)d_in[i + 1];

  float* ws = (float*)d_ws;
  size_t off = 0;
  float* pts   = ws + off; off += (size_t)BN * 3;
  float* p     = ws + off; off += (size_t)BN * 3;
  int*   idx   = (int*)(ws + off); off += (size_t)BN * KK;
  float* sq    = ws + off; off += BN;
  float* t128  = ws + off; off += (size_t)BN * 128;
  float* dpart = ws + off; off += 4 * 8 * 1024;
  float* h1    = ws + off; off += 4 * 512;
  float* x1    = ws + off; off += (size_t)BN * 64;
  float* x2    = ws + off; off += (size_t)BN * 64;
  float* x3    = ws + off; off += (size_t)BN * 64;
  float* gpart = ws + off; off += 4 * 8 * 1024;
  float* gc    = ws + off; off += 4 * 512;
  float* uvb   = ws + off; off += (size_t)BN * 128;                 // u/v buffer
  unsigned short* xcat = (unsigned short*)(ws + off); off += (size_t)BN * 96;
  unsigned short* c1wT = (unsigned short*)(ws + off); off += 98304;
  unsigned short* c2wT = (unsigned short*)(ws + off); off += 49152;
  unsigned short* c3wT = (unsigned short*)(ws + off); off += 65536;
  unsigned short* w3Th = (unsigned short*)(ws + off); off += 65536;
  unsigned short* w3Tm = (unsigned short*)(ws + off); off += 65536;
  unsigned short* w3Tl = (unsigned short*)(ws + off); off += 65536;
  unsigned short* tw2h = (unsigned short*)(ws + off); off += 4096;  // 128x64 bf16
  unsigned short* tw2m = (unsigned short*)(ws + off); off += 4096;
  unsigned short* tw2l = (unsigned short*)(ws + off); off += 4096;
  unsigned short* e1h  = (unsigned short*)(ws + off); off += 2048;  // 64x64 bf16
  unsigned short* e1m  = (unsigned short*)(ws + off); off += 2048;
  unsigned short* e1l  = (unsigned short*)(ws + off); off += 2048;
  unsigned short* e2h  = (unsigned short*)(ws + off); off += 2048;
  unsigned short* e2m  = (unsigned short*)(ws + off); off += 2048;
  unsigned short* e2l  = (unsigned short*)(ws + off); off += 2048;
  unsigned short* xsh  = (unsigned short*)(ws + off); off += 524288;
  unsigned short* xsm  = (unsigned short*)(ws + off); off += 524288;
  unsigned short* xsl  = (unsigned short*)(ws + off); off += 524288;
  float* MdC   = ws + off; off += 8192;
  float* MdD   = ws + off; off += 8192;
  float* Dbuf  = ws + off; off += (size_t)Nn * Nn;
  unsigned short* t3h = (unsigned short*)Dbuf;
  unsigned short* t3m = t3h + (size_t)BN * 128;
  unsigned short* t3l = t3m + (size_t)BN * 128;

  // weight prep
  k_cvtT<<<dim3(768), dim3(256), 0, stream>>>(W[22], c1wT, 1024, 192, 1024, 0);
  k_cvtT<<<dim3(384), dim3(256), 0, stream>>>(W[24], c2wT, 512, 192, 512, 1024);
  k_cvtT<<<dim3(512), dim3(256), 0, stream>>>(W[26], c3wT, 256, 512, 256, 0);
  k_cvtT3<<<dim3(512), dim3(256), 0, stream>>>(W[4], w3Th, w3Tm, w3Tl, 1024, 128, 1024);
  k_cvtT3<<<dim3(32), dim3(256), 0, stream>>>(W[2], tw2h, tw2m, tw2l, 128, 64, 128);
  k_cvtT3<<<dim3(16), dim3(256), 0, stream>>>(W[14], e1h, e1m, e1l, 64, 64, 64);
  k_cvtT3<<<dim3(16), dim3(256), 0, stream>>>(W[18], e2h, e2m, e2l, 64, 64, 64);
  k_prepD<<<dim3(32), dim3(256), 0, stream>>>(W[16], MdC);
  k_prepD<<<dim3(32), dim3(256), 0, stream>>>(W[20], MdD);

  k_pts<<<dim3(192), dim3(256), 0, stream>>>(xin, pts);

  // stage 1: transform branch
  k_knn3<<<dim3(1024), dim3(1024), 0, stream>>>(pts, idx);
  k_uv3<<<dim3(4096), dim3(256), 0, stream>>>(pts, W[0], W[1], uvb);
  k_econv<128><<<dim3(4096), dim3(256), 0, stream>>>(uvb, idx, tw2h, tw2m, tw2l, W[3], t128);
  k_split3<<<dim3(8192), dim3(256), 0, stream>>>(t128, t3h, t3m, t3l, BN * 128);
  k_mgemm3s<128><<<dim3(512), dim3(256), 0, stream>>>(t3h, t3m, t3l, w3Th, w3Tm, w3Tl, dpart);
  k_fc1<<<dim3(32), dim3(256), 0, stream>>>(dpart, W[5], W[6], W[7], h1);
  k_fc23p<<<dim3(4), dim3(256), 0, stream>>>(h1, W[8], W[9], W[10], W[11], pts, p);

  // stage 2
  k_knn3<<<dim3(1024), dim3(1024), 0, stream>>>(p, idx);
  k_uv3<<<dim3(4096), dim3(256), 0, stream>>>(p, W[12], W[13], uvb);
  k_econv<64><<<dim3(4096), dim3(256), 0, stream>>>(uvb, idx, e1h, e1m, e1l, W[15], x1);
  k_sqnorm<<<dim3(64), dim3(256), 0, stream>>>(x1, sq);
  k_split3<<<dim3(4096), dim3(256), 0, stream>>>(x1, xsh, xsm, xsl, BN * 64);
  for (int b = 0; b < 4; ++b) {
    k_dist3s<<<dim3(4096), dim3(256), 0, stream>>>(xsh, xsm, xsl, sq, b, Dbuf);
    k_sel<<<dim3(1024), dim3(256), 0, stream>>>(Dbuf, b, idx);
  }
  k_uv<<<dim3(256), dim3(256), 0, stream>>>(x1, MdC, W[17], uvb);
  k_econv<64><<<dim3(4096), dim3(256), 0, stream>>>(uvb, idx, e2h, e2m, e2l, W[19], x2);
  k_sqnorm<<<dim3(64), dim3(256), 0, stream>>>(x2, sq);
  k_split3<<<dim3(4096), dim3(256), 0, stream>>>(x2, xsh, xsm, xsl, BN * 64);
  for (int b = 0; b < 4; ++b) {
    k_dist3s<<<dim3(4096), dim3(256), 0, stream>>>(xsh, xsm, xsl, sq, b, Dbuf);
    k_sel<<<dim3(1024), dim3(256), 0, stream>>>(Dbuf, b, idx);
  }
  // edgeD via u/v factorization (bias folded into u)
  k_uv<<<dim3(256), dim3(256), 0, stream>>>(x2, MdD, W[21], uvb);
  k_gmax<<<dim3(4096), dim3(256), 0, stream>>>(uvb, idx, x3);

  // stage 3
  k_cat<<<dim3(12288), dim3(256), 0, stream>>>(x1, x2, x3, xcat);
  k_mgemm<192><<<dim3(512), dim3(256), 0, stream>>>(xcat, c1wT, gpart);
  k_j2<<<dim3(8), dim3(256), 0, stream>>>(gpart, W[23], W[24], gc);
  k_final<<<dim3(1024), dim3(256), 0, stream>>>(xcat, gc, W[25], c2wT, c3wT,
                                                W[27], W[28], W[29], (float*)d_out);
}